// Round 2
// baseline (3048.387 us; speedup 1.0000x reference)
//
#include <hip/hip_runtime.h>

#define THREADS 256

// ---------------------------------------------------------------- bf16 helpers (raw ushort storage)
__device__ __forceinline__ float bf2f(unsigned short u) {
    union { unsigned int i; float f; } v;
    v.i = ((unsigned int)u) << 16;
    return v.f;
}
__device__ __forceinline__ unsigned short f2bf(float f) {
    union { float f; unsigned int i; } v;
    v.f = f;
    unsigned int r = (v.i + 0x7FFFu + ((v.i >> 16) & 1u)) >> 16;  // RNE
    return (unsigned short)r;
}
__device__ __forceinline__ float4 ld4f(const float* p) {
    return *reinterpret_cast<const float4*>(p);
}
__device__ __forceinline__ float4 ld4f(const unsigned short* p) {
    ushort4 u = *reinterpret_cast<const ushort4*>(p);
    return make_float4(bf2f(u.x), bf2f(u.y), bf2f(u.z), bf2f(u.w));
}
__device__ __forceinline__ float ld1f(const float* p) { return *p; }
__device__ __forceinline__ float ld1f(const unsigned short* p) { return bf2f(*p); }

// ---------------------------------------------------------------- edge accessor (int32 or int64 payload)
// mode==1: buffer actually holds int64 little-endian values (< 2^31) -> low word at 2*idx
__device__ __forceinline__ int edge_get(const int* base, int E, int mode, int which, int e) {
    size_t idx = (size_t)which * (size_t)E + (size_t)e;
    return mode ? base[2 * idx] : base[idx];
}

__global__ __launch_bounds__(256) void k_detect(const int* __restrict__ e, int E,
                                                int* __restrict__ mode) {
    __shared__ int nz;
    if (threadIdx.x == 0) nz = 0;
    __syncthreads();
    int lim = 2 * E;
    if (lim > 8192) lim = 8192;
    for (int i = 1 + 2 * (int)threadIdx.x; i < lim; i += 512)
        if (e[i] != 0) nz = 1;
    __syncthreads();
    if (threadIdx.x == 0) *mode = (nz == 0) ? 1 : 0;
}

// ---------------------------------------------------------------- graph prep
__global__ __launch_bounds__(256) void k_count(const int* __restrict__ eb, int E,
                                               const int* __restrict__ mode, int N,
                                               int* __restrict__ cnt) {
    int m = *mode;
    int e = blockIdx.x * THREADS + threadIdx.x;
    if (e < E) {
        int c = edge_get(eb, E, m, 1, e);
        if ((unsigned)c < (unsigned)N) atomicAdd(&cnt[c], 1);
    }
}

__global__ __launch_bounds__(256) void k_scan1(const int* __restrict__ cnt, int N,
                                               int* __restrict__ bsum) {
    __shared__ int s[256];
    int i = blockIdx.x * 256 + threadIdx.x;
    s[threadIdx.x] = (i < N) ? cnt[i] : 0;
    __syncthreads();
    for (int off = 128; off > 0; off >>= 1) {
        if (threadIdx.x < off) s[threadIdx.x] += s[threadIdx.x + off];
        __syncthreads();
    }
    if (threadIdx.x == 0) bsum[blockIdx.x] = s[0];
}

__global__ __launch_bounds__(512) void k_scan2(int* __restrict__ bsum, int nb) {
    __shared__ int s[512];
    int t = threadIdx.x;
    int v = (t < nb) ? bsum[t] : 0;
    s[t] = v;
    __syncthreads();
    for (int off = 1; off < 512; off <<= 1) {
        int add = (t >= off) ? s[t - off] : 0;
        __syncthreads();
        s[t] += add;
        __syncthreads();
    }
    if (t < nb) bsum[t] = s[t] - v;  // exclusive
}

__global__ __launch_bounds__(256) void k_scan3(const int* __restrict__ cnt, int N,
                                               const int* __restrict__ bsum,
                                               int* __restrict__ offs) {
    __shared__ int s[256];
    int i = blockIdx.x * 256 + threadIdx.x;
    int v = (i < N) ? cnt[i] : 0;
    s[threadIdx.x] = v;
    __syncthreads();
    for (int off = 1; off < 256; off <<= 1) {
        int add = (threadIdx.x >= off) ? s[threadIdx.x - off] : 0;
        __syncthreads();
        s[threadIdx.x] += add;
        __syncthreads();
    }
    if (i < N) offs[i] = bsum[blockIdx.x] + s[threadIdx.x] - v;
}

__global__ __launch_bounds__(256) void k_deginv(const int* __restrict__ cnt,
                                                const int* __restrict__ offs, int N,
                                                float* __restrict__ deg_inv,
                                                int* __restrict__ cursor) {
    int i = blockIdx.x * 256 + threadIdx.x;
    if (i < N) {
        int c = cnt[i];
        deg_inv[i] = (c > 0) ? 1.0f / (float)c : 0.0f;
        cursor[i] = offs[i];
    }
}

__global__ __launch_bounds__(256) void k_scatter(const int* __restrict__ eb, int E,
                                                 const int* __restrict__ mode, int N,
                                                 int* __restrict__ cursor,
                                                 int* __restrict__ csr_src) {
    int m = *mode;
    int e = blockIdx.x * THREADS + threadIdx.x;
    if (e < E) {
        int c = edge_get(eb, E, m, 1, e);
        if ((unsigned)c < (unsigned)N) {
            int r = edge_get(eb, E, m, 0, e);
            if ((unsigned)r >= (unsigned)N) r = 0;  // crash-proof clamp
            int pos = atomicAdd(&cursor[c], 1);
            csr_src[pos] = r;
        }
    }
}

// ---------------------------------------------------------------- Q/K proj + row L2-norm (bf16 out)
__global__ __launch_bounds__(256) void k_proj(const float* __restrict__ x,
                                              const float* __restrict__ Wq,
                                              const float* __restrict__ bq,
                                              const float* __restrict__ Wk,
                                              const float* __restrict__ bk,
                                              unsigned short* __restrict__ qs,
                                              unsigned short* __restrict__ ks,
                                              float* __restrict__ ks_sum, int N) {
    __shared__ float xs[16][128];
    __shared__ float partq[4][16];
    __shared__ float partk[4][16];
    const int t = threadIdx.x;
    const int r0 = blockIdx.x * 16;
    for (int i = 0; i < 2; i++) {
        int idx4 = i * 256 + t;
        int r = idx4 >> 5, c4 = (idx4 & 31) * 4;
        float4 v = make_float4(0.f, 0.f, 0.f, 0.f);
        if (r0 + r < N) v = ld4f(&x[(size_t)(r0 + r) * 128 + c4]);
        *reinterpret_cast<float4*>(&xs[r][c4]) = v;
    }
    __syncthreads();

    float aq[16], ak[16];
#pragma unroll
    for (int r = 0; r < 16; r++) { aq[r] = 0.f; ak[r] = 0.f; }
    const int col = t;
    for (int k = 0; k < 128; k += 4) {
        float wq0 = Wq[(k + 0) * 256 + col];
        float wq1 = Wq[(k + 1) * 256 + col];
        float wq2 = Wq[(k + 2) * 256 + col];
        float wq3 = Wq[(k + 3) * 256 + col];
        float wk0 = Wk[(k + 0) * 256 + col];
        float wk1 = Wk[(k + 1) * 256 + col];
        float wk2 = Wk[(k + 2) * 256 + col];
        float wk3 = Wk[(k + 3) * 256 + col];
#pragma unroll
        for (int r = 0; r < 16; r++) {
            float4 xv = *reinterpret_cast<const float4*>(&xs[r][k]);
            aq[r] += xv.x * wq0 + xv.y * wq1 + xv.z * wq2 + xv.w * wq3;
            ak[r] += xv.x * wk0 + xv.y * wk1 + xv.z * wk2 + xv.w * wk3;
        }
    }
    float bqv = bq[col], bkv = bk[col];
#pragma unroll
    for (int r = 0; r < 16; r++) { aq[r] += bqv; ak[r] += bkv; }

    const int lane = t & 63, w = t >> 6;
#pragma unroll
    for (int r = 0; r < 16; r++) {
        float sq = aq[r] * aq[r];
        float sk = ak[r] * ak[r];
#pragma unroll
        for (int off = 1; off < 64; off <<= 1) {
            sq += __shfl_xor(sq, off);
            sk += __shfl_xor(sk, off);
        }
        if (lane == 0) { partq[w][r] = sq; partk[w][r] = sk; }
    }
    __syncthreads();

    const int h = col >> 7;
    float local_ks = 0.f;
#pragma unroll
    for (int r = 0; r < 16; r++) {
        if (r0 + r < N) {
            float invq = rsqrtf(partq[2 * h][r] + partq[2 * h + 1][r]);
            float invk = rsqrtf(partk[2 * h][r] + partk[2 * h + 1][r]);
            unsigned short qb = f2bf(aq[r] * invq);
            unsigned short kb = f2bf(ak[r] * invk);
            qs[(size_t)(r0 + r) * 256 + col] = qb;
            ks[(size_t)(r0 + r) * 256 + col] = kb;
            local_ks += bf2f(kb);
        }
    }
    atomicAdd(&ks_sum[col], local_ks);
}

// ---------------------------------------------------------------- den = qs . ks_sum + N
__global__ __launch_bounds__(256) void k_den(const unsigned short* __restrict__ qs,
                                             const float* __restrict__ ks_sum,
                                             float* __restrict__ den, int N) {
    int w = threadIdx.x >> 6, lane = threadIdx.x & 63;
    int n = blockIdx.x * 4 + w;
    if (n >= N) return;
    float4 q = ld4f(&qs[(size_t)n * 256 + lane * 4]);
    float4 kv = *reinterpret_cast<const float4*>(&ks_sum[lane * 4]);
    float s = q.x * kv.x + q.y * kv.y + q.z * kv.z + q.w * kv.w;
#pragma unroll
    for (int off = 1; off < 32; off <<= 1) s += __shfl_xor(s, off);
    if ((lane & 31) == 0) den[n * 2 + (lane >> 5)] = s + (float)N;
}

// ---------------------------------------------------------------- kvs = ks^T @ vs (split-K, atomic combine)
template <typename TV>
__global__ __launch_bounds__(256) void k_kvs(const unsigned short* __restrict__ ks,
                                             const TV* __restrict__ vs, int vstride, int vmask,
                                             float* __restrict__ kvs, float* __restrict__ vs_sum,
                                             int N) {
    __shared__ float ksb[32][64];
    __shared__ float vsb[32][64];
    const int t = threadIdx.x;
    const int combo = blockIdx.y;
    const int h = combo >> 2, ti = (combo >> 1) & 1, tj = combo & 1;
    const int rows_per = (N + 255) >> 8;
    int r0 = blockIdx.x * rows_per;
    int rend = min(r0 + rows_per, N);
    const int ir = t >> 4, jr = t & 15;
    const int i0 = ir * 4, j0 = jr * 4;
    const int kbase = h * 128 + ti * 64;
    const int vbase = h * 128 + tj * 64;
    const bool do_vsum = (ti == 0) && (ir == 0);

    float acc[4][4];
#pragma unroll
    for (int a = 0; a < 4; a++)
#pragma unroll
        for (int b = 0; b < 4; b++) acc[a][b] = 0.f;
    float vsum[4] = {0.f, 0.f, 0.f, 0.f};

    for (int c0 = r0; c0 < rend; c0 += 32) {
        int L = rend - c0;
        if (L > 32) L = 32;
#pragma unroll
        for (int i = 0; i < 4; i++) {
            int idx4 = i * 256 + t;
            int arr = idx4 >> 9;
            int rem = idx4 & 511;
            int l = rem >> 4, c4 = (rem & 15) * 4;
            float4 v = make_float4(0.f, 0.f, 0.f, 0.f);
            if (l < L) {
                if (arr == 0)
                    v = ld4f(&ks[(size_t)(c0 + l) * 256 + kbase + c4]);
                else
                    v = ld4f(&vs[(size_t)(c0 + l) * vstride + ((vbase + c4) & vmask)]);
            }
            if (arr == 0)
                *reinterpret_cast<float4*>(&ksb[l][c4]) = v;
            else
                *reinterpret_cast<float4*>(&vsb[l][c4]) = v;
        }
        __syncthreads();
#pragma unroll 4
        for (int l = 0; l < 32; l++) {
            float4 kv = *reinterpret_cast<const float4*>(&ksb[l][i0]);
            float4 vv = *reinterpret_cast<const float4*>(&vsb[l][j0]);
            acc[0][0] += kv.x * vv.x; acc[0][1] += kv.x * vv.y; acc[0][2] += kv.x * vv.z; acc[0][3] += kv.x * vv.w;
            acc[1][0] += kv.y * vv.x; acc[1][1] += kv.y * vv.y; acc[1][2] += kv.y * vv.z; acc[1][3] += kv.y * vv.w;
            acc[2][0] += kv.z * vv.x; acc[2][1] += kv.z * vv.y; acc[2][2] += kv.z * vv.z; acc[2][3] += kv.z * vv.w;
            acc[3][0] += kv.w * vv.x; acc[3][1] += kv.w * vv.y; acc[3][2] += kv.w * vv.z; acc[3][3] += kv.w * vv.w;
            if (do_vsum) { vsum[0] += vv.x; vsum[1] += vv.y; vsum[2] += vv.z; vsum[3] += vv.w; }
        }
        __syncthreads();
    }
#pragma unroll
    for (int a = 0; a < 4; a++)
#pragma unroll
        for (int b = 0; b < 4; b++)
            atomicAdd(&kvs[h * 16384 + (ti * 64 + i0 + a) * 128 + tj * 64 + j0 + b], acc[a][b]);
    if (do_vsum) {
#pragma unroll
        for (int b = 0; b < 4; b++) atomicAdd(&vs_sum[h * 128 + tj * 64 + j0 + b], vsum[b]);
    }
}

// ---------------------------------------------------------------- GCN gather: cur = 0.5*deg_inv*sum prev[src]
template <typename TS>
__global__ __launch_bounds__(256) void k_gather(const TS* __restrict__ prev, int pstride, int pmask,
                                                const int* __restrict__ csr_src,
                                                const int* __restrict__ offs,
                                                const int* __restrict__ cnt,
                                                const float* __restrict__ deg_inv,
                                                unsigned short* __restrict__ cur, int N) {
    const int t = threadIdx.x;
    const int ch = t & pmask;
    int nbase = blockIdx.x * 8;
    for (int i = 0; i < 8; i++) {
        int n = nbase + i;
        if (n >= N) return;
        int start = offs[n], d = cnt[n];
        int e = start, eend = start + d;
        float acc = 0.f;
        for (; e + 4 <= eend; e += 4) {
            int s0 = csr_src[e], s1 = csr_src[e + 1], s2 = csr_src[e + 2], s3 = csr_src[e + 3];
            acc += ld1f(&prev[(size_t)s0 * pstride + ch]);
            acc += ld1f(&prev[(size_t)s1 * pstride + ch]);
            acc += ld1f(&prev[(size_t)s2 * pstride + ch]);
            acc += ld1f(&prev[(size_t)s3 * pstride + ch]);
        }
        for (; e < eend; e++) acc += ld1f(&prev[(size_t)csr_src[e] * pstride + ch]);
        cur[(size_t)n * 256 + t] = f2bf(0.5f * deg_inv[n] * acc);
    }
}

// ---------------------------------------------------------------- cur += (qs@kvs + vs_sum)/den
__global__ __launch_bounds__(256) void k_combine(const unsigned short* __restrict__ qs,
                                                 const float* __restrict__ kvs,
                                                 const float* __restrict__ vs_sum,
                                                 const float* __restrict__ den,
                                                 unsigned short* __restrict__ cur, int N) {
    __shared__ float kvsl[128][64];            // 32 KB
    __shared__ unsigned short qst[128][72];    // 18 KB
    const int t = threadIdx.x;
    const int h = blockIdx.y >> 1, jh = blockIdx.y & 1;
    const int n0t = blockIdx.x * 64;
#pragma unroll
    for (int i = 0; i < 8; i++) {
        int idx4 = i * 256 + t;
        int k = idx4 >> 4, j4 = (idx4 & 15) * 4;
        *reinterpret_cast<float4*>(&kvsl[k][j4]) =
            *reinterpret_cast<const float4*>(&kvs[h * 16384 + k * 128 + jh * 64 + j4]);
    }
    {
        int n_l = t >> 2, k0 = (t & 3) * 32;
        int n = n0t + n_l;
#pragma unroll
        for (int c = 0; c < 8; c++) {
            ushort4 u = make_ushort4(0, 0, 0, 0);
            if (n < N)
                u = *reinterpret_cast<const ushort4*>(&qs[(size_t)n * 256 + h * 128 + k0 + c * 4]);
            qst[k0 + c * 4 + 0][n_l] = u.x;
            qst[k0 + c * 4 + 1][n_l] = u.y;
            qst[k0 + c * 4 + 2][n_l] = u.z;
            qst[k0 + c * 4 + 3][n_l] = u.w;
        }
    }
    __syncthreads();
    const int nr = t >> 4, jr = t & 15;
    const int n0 = nr * 4, j0 = jr * 4;
    float acc[4][4];
#pragma unroll
    for (int a = 0; a < 4; a++)
#pragma unroll
        for (int b = 0; b < 4; b++) acc[a][b] = 0.f;
#pragma unroll 4
    for (int k = 0; k < 128; k++) {
        float4 q4 = ld4f(&qst[k][n0]);
        float4 v4 = *reinterpret_cast<const float4*>(&kvsl[k][j0]);
        acc[0][0] += q4.x * v4.x; acc[0][1] += q4.x * v4.y; acc[0][2] += q4.x * v4.z; acc[0][3] += q4.x * v4.w;
        acc[1][0] += q4.y * v4.x; acc[1][1] += q4.y * v4.y; acc[1][2] += q4.y * v4.z; acc[1][3] += q4.y * v4.w;
        acc[2][0] += q4.z * v4.x; acc[2][1] += q4.z * v4.y; acc[2][2] += q4.z * v4.z; acc[2][3] += q4.z * v4.w;
        acc[3][0] += q4.w * v4.x; acc[3][1] += q4.w * v4.y; acc[3][2] += q4.w * v4.z; acc[3][3] += q4.w * v4.w;
    }
    const int jg = jh * 64 + j0;
    float4 vsum4 = *reinterpret_cast<const float4*>(&vs_sum[h * 128 + jg]);
#pragma unroll
    for (int a = 0; a < 4; a++) {
        int n = n0t + n0 + a;
        if (n < N) {
            float invd = 1.0f / den[n * 2 + h];
            unsigned short* cp = &cur[(size_t)n * 256 + h * 128 + jg];
            float4 c4 = ld4f(cp);
            c4.x += (acc[a][0] + vsum4.x) * invd;
            c4.y += (acc[a][1] + vsum4.y) * invd;
            c4.z += (acc[a][2] + vsum4.z) * invd;
            c4.w += (acc[a][3] + vsum4.w) * invd;
            ushort4 s;
            s.x = f2bf(c4.x); s.y = f2bf(c4.y); s.z = f2bf(c4.z); s.w = f2bf(c4.w);
            *reinterpret_cast<ushort4*>(cp) = s;
        }
    }
}

// ---------------------------------------------------------------- out += (term @ Wo_blk)/H (+ bias/H)
// xcat flat order: Wo row = h*640 + tblk*128 + c
template <typename TS>
__global__ __launch_bounds__(256) void k_out(const TS* __restrict__ term, int tstride, int tmask,
                                             const float* __restrict__ Wo,
                                             const float* __restrict__ Wo_b, int tblk, float bscale,
                                             float* __restrict__ out, int N) {
    __shared__ unsigned short tl[256][40];  // 20 KB, [channel][row]
    __shared__ float wl[64][128];           // 32 KB
    const int t = threadIdx.x;
    const int n0t = blockIdx.x * 32;
    {
        int n_l = t >> 3, c0 = (t & 7) * 4;
        int n = n0t + n_l;
#pragma unroll
        for (int i = 0; i < 8; i++) {
            int c = c0 + i * 32;
            float4 v = make_float4(0.f, 0.f, 0.f, 0.f);
            if (n < N) v = ld4f(&term[(size_t)n * tstride + (c & tmask)]);
            tl[c + 0][n_l] = f2bf(v.x);
            tl[c + 1][n_l] = f2bf(v.y);
            tl[c + 2][n_l] = f2bf(v.z);
            tl[c + 3][n_l] = f2bf(v.w);
        }
    }
    const int nr = t >> 5, jr = t & 31;
    const int n0 = nr * 4, j0 = jr * 4;
    float acc[4][4];
#pragma unroll
    for (int a = 0; a < 4; a++)
#pragma unroll
        for (int b = 0; b < 4; b++) acc[a][b] = 0.f;

    for (int cb = 0; cb < 4; cb++) {
        __syncthreads();
#pragma unroll
        for (int i = 0; i < 8; i++) {
            int idx4 = i * 256 + t;
            int kc = idx4 >> 5, j4 = (idx4 & 31) * 4;
            int c = cb * 64 + kc;
            int wrow = (c >> 7) * 640 + tblk * 128 + (c & 127);
            *reinterpret_cast<float4*>(&wl[kc][j4]) =
                *reinterpret_cast<const float4*>(&Wo[(size_t)wrow * 128 + j4]);
        }
        __syncthreads();
#pragma unroll 4
        for (int kc = 0; kc < 64; kc++) {
            int c = cb * 64 + kc;
            float4 q4 = ld4f(&tl[c][n0]);
            float4 w4 = *reinterpret_cast<const float4*>(&wl[kc][j0]);
            acc[0][0] += q4.x * w4.x; acc[0][1] += q4.x * w4.y; acc[0][2] += q4.x * w4.z; acc[0][3] += q4.x * w4.w;
            acc[1][0] += q4.y * w4.x; acc[1][1] += q4.y * w4.y; acc[1][2] += q4.y * w4.z; acc[1][3] += q4.y * w4.w;
            acc[2][0] += q4.z * w4.x; acc[2][1] += q4.z * w4.y; acc[2][2] += q4.z * w4.z; acc[2][3] += q4.z * w4.w;
            acc[3][0] += q4.w * w4.x; acc[3][1] += q4.w * w4.y; acc[3][2] += q4.w * w4.z; acc[3][3] += q4.w * w4.w;
        }
    }
    float4 b4 = *reinterpret_cast<const float4*>(&Wo_b[j0]);
#pragma unroll
    for (int a = 0; a < 4; a++) {
        int n = n0t + n0 + a;
        if (n < N) {
            float4 o4 = *reinterpret_cast<float4*>(&out[(size_t)n * 128 + j0]);
            o4.x += 0.5f * acc[a][0] + bscale * b4.x;
            o4.y += 0.5f * acc[a][1] + bscale * b4.y;
            o4.z += 0.5f * acc[a][2] + bscale * b4.z;
            o4.w += 0.5f * acc[a][3] + bscale * b4.w;
            *reinterpret_cast<float4*>(&out[(size_t)n * 128 + j0]) = o4;
        }
    }
}

// ================================================================ host
extern "C" void kernel_launch(void* const* d_in, const int* in_sizes, int n_in,
                              void* d_out, int out_size, void* d_ws, size_t ws_size,
                              hipStream_t stream) {
    const int N = in_sizes[0] / 128;
    const int E = in_sizes[1] / 2;
    const float* x = (const float*)d_in[0];
    const int* eraw = (const int*)d_in[1];
    const float* Wq_w = (const float*)d_in[2];
    const float* Wq_b = (const float*)d_in[3];
    const float* Wk_w = (const float*)d_in[4];
    const float* Wk_b = (const float*)d_in[5];
    const float* Wo_w = (const float*)d_in[6];
    const float* Wo_b = (const float*)d_in[7];
    float* out = (float*)d_out;

    char* p = (char*)d_ws;
    auto alloc = [&](size_t bytes) -> void* {
        void* r = (void*)p;
        p += (bytes + 255) & ~(size_t)255;
        return r;
    };
    // bf16 (ushort) big buffers: total ~214 MB
    unsigned short* qs = (unsigned short*)alloc((size_t)N * 256 * 2);
    unsigned short* ks = (unsigned short*)alloc((size_t)N * 256 * 2);
    unsigned short* bufA = (unsigned short*)alloc((size_t)N * 256 * 2);
    unsigned short* bufB = (unsigned short*)alloc((size_t)N * 256 * 2);
    float* deg_inv = (float*)alloc((size_t)N * 4);
    float* den = (float*)alloc((size_t)N * 2 * 4);
    float* kvs = (float*)alloc((size_t)(2 * 128 * 128 + 256) * 4);  // + vs_sum tail
    float* ks_sum = (float*)alloc(256 * 4);
    int* cnt = (int*)alloc((size_t)N * 4);
    int* offs = (int*)alloc((size_t)N * 4);
    int* cursor = (int*)alloc((size_t)N * 4);
    int* bsum = (int*)alloc(512 * 4);
    int* mode = (int*)alloc(256);
    int* csr = (int*)alloc((size_t)E * 4);

    hipMemsetAsync(cnt, 0, (size_t)N * 4, stream);
    hipMemsetAsync(ks_sum, 0, 256 * 4, stream);
    hipMemsetAsync(out, 0, (size_t)N * 128 * 4, stream);

    const int nb = (N + 255) / 256;
    const int eb = (E + 255) / 256;
    k_detect<<<1, 256, 0, stream>>>(eraw, E, mode);
    k_count<<<eb, 256, 0, stream>>>(eraw, E, mode, N, cnt);
    k_scan1<<<nb, 256, 0, stream>>>(cnt, N, bsum);
    k_scan2<<<1, 512, 0, stream>>>(bsum, nb);
    k_scan3<<<nb, 256, 0, stream>>>(cnt, N, bsum, offs);
    k_deginv<<<nb, 256, 0, stream>>>(cnt, offs, N, deg_inv, cursor);
    k_scatter<<<eb, 256, 0, stream>>>(eraw, E, mode, N, cursor, csr);

    k_proj<<<(N + 15) / 16, 256, 0, stream>>>(x, Wq_w, Wq_b, Wk_w, Wk_b, qs, ks, ks_sum, N);
    k_den<<<(N + 3) / 4, 256, 0, stream>>>(qs, ks_sum, den, N);

    // term 0 = x broadcast to both heads (read f32 directly)
    k_out<float><<<(N + 31) / 32, 256, 0, stream>>>(x, 128, 127, Wo_w, Wo_b, 0, 0.5f, out, N);

    const size_t kvs_bytes = (size_t)(2 * 128 * 128 + 256) * 4;
    dim3 g1(256, 8);
    dim3 g2((N + 63) / 64, 4);
    const int gb = (N + 7) / 8;
    const int ob = (N + 31) / 32;

    // hop 1: prev = x (f32, stride 128, head-broadcast)
    hipMemsetAsync(kvs, 0, kvs_bytes, stream);
    k_kvs<float><<<g1, 256, 0, stream>>>(ks, x, 128, 127, kvs, kvs + 32768, N);
    k_gather<float><<<gb, 256, 0, stream>>>(x, 128, 127, csr, offs, cnt, deg_inv, bufA, N);
    k_combine<<<g2, 256, 0, stream>>>(qs, kvs, kvs + 32768, den, bufA, N);
    k_out<unsigned short><<<ob, 256, 0, stream>>>(bufA, 256, 255, Wo_w, Wo_b, 1, 0.0f, out, N);

    // hops 2..4: prev = bf16 term buffers
    unsigned short* prev = bufA;
    unsigned short* cur = bufB;
    for (int step = 2; step <= 4; step++) {
        hipMemsetAsync(kvs, 0, kvs_bytes, stream);
        k_kvs<unsigned short><<<g1, 256, 0, stream>>>(ks, prev, 256, 255, kvs, kvs + 32768, N);
        k_gather<unsigned short><<<gb, 256, 0, stream>>>(prev, 256, 255, csr, offs, cnt, deg_inv,
                                                         cur, N);
        k_combine<<<g2, 256, 0, stream>>>(qs, kvs, kvs + 32768, den, cur, N);
        k_out<unsigned short><<<ob, 256, 0, stream>>>(cur, 256, 255, Wo_w, Wo_b, step, 0.0f, out, N);
        unsigned short* tmp = prev;
        prev = cur;
        cur = tmp;
    }
}

// Round 3
// 2709.868 us; speedup vs baseline: 1.1249x; 1.1249x over previous
//
#include <hip/hip_runtime.h>

#define THREADS 256

typedef __attribute__((ext_vector_type(8))) short short8;
typedef __attribute__((ext_vector_type(4))) float f32x4;

// ---------------------------------------------------------------- bf16 helpers (raw ushort storage)
__device__ __forceinline__ float bf2f(unsigned short u) {
    union { unsigned int i; float f; } v;
    v.i = ((unsigned int)u) << 16;
    return v.f;
}
__device__ __forceinline__ unsigned short f2bf(float f) {
    union { float f; unsigned int i; } v;
    v.f = f;
    unsigned int r = (v.i + 0x7FFFu + ((v.i >> 16) & 1u)) >> 16;  // RNE
    return (unsigned short)r;
}
__device__ __forceinline__ float4 ld4f(const float* p) {
    return *reinterpret_cast<const float4*>(p);
}
__device__ __forceinline__ float4 ld4f(const unsigned short* p) {
    ushort4 u = *reinterpret_cast<const ushort4*>(p);
    return make_float4(bf2f(u.x), bf2f(u.y), bf2f(u.z), bf2f(u.w));
}
__device__ __forceinline__ float ld1f(const float* p) { return *p; }
__device__ __forceinline__ float ld1f(const unsigned short* p) { return bf2f(*p); }

// ---------------------------------------------------------------- edge accessor (int32 or int64 payload)
__device__ __forceinline__ int edge_get(const int* base, int E, int mode, int which, int e) {
    size_t idx = (size_t)which * (size_t)E + (size_t)e;
    return mode ? base[2 * idx] : base[idx];
}

__global__ __launch_bounds__(256) void k_detect(const int* __restrict__ e, int E,
                                                int* __restrict__ mode) {
    __shared__ int nz;
    if (threadIdx.x == 0) nz = 0;
    __syncthreads();
    int lim = 2 * E;
    if (lim > 8192) lim = 8192;
    for (int i = 1 + 2 * (int)threadIdx.x; i < lim; i += 512)
        if (e[i] != 0) nz = 1;
    __syncthreads();
    if (threadIdx.x == 0) *mode = (nz == 0) ? 1 : 0;
}

// ---------------------------------------------------------------- graph prep
__global__ __launch_bounds__(256) void k_count(const int* __restrict__ eb, int E,
                                               const int* __restrict__ mode, int N,
                                               int* __restrict__ cnt) {
    int m = *mode;
    int e = blockIdx.x * THREADS + threadIdx.x;
    if (e < E) {
        int c = edge_get(eb, E, m, 1, e);
        if ((unsigned)c < (unsigned)N) atomicAdd(&cnt[c], 1);
    }
}

__global__ __launch_bounds__(256) void k_scan1(const int* __restrict__ cnt, int N,
                                               int* __restrict__ bsum) {
    __shared__ int s[256];
    int i = blockIdx.x * 256 + threadIdx.x;
    s[threadIdx.x] = (i < N) ? cnt[i] : 0;
    __syncthreads();
    for (int off = 128; off > 0; off >>= 1) {
        if (threadIdx.x < off) s[threadIdx.x] += s[threadIdx.x + off];
        __syncthreads();
    }
    if (threadIdx.x == 0) bsum[blockIdx.x] = s[0];
}

__global__ __launch_bounds__(512) void k_scan2(int* __restrict__ bsum, int nb) {
    __shared__ int s[512];
    int t = threadIdx.x;
    int v = (t < nb) ? bsum[t] : 0;
    s[t] = v;
    __syncthreads();
    for (int off = 1; off < 512; off <<= 1) {
        int add = (t >= off) ? s[t - off] : 0;
        __syncthreads();
        s[t] += add;
        __syncthreads();
    }
    if (t < nb) bsum[t] = s[t] - v;  // exclusive
}

__global__ __launch_bounds__(256) void k_scan3(const int* __restrict__ cnt, int N,
                                               const int* __restrict__ bsum,
                                               int* __restrict__ offs) {
    __shared__ int s[256];
    int i = blockIdx.x * 256 + threadIdx.x;
    int v = (i < N) ? cnt[i] : 0;
    s[threadIdx.x] = v;
    __syncthreads();
    for (int off = 1; off < 256; off <<= 1) {
        int add = (threadIdx.x >= off) ? s[threadIdx.x - off] : 0;
        __syncthreads();
        s[threadIdx.x] += add;
        __syncthreads();
    }
    if (i < N) offs[i] = bsum[blockIdx.x] + s[threadIdx.x] - v;
}

__global__ __launch_bounds__(256) void k_deginv(const int* __restrict__ cnt,
                                                const int* __restrict__ offs, int N,
                                                float* __restrict__ deg_inv,
                                                int* __restrict__ cursor) {
    int i = blockIdx.x * 256 + threadIdx.x;
    if (i < N) {
        int c = cnt[i];
        deg_inv[i] = (c > 0) ? 1.0f / (float)c : 0.0f;
        cursor[i] = offs[i];
    }
}

__global__ __launch_bounds__(256) void k_scatter(const int* __restrict__ eb, int E,
                                                 const int* __restrict__ mode, int N,
                                                 int* __restrict__ cursor,
                                                 int* __restrict__ csr_src) {
    int m = *mode;
    int e = blockIdx.x * THREADS + threadIdx.x;
    if (e < E) {
        int c = edge_get(eb, E, m, 1, e);
        if ((unsigned)c < (unsigned)N) {
            int r = edge_get(eb, E, m, 0, e);
            if ((unsigned)r >= (unsigned)N) r = 0;
            int pos = atomicAdd(&cursor[c], 1);
            csr_src[pos] = r;
        }
    }
}

// ---------------------------------------------------------------- weight prep (bf16, transposed)
__global__ __launch_bounds__(256) void k_prep_wqk(const float* __restrict__ Wq,
                                                  const float* __restrict__ Wk,
                                                  unsigned short* __restrict__ WqkT) {
    int i = blockIdx.x * 256 + threadIdx.x;  // 512*128
    if (i < 512 * 128) {
        int oc = i >> 7, k = i & 127;
        float v = (oc < 256) ? Wq[k * 256 + oc] : Wk[k * 256 + (oc - 256)];
        WqkT[i] = f2bf(v);
    }
}

__global__ __launch_bounds__(256) void k_prep_wo(const float* __restrict__ Wo,
                                                 unsigned short* __restrict__ WoT) {
    int i = blockIdx.x * 256 + threadIdx.x;  // 1280*128
    if (i < 1280 * 128) {
        int r = i >> 7, j = i & 127;
        WoT[(size_t)j * 1280 + r] = f2bf(Wo[i]);
    }
}

__global__ __launch_bounds__(256) void k_kvsT(const float* __restrict__ kvs,
                                              unsigned short* __restrict__ kvsT) {
    int i = blockIdx.x * 256 + threadIdx.x;  // 2*128*128
    if (i < 32768) {
        int h = i >> 14, rem = i & 16383, c = rem >> 7, k = rem & 127;
        kvsT[i] = f2bf(kvs[h * 16384 + k * 128 + c]);
    }
}

// ---------------------------------------------------------------- Q/K proj + row L2-norm (MFMA)
// Block: 64 rows x 512 outcols. wave0=Q.h0, wave1=Q.h1, wave2=K.h0, wave3=K.h1
__global__ __launch_bounds__(256) void k_proj(const float* __restrict__ x,
                                              const unsigned short* __restrict__ WqkT,
                                              const float* __restrict__ bq,
                                              const float* __restrict__ bk,
                                              unsigned short* __restrict__ qs,
                                              unsigned short* __restrict__ ks,
                                              float* __restrict__ ks_sum, int N) {
    __shared__ unsigned short xs[64 * 128];
    const int t = threadIdx.x;
    const int n0 = blockIdx.x * 64;
#pragma unroll
    for (int i = 0; i < 4; i++) {
        int chunk = i * 256 + t;
        int r = chunk >> 4, c0 = (chunk & 15) * 8;
        float4 a0 = make_float4(0.f, 0.f, 0.f, 0.f), a1 = a0;
        if (n0 + r < N) {
            a0 = ld4f(&x[(size_t)(n0 + r) * 128 + c0]);
            a1 = ld4f(&x[(size_t)(n0 + r) * 128 + c0 + 4]);
        }
        short8 v = {(short)f2bf(a0.x), (short)f2bf(a0.y), (short)f2bf(a0.z), (short)f2bf(a0.w),
                    (short)f2bf(a1.x), (short)f2bf(a1.y), (short)f2bf(a1.z), (short)f2bf(a1.w)};
        int byte = r * 256 + ((c0 * 2) ^ ((r & 7) << 4));
        *reinterpret_cast<short8*>(reinterpret_cast<char*>(xs) + byte) = v;
    }
    __syncthreads();
    const int w = t >> 6, l = t & 63, lrow = l & 15, lhi = l >> 4;
    f32x4 acc[4][8];
    const f32x4 fz = {0.f, 0.f, 0.f, 0.f};
#pragma unroll
    for (int mt = 0; mt < 4; mt++)
#pragma unroll
        for (int nt = 0; nt < 8; nt++) acc[mt][nt] = fz;

    for (int kk = 0; kk < 4; kk++) {
        int kb = kk * 32 + lhi * 8;
        short8 af[4];
#pragma unroll
        for (int mt = 0; mt < 4; mt++) {
            int r = mt * 16 + lrow;
            af[mt] = *reinterpret_cast<const short8*>(
                reinterpret_cast<const char*>(xs) + r * 256 + ((kb * 2) ^ ((r & 7) << 4)));
        }
#pragma unroll
        for (int nt = 0; nt < 8; nt++) {
            int oc = w * 128 + nt * 16 + lrow;
            short8 bf = *reinterpret_cast<const short8*>(&WqkT[(size_t)oc * 128 + kb]);
#pragma unroll
            for (int mt = 0; mt < 4; mt++)
                acc[mt][nt] = __builtin_amdgcn_mfma_f32_16x16x32_bf16(af[mt], bf, acc[mt][nt], 0, 0, 0);
        }
    }
    // bias
#pragma unroll
    for (int nt = 0; nt < 8; nt++) {
        int oc = w * 128 + nt * 16 + lrow;
        float b = (oc < 256) ? bq[oc] : bk[oc - 256];
#pragma unroll
        for (int mt = 0; mt < 4; mt++)
#pragma unroll
            for (int reg = 0; reg < 4; reg++) acc[mt][nt][reg] += b;
    }
    // row-norm + store
    unsigned short* dst = (w < 2) ? qs : ks;
    const int hc = (w & 1) * 128;
    float colsum[8];
#pragma unroll
    for (int nt = 0; nt < 8; nt++) colsum[nt] = 0.f;
#pragma unroll
    for (int mt = 0; mt < 4; mt++) {
        float ss[4] = {0.f, 0.f, 0.f, 0.f};
#pragma unroll
        for (int nt = 0; nt < 8; nt++)
#pragma unroll
            for (int reg = 0; reg < 4; reg++) ss[reg] += acc[mt][nt][reg] * acc[mt][nt][reg];
#pragma unroll
        for (int m_ = 1; m_ < 16; m_ <<= 1)
#pragma unroll
            for (int reg = 0; reg < 4; reg++) ss[reg] += __shfl_xor(ss[reg], m_);
#pragma unroll
        for (int reg = 0; reg < 4; reg++) {
            int n = n0 + mt * 16 + lhi * 4 + reg;
            float rv = rsqrtf(ss[reg]);
            if (n < N) {
#pragma unroll
                for (int nt = 0; nt < 8; nt++) {
                    unsigned short ub = f2bf(acc[mt][nt][reg] * rv);
                    dst[(size_t)n * 256 + hc + nt * 16 + lrow] = ub;
                    colsum[nt] += bf2f(ub);
                }
            }
        }
    }
    if (w >= 2) {
#pragma unroll
        for (int nt = 0; nt < 8; nt++)
            atomicAdd(&ks_sum[hc + nt * 16 + lrow], colsum[nt]);
    }
}

// ---------------------------------------------------------------- den = qs . ks_sum + N
__global__ __launch_bounds__(256) void k_den(const unsigned short* __restrict__ qs,
                                             const float* __restrict__ ks_sum,
                                             float* __restrict__ den, int N) {
    int w = threadIdx.x >> 6, lane = threadIdx.x & 63;
    int n = blockIdx.x * 4 + w;
    if (n >= N) return;
    float4 q = ld4f(&qs[(size_t)n * 256 + lane * 4]);
    float4 kv = *reinterpret_cast<const float4*>(&ks_sum[lane * 4]);
    float s = q.x * kv.x + q.y * kv.y + q.z * kv.z + q.w * kv.w;
#pragma unroll
    for (int off = 1; off < 32; off <<= 1) s += __shfl_xor(s, off);
    if ((lane & 31) == 0) den[n * 2 + (lane >> 5)] = s + (float)N;
}

// ---------------------------------------------------------------- kvs = ks^T @ vs (split-K, atomic combine)
template <typename TV>
__global__ __launch_bounds__(256) void k_kvs(const unsigned short* __restrict__ ks,
                                             const TV* __restrict__ vs, int vstride, int vmask,
                                             float* __restrict__ kvs, float* __restrict__ vs_sum,
                                             int N) {
    __shared__ float ksb[32][64];
    __shared__ float vsb[32][64];
    const int t = threadIdx.x;
    const int combo = blockIdx.y;
    const int h = combo >> 2, ti = (combo >> 1) & 1, tj = combo & 1;
    const int rows_per = (N + 255) >> 8;
    int r0 = blockIdx.x * rows_per;
    int rend = min(r0 + rows_per, N);
    const int ir = t >> 4, jr = t & 15;
    const int i0 = ir * 4, j0 = jr * 4;
    const int kbase = h * 128 + ti * 64;
    const int vbase = h * 128 + tj * 64;
    const bool do_vsum = (ti == 0) && (ir == 0);

    float acc[4][4];
#pragma unroll
    for (int a = 0; a < 4; a++)
#pragma unroll
        for (int b = 0; b < 4; b++) acc[a][b] = 0.f;
    float vsum[4] = {0.f, 0.f, 0.f, 0.f};

    for (int c0 = r0; c0 < rend; c0 += 32) {
        int L = rend - c0;
        if (L > 32) L = 32;
#pragma unroll
        for (int i = 0; i < 4; i++) {
            int idx4 = i * 256 + t;
            int arr = idx4 >> 9;
            int rem = idx4 & 511;
            int ll = rem >> 4, c4 = (rem & 15) * 4;
            float4 v = make_float4(0.f, 0.f, 0.f, 0.f);
            if (ll < L) {
                if (arr == 0)
                    v = ld4f(&ks[(size_t)(c0 + ll) * 256 + kbase + c4]);
                else
                    v = ld4f(&vs[(size_t)(c0 + ll) * vstride + ((vbase + c4) & vmask)]);
            }
            if (arr == 0)
                *reinterpret_cast<float4*>(&ksb[ll][c4]) = v;
            else
                *reinterpret_cast<float4*>(&vsb[ll][c4]) = v;
        }
        __syncthreads();
#pragma unroll 4
        for (int ll = 0; ll < 32; ll++) {
            float4 kv = *reinterpret_cast<const float4*>(&ksb[ll][i0]);
            float4 vv = *reinterpret_cast<const float4*>(&vsb[ll][j0]);
            acc[0][0] += kv.x * vv.x; acc[0][1] += kv.x * vv.y; acc[0][2] += kv.x * vv.z; acc[0][3] += kv.x * vv.w;
            acc[1][0] += kv.y * vv.x; acc[1][1] += kv.y * vv.y; acc[1][2] += kv.y * vv.z; acc[1][3] += kv.y * vv.w;
            acc[2][0] += kv.z * vv.x; acc[2][1] += kv.z * vv.y; acc[2][2] += kv.z * vv.z; acc[2][3] += kv.z * vv.w;
            acc[3][0] += kv.w * vv.x; acc[3][1] += kv.w * vv.y; acc[3][2] += kv.w * vv.z; acc[3][3] += kv.w * vv.w;
            if (do_vsum) { vsum[0] += vv.x; vsum[1] += vv.y; vsum[2] += vv.z; vsum[3] += vv.w; }
        }
        __syncthreads();
    }
#pragma unroll
    for (int a = 0; a < 4; a++)
#pragma unroll
        for (int b = 0; b < 4; b++)
            atomicAdd(&kvs[h * 16384 + (ti * 64 + i0 + a) * 128 + tj * 64 + j0 + b], acc[a][b]);
    if (do_vsum) {
#pragma unroll
        for (int b = 0; b < 4; b++) atomicAdd(&vs_sum[h * 128 + tj * 64 + j0 + b], vsum[b]);
    }
}

// ---------------------------------------------------------------- GCN gather: cur = 0.5*deg_inv*sum prev[src]
template <typename TS>
__global__ __launch_bounds__(256) void k_gather(const TS* __restrict__ prev, int pstride, int pmask,
                                                const int* __restrict__ csr_src,
                                                const int* __restrict__ offs,
                                                const int* __restrict__ cnt,
                                                const float* __restrict__ deg_inv,
                                                unsigned short* __restrict__ cur, int N) {
    const int t = threadIdx.x;
    const int ch = t & pmask;
    int nbase = blockIdx.x * 8;
    for (int i = 0; i < 8; i++) {
        int n = nbase + i;
        if (n >= N) return;
        int start = offs[n], d = cnt[n];
        int e = start, eend = start + d;
        float acc = 0.f;
        for (; e + 4 <= eend; e += 4) {
            int s0 = csr_src[e], s1 = csr_src[e + 1], s2 = csr_src[e + 2], s3 = csr_src[e + 3];
            acc += ld1f(&prev[(size_t)s0 * pstride + ch]);
            acc += ld1f(&prev[(size_t)s1 * pstride + ch]);
            acc += ld1f(&prev[(size_t)s2 * pstride + ch]);
            acc += ld1f(&prev[(size_t)s3 * pstride + ch]);
        }
        for (; e < eend; e++) acc += ld1f(&prev[(size_t)csr_src[e] * pstride + ch]);
        cur[(size_t)n * 256 + t] = f2bf(0.5f * deg_inv[n] * acc);
    }
}

// ---------------------------------------------------------------- fused: cur += (qs@kvs+vs_sum)/den ; out += 0.5*cur@Wo_blk
// Block: 64 rows. phase1 waves: (h,jh) quadrants; phase3 waves: j-col strips.
__global__ __launch_bounds__(256) void k_att_out(const unsigned short* __restrict__ qs,
                                                 const unsigned short* __restrict__ kvsT,
                                                 const float* __restrict__ vs_sum,
                                                 const float* __restrict__ den,
                                                 unsigned short* __restrict__ cur,
                                                 const unsigned short* __restrict__ WoT,
                                                 float* __restrict__ out, int tblk, int N) {
    __shared__ unsigned short sm[64 * 256];
    const int t = threadIdx.x;
    const int n0 = blockIdx.x * 64;
    // stage qs tile (64 x 256), swizzled
#pragma unroll
    for (int i = 0; i < 8; i++) {
        int chunk = i * 256 + t;
        int r = chunk >> 5, c0 = (chunk & 31) * 8;
        short8 v = {0, 0, 0, 0, 0, 0, 0, 0};
        if (n0 + r < N) v = *reinterpret_cast<const short8*>(&qs[(size_t)(n0 + r) * 256 + c0]);
        *reinterpret_cast<short8*>(reinterpret_cast<char*>(sm) + r * 512 +
                                   ((c0 * 2) ^ ((r & 7) << 4))) = v;
    }
    __syncthreads();
    const int w = t >> 6, l = t & 63, lrow = l & 15, lhi = l >> 4;
    const int h = w >> 1, jh = w & 1;
    const f32x4 fz = {0.f, 0.f, 0.f, 0.f};
    f32x4 acc[4][4];
#pragma unroll
    for (int mt = 0; mt < 4; mt++)
#pragma unroll
        for (int nt = 0; nt < 4; nt++) acc[mt][nt] = fz;

    for (int kk = 0; kk < 4; kk++) {
        int kb = kk * 32 + lhi * 8;
        short8 af[4];
#pragma unroll
        for (int mt = 0; mt < 4; mt++) {
            int r = mt * 16 + lrow;
            af[mt] = *reinterpret_cast<const short8*>(
                reinterpret_cast<const char*>(sm) + r * 512 +
                (((h * 128 + kb) * 2) ^ ((r & 7) << 4)));
        }
#pragma unroll
        for (int nt = 0; nt < 4; nt++) {
            int c = jh * 64 + nt * 16 + lrow;
            short8 bf = *reinterpret_cast<const short8*>(&kvsT[((size_t)h * 128 + c) * 128 + kb]);
#pragma unroll
            for (int mt = 0; mt < 4; mt++)
                acc[mt][nt] = __builtin_amdgcn_mfma_f32_16x16x32_bf16(af[mt], bf, acc[mt][nt], 0, 0, 0);
        }
    }
    __syncthreads();  // done reading qs from sm
    // phase2: cur = gather + (attn + vs_sum)/den ; write back + stage into sm
#pragma unroll
    for (int mt = 0; mt < 4; mt++) {
#pragma unroll
        for (int reg = 0; reg < 4; reg++) {
            int r = mt * 16 + lhi * 4 + reg;
            int n = n0 + r;
            if (n < N) {
                float idn = 1.0f / den[n * 2 + h];
#pragma unroll
                for (int nt = 0; nt < 4; nt++) {
                    int c = h * 128 + jh * 64 + nt * 16 + lrow;
                    float g = bf2f(cur[(size_t)n * 256 + c]);
                    float v = g + (acc[mt][nt][reg] + vs_sum[c]) * idn;
                    unsigned short ub = f2bf(v);
                    cur[(size_t)n * 256 + c] = ub;
                    *reinterpret_cast<unsigned short*>(reinterpret_cast<char*>(sm) + r * 512 +
                                                       ((c * 2) ^ ((r & 7) << 4))) = ub;
                }
            }
        }
    }
    __syncthreads();
    // phase3: out += 0.5 * cur @ WoT(tblk), wave w covers j in [w*32, w*32+32)
    f32x4 acc2[4][2];
#pragma unroll
    for (int mt = 0; mt < 4; mt++)
#pragma unroll
        for (int nt = 0; nt < 2; nt++) acc2[mt][nt] = fz;
    for (int kk = 0; kk < 8; kk++) {
        int kb = kk * 32 + lhi * 8;
        short8 af[4];
#pragma unroll
        for (int mt = 0; mt < 4; mt++) {
            int r = mt * 16 + lrow;
            af[mt] = *reinterpret_cast<const short8*>(
                reinterpret_cast<const char*>(sm) + r * 512 + ((kb * 2) ^ ((r & 7) << 4)));
        }
        int woff = (kb >> 7) * 640 + tblk * 128 + (kb & 127);
#pragma unroll
        for (int nt = 0; nt < 2; nt++) {
            int j = w * 32 + nt * 16 + lrow;
            short8 bf = *reinterpret_cast<const short8*>(&WoT[(size_t)j * 1280 + woff]);
#pragma unroll
            for (int mt = 0; mt < 4; mt++)
                acc2[mt][nt] = __builtin_amdgcn_mfma_f32_16x16x32_bf16(af[mt], bf, acc2[mt][nt], 0, 0, 0);
        }
    }
#pragma unroll
    for (int nt = 0; nt < 2; nt++) {
        int j = w * 32 + nt * 16 + lrow;
#pragma unroll
        for (int mt = 0; mt < 4; mt++)
#pragma unroll
            for (int reg = 0; reg < 4; reg++) {
                int n = n0 + mt * 16 + lhi * 4 + reg;
                if (n < N) out[(size_t)n * 128 + j] += 0.5f * acc2[mt][nt][reg];
            }
    }
}

// ---------------------------------------------------------------- term0: out = 0.5*([x|x]@Wo_0 + bias)
__global__ __launch_bounds__(256) void k_out0(const float* __restrict__ x,
                                              const unsigned short* __restrict__ WoT,
                                              const float* __restrict__ Wo_b,
                                              float* __restrict__ out, int N) {
    __shared__ unsigned short sm[64 * 256];
    const int t = threadIdx.x;
    const int n0 = blockIdx.x * 64;
#pragma unroll
    for (int i = 0; i < 8; i++) {
        int chunk = i * 256 + t;
        int r = chunk >> 5, c0 = (chunk & 31) * 8, cs = c0 & 127;
        float4 a0 = make_float4(0.f, 0.f, 0.f, 0.f), a1 = a0;
        if (n0 + r < N) {
            a0 = ld4f(&x[(size_t)(n0 + r) * 128 + cs]);
            a1 = ld4f(&x[(size_t)(n0 + r) * 128 + cs + 4]);
        }
        short8 v = {(short)f2bf(a0.x), (short)f2bf(a0.y), (short)f2bf(a0.z), (short)f2bf(a0.w),
                    (short)f2bf(a1.x), (short)f2bf(a1.y), (short)f2bf(a1.z), (short)f2bf(a1.w)};
        *reinterpret_cast<short8*>(reinterpret_cast<char*>(sm) + r * 512 +
                                   ((c0 * 2) ^ ((r & 7) << 4))) = v;
    }
    __syncthreads();
    const int w = t >> 6, l = t & 63, lrow = l & 15, lhi = l >> 4;
    const f32x4 fz = {0.f, 0.f, 0.f, 0.f};
    f32x4 acc2[4][2];
#pragma unroll
    for (int mt = 0; mt < 4; mt++)
#pragma unroll
        for (int nt = 0; nt < 2; nt++) acc2[mt][nt] = fz;
    for (int kk = 0; kk < 8; kk++) {
        int kb = kk * 32 + lhi * 8;
        short8 af[4];
#pragma unroll
        for (int mt = 0; mt < 4; mt++) {
            int r = mt * 16 + lrow;
            af[mt] = *reinterpret_cast<const short8*>(
                reinterpret_cast<const char*>(sm) + r * 512 + ((kb * 2) ^ ((r & 7) << 4)));
        }
        int woff = (kb >> 7) * 640 + (kb & 127);  // tblk = 0
#pragma unroll
        for (int nt = 0; nt < 2; nt++) {
            int j = w * 32 + nt * 16 + lrow;
            short8 bf = *reinterpret_cast<const short8*>(&WoT[(size_t)j * 1280 + woff]);
#pragma unroll
            for (int mt = 0; mt < 4; mt++)
                acc2[mt][nt] = __builtin_amdgcn_mfma_f32_16x16x32_bf16(af[mt], bf, acc2[mt][nt], 0, 0, 0);
        }
    }
#pragma unroll
    for (int nt = 0; nt < 2; nt++) {
        int j = w * 32 + nt * 16 + lrow;
        float b = Wo_b[j];
#pragma unroll
        for (int mt = 0; mt < 4; mt++)
#pragma unroll
            for (int reg = 0; reg < 4; reg++) {
                int n = n0 + mt * 16 + lhi * 4 + reg;
                if (n < N) out[(size_t)n * 128 + j] = 0.5f * (acc2[mt][nt][reg] + b);
            }
    }
}

// ================================================================ host
extern "C" void kernel_launch(void* const* d_in, const int* in_sizes, int n_in,
                              void* d_out, int out_size, void* d_ws, size_t ws_size,
                              hipStream_t stream) {
    const int N = in_sizes[0] / 128;
    const int E = in_sizes[1] / 2;
    const float* x = (const float*)d_in[0];
    const int* eraw = (const int*)d_in[1];
    const float* Wq_w = (const float*)d_in[2];
    const float* Wq_b = (const float*)d_in[3];
    const float* Wk_w = (const float*)d_in[4];
    const float* Wk_b = (const float*)d_in[5];
    const float* Wo_w = (const float*)d_in[6];
    const float* Wo_b = (const float*)d_in[7];
    float* out = (float*)d_out;

    char* p = (char*)d_ws;
    auto alloc = [&](size_t bytes) -> void* {
        void* r = (void*)p;
        p += (bytes + 255) & ~(size_t)255;
        return r;
    };
    unsigned short* qs = (unsigned short*)alloc((size_t)N * 256 * 2);
    unsigned short* ks = (unsigned short*)alloc((size_t)N * 256 * 2);
    unsigned short* bufA = (unsigned short*)alloc((size_t)N * 256 * 2);
    unsigned short* bufB = (unsigned short*)alloc((size_t)N * 256 * 2);
    float* deg_inv = (float*)alloc((size_t)N * 4);
    float* den = (float*)alloc((size_t)N * 2 * 4);
    float* kvs = (float*)alloc((size_t)(2 * 128 * 128 + 256) * 4);  // + vs_sum tail
    float* ks_sum = (float*)alloc(256 * 4);
    unsigned short* WqkT = (unsigned short*)alloc(512 * 128 * 2);
    unsigned short* WoT = (unsigned short*)alloc(1280 * 128 * 2);
    unsigned short* kvsTb = (unsigned short*)alloc(32768 * 2);
    int* cnt = (int*)alloc((size_t)N * 4);
    int* offs = (int*)alloc((size_t)N * 4);
    int* cursor = (int*)alloc((size_t)N * 4);
    int* bsum = (int*)alloc(512 * 4);
    int* mode = (int*)alloc(256);
    int* csr = (int*)alloc((size_t)E * 4);

    hipMemsetAsync(cnt, 0, (size_t)N * 4, stream);
    hipMemsetAsync(ks_sum, 0, 256 * 4, stream);

    const int nb = (N + 255) / 256;
    const int eb = (E + 255) / 256;
    k_detect<<<1, 256, 0, stream>>>(eraw, E, mode);
    k_count<<<eb, 256, 0, stream>>>(eraw, E, mode, N, cnt);
    k_scan1<<<nb, 256, 0, stream>>>(cnt, N, bsum);
    k_scan2<<<1, 512, 0, stream>>>(bsum, nb);
    k_scan3<<<nb, 256, 0, stream>>>(cnt, N, bsum, offs);
    k_deginv<<<nb, 256, 0, stream>>>(cnt, offs, N, deg_inv, cursor);
    k_scatter<<<eb, 256, 0, stream>>>(eraw, E, mode, N, cursor, csr);

    k_prep_wqk<<<256, 256, 0, stream>>>(Wq_w, Wk_w, WqkT);
    k_prep_wo<<<640, 256, 0, stream>>>(Wo_w, WoT);

    const int nb64 = (N + 63) / 64;
    k_proj<<<nb64, 256, 0, stream>>>(x, WqkT, Wq_b, Wk_b, qs, ks, ks_sum, N);
    k_den<<<(N + 3) / 4, 256, 0, stream>>>(qs, ks_sum, den, N);
    k_out0<<<nb64, 256, 0, stream>>>(x, WoT, Wo_b, out, N);

    const size_t kvs_bytes = (size_t)(2 * 128 * 128 + 256) * 4;
    dim3 g1(256, 8);
    const int gb = (N + 7) / 8;

    // hop 1: prev = x (f32, stride 128, head-broadcast)
    hipMemsetAsync(kvs, 0, kvs_bytes, stream);
    k_kvs<float><<<g1, 256, 0, stream>>>(ks, x, 128, 127, kvs, kvs + 32768, N);
    k_kvsT<<<128, 256, 0, stream>>>(kvs, kvsTb);
    k_gather<float><<<gb, 256, 0, stream>>>(x, 128, 127, csr, offs, cnt, deg_inv, bufA, N);
    k_att_out<<<nb64, 256, 0, stream>>>(qs, kvsTb, kvs + 32768, den, bufA, WoT, out, 1, N);

    // hops 2..4
    unsigned short* prev = bufA;
    unsigned short* cur = bufB;
    for (int step = 2; step <= 4; step++) {
        hipMemsetAsync(kvs, 0, kvs_bytes, stream);
        k_kvs<unsigned short><<<g1, 256, 0, stream>>>(ks, prev, 256, 255, kvs, kvs + 32768, N);
        k_kvsT<<<128, 256, 0, stream>>>(kvs, kvsTb);
        k_gather<unsigned short><<<gb, 256, 0, stream>>>(prev, 256, 255, csr, offs, cnt, deg_inv,
                                                         cur, N);
        k_att_out<<<nb64, 256, 0, stream>>>(qs, kvsTb, kvs + 32768, den, cur, WoT, out, step, N);
        unsigned short* tmp = prev;
        prev = cur;
        cur = tmp;
    }
}

// Round 4
// 2387.149 us; speedup vs baseline: 1.2770x; 1.1352x over previous
//
#include <hip/hip_runtime.h>

#define THREADS 256

typedef __attribute__((ext_vector_type(8))) short short8;
typedef __attribute__((ext_vector_type(4))) float f32x4;

// ---------------------------------------------------------------- bf16 helpers (raw ushort storage)
__device__ __forceinline__ float bf2f(unsigned short u) {
    union { unsigned int i; float f; } v;
    v.i = ((unsigned int)u) << 16;
    return v.f;
}
__device__ __forceinline__ unsigned short f2bf(float f) {
    union { float f; unsigned int i; } v;
    v.f = f;
    unsigned int r = (v.i + 0x7FFFu + ((v.i >> 16) & 1u)) >> 16;  // RNE
    return (unsigned short)r;
}
__device__ __forceinline__ float4 ld4f(const float* p) {
    return *reinterpret_cast<const float4*>(p);
}
__device__ __forceinline__ float4 ld4f(const unsigned short* p) {
    ushort4 u = *reinterpret_cast<const ushort4*>(p);
    return make_float4(bf2f(u.x), bf2f(u.y), bf2f(u.z), bf2f(u.w));
}
__device__ __forceinline__ float ld1f(const float* p) { return *p; }
__device__ __forceinline__ float ld1f(const unsigned short* p) { return bf2f(*p); }

// ---------------------------------------------------------------- edge accessor (int32 or int64 payload)
__device__ __forceinline__ int edge_get(const int* base, int E, int mode, int which, int e) {
    size_t idx = (size_t)which * (size_t)E + (size_t)e;
    return mode ? base[2 * idx] : base[idx];
}

__global__ __launch_bounds__(256) void k_detect(const int* __restrict__ e, int E,
                                                int* __restrict__ mode) {
    __shared__ int nz;
    if (threadIdx.x == 0) nz = 0;
    __syncthreads();
    int lim = 2 * E;
    if (lim > 8192) lim = 8192;
    for (int i = 1 + 2 * (int)threadIdx.x; i < lim; i += 512)
        if (e[i] != 0) nz = 1;
    __syncthreads();
    if (threadIdx.x == 0) *mode = (nz == 0) ? 1 : 0;
}

// ---------------------------------------------------------------- graph prep
__global__ __launch_bounds__(256) void k_count(const int* __restrict__ eb, int E,
                                               const int* __restrict__ mode, int N,
                                               int* __restrict__ cnt) {
    int m = *mode;
    int e = blockIdx.x * THREADS + threadIdx.x;
    if (e < E) {
        int c = edge_get(eb, E, m, 1, e);
        if ((unsigned)c < (unsigned)N) atomicAdd(&cnt[c], 1);
    }
}

__global__ __launch_bounds__(256) void k_scan1(const int* __restrict__ cnt, int N,
                                               int* __restrict__ bsum) {
    __shared__ int s[256];
    int i = blockIdx.x * 256 + threadIdx.x;
    s[threadIdx.x] = (i < N) ? cnt[i] : 0;
    __syncthreads();
    for (int off = 128; off > 0; off >>= 1) {
        if (threadIdx.x < off) s[threadIdx.x] += s[threadIdx.x + off];
        __syncthreads();
    }
    if (threadIdx.x == 0) bsum[blockIdx.x] = s[0];
}

__global__ __launch_bounds__(512) void k_scan2(int* __restrict__ bsum, int nb) {
    __shared__ int s[512];
    int t = threadIdx.x;
    int v = (t < nb) ? bsum[t] : 0;
    s[t] = v;
    __syncthreads();
    for (int off = 1; off < 512; off <<= 1) {
        int add = (t >= off) ? s[t - off] : 0;
        __syncthreads();
        s[t] += add;
        __syncthreads();
    }
    if (t < nb) bsum[t] = s[t] - v;  // exclusive
}

__global__ __launch_bounds__(256) void k_scan3(const int* __restrict__ cnt, int N,
                                               const int* __restrict__ bsum,
                                               int* __restrict__ offs) {
    __shared__ int s[256];
    int i = blockIdx.x * 256 + threadIdx.x;
    int v = (i < N) ? cnt[i] : 0;
    s[threadIdx.x] = v;
    __syncthreads();
    for (int off = 1; off < 256; off <<= 1) {
        int add = (threadIdx.x >= off) ? s[threadIdx.x - off] : 0;
        __syncthreads();
        s[threadIdx.x] += add;
        __syncthreads();
    }
    if (i < N) offs[i] = bsum[blockIdx.x] + s[threadIdx.x] - v;
}

__global__ __launch_bounds__(256) void k_deginv(const int* __restrict__ cnt,
                                                const int* __restrict__ offs, int N,
                                                float* __restrict__ deg_inv,
                                                int* __restrict__ cursor) {
    int i = blockIdx.x * 256 + threadIdx.x;
    if (i < N) {
        int c = cnt[i];
        deg_inv[i] = (c > 0) ? 1.0f / (float)c : 0.0f;
        cursor[i] = offs[i];
    }
}

__global__ __launch_bounds__(256) void k_scatter(const int* __restrict__ eb, int E,
                                                 const int* __restrict__ mode, int N,
                                                 int* __restrict__ cursor,
                                                 int* __restrict__ csr_src) {
    int m = *mode;
    int e = blockIdx.x * THREADS + threadIdx.x;
    if (e < E) {
        int c = edge_get(eb, E, m, 1, e);
        if ((unsigned)c < (unsigned)N) {
            int r = edge_get(eb, E, m, 0, e);
            if ((unsigned)r >= (unsigned)N) r = 0;
            int pos = atomicAdd(&cursor[c], 1);
            csr_src[pos] = r;
        }
    }
}

// ---------------------------------------------------------------- weight prep (bf16, transposed)
__global__ __launch_bounds__(256) void k_prep_wqk(const float* __restrict__ Wq,
                                                  const float* __restrict__ Wk,
                                                  unsigned short* __restrict__ WqkT) {
    int i = blockIdx.x * 256 + threadIdx.x;  // 512*128
    if (i < 512 * 128) {
        int oc = i >> 7, k = i & 127;
        float v = (oc < 256) ? Wq[k * 256 + oc] : Wk[k * 256 + (oc - 256)];
        WqkT[i] = f2bf(v);
    }
}

__global__ __launch_bounds__(256) void k_prep_wo(const float* __restrict__ Wo,
                                                 unsigned short* __restrict__ WoT) {
    int i = blockIdx.x * 256 + threadIdx.x;  // 1280*128
    if (i < 1280 * 128) {
        int r = i >> 7, j = i & 127;
        WoT[(size_t)j * 1280 + r] = f2bf(Wo[i]);
    }
}

__global__ __launch_bounds__(256) void k_kvsT(const float* __restrict__ kvs,
                                              unsigned short* __restrict__ kvsT) {
    int i = blockIdx.x * 256 + threadIdx.x;  // 2*128*128
    if (i < 32768) {
        int h = i >> 14, rem = i & 16383, c = rem >> 7, k = rem & 127;
        kvsT[i] = f2bf(kvs[h * 16384 + k * 128 + c]);
    }
}

// ---------------------------------------------------------------- Q/K proj + row L2-norm (MFMA, atomic-free)
// Block: 64 rows x 512 outcols. wave0=Q.h0, wave1=Q.h1, wave2=K.h0, wave3=K.h1
__global__ __launch_bounds__(256) void k_proj(const float* __restrict__ x,
                                              const unsigned short* __restrict__ WqkT,
                                              const float* __restrict__ bq,
                                              const float* __restrict__ bk,
                                              unsigned short* __restrict__ qs,
                                              unsigned short* __restrict__ ks, int N) {
    __shared__ unsigned short xs[64 * 128];  // 16 KB input staging
    __shared__ unsigned short os[64 * 256];  // 32 KB output staging
    const int t = threadIdx.x;
    const int n0 = blockIdx.x * 64;
#pragma unroll
    for (int i = 0; i < 4; i++) {
        int chunk = i * 256 + t;
        int r = chunk >> 4, c0 = (chunk & 15) * 8;
        float4 a0 = make_float4(0.f, 0.f, 0.f, 0.f), a1 = a0;
        if (n0 + r < N) {
            a0 = ld4f(&x[(size_t)(n0 + r) * 128 + c0]);
            a1 = ld4f(&x[(size_t)(n0 + r) * 128 + c0 + 4]);
        }
        short8 v = {(short)f2bf(a0.x), (short)f2bf(a0.y), (short)f2bf(a0.z), (short)f2bf(a0.w),
                    (short)f2bf(a1.x), (short)f2bf(a1.y), (short)f2bf(a1.z), (short)f2bf(a1.w)};
        int byte = r * 256 + ((c0 * 2) ^ ((r & 7) << 4));
        *reinterpret_cast<short8*>(reinterpret_cast<char*>(xs) + byte) = v;
    }
    __syncthreads();
    const int w = t >> 6, l = t & 63, lrow = l & 15, lhi = l >> 4;
    f32x4 acc[4][8];
    const f32x4 fz = {0.f, 0.f, 0.f, 0.f};
#pragma unroll
    for (int mt = 0; mt < 4; mt++)
#pragma unroll
        for (int nt = 0; nt < 8; nt++) acc[mt][nt] = fz;

    for (int kk = 0; kk < 4; kk++) {
        int kb = kk * 32 + lhi * 8;
        short8 af[4];
#pragma unroll
        for (int mt = 0; mt < 4; mt++) {
            int r = mt * 16 + lrow;
            af[mt] = *reinterpret_cast<const short8*>(
                reinterpret_cast<const char*>(xs) + r * 256 + ((kb * 2) ^ ((r & 7) << 4)));
        }
#pragma unroll
        for (int nt = 0; nt < 8; nt++) {
            int oc = w * 128 + nt * 16 + lrow;
            short8 bf = *reinterpret_cast<const short8*>(&WqkT[(size_t)oc * 128 + kb]);
#pragma unroll
            for (int mt = 0; mt < 4; mt++)
                acc[mt][nt] = __builtin_amdgcn_mfma_f32_16x16x32_bf16(af[mt], bf, acc[mt][nt], 0, 0, 0);
        }
    }
    // bias
#pragma unroll
    for (int nt = 0; nt < 8; nt++) {
        int oc = w * 128 + nt * 16 + lrow;
        float b = (oc < 256) ? bq[oc] : bk[oc - 256];
#pragma unroll
        for (int mt = 0; mt < 4; mt++)
#pragma unroll
            for (int reg = 0; reg < 4; reg++) acc[mt][nt][reg] += b;
    }
    // row-norm in registers
    const int hc = (w & 1) * 128;
    float rv[4][4];
#pragma unroll
    for (int mt = 0; mt < 4; mt++) {
        float ss[4] = {0.f, 0.f, 0.f, 0.f};
#pragma unroll
        for (int nt = 0; nt < 8; nt++)
#pragma unroll
            for (int reg = 0; reg < 4; reg++) ss[reg] += acc[mt][nt][reg] * acc[mt][nt][reg];
#pragma unroll
        for (int m_ = 1; m_ < 16; m_ <<= 1)
#pragma unroll
            for (int reg = 0; reg < 4; reg++) ss[reg] += __shfl_xor(ss[reg], m_);
#pragma unroll
        for (int reg = 0; reg < 4; reg++) rv[mt][reg] = rsqrtf(ss[reg]);
    }
    // two passes: pass0 waves 0,1 (q) -> os -> coalesced global; pass1 waves 2,3 (k)
    for (int pass = 0; pass < 2; pass++) {
        if ((w >> 1) == pass) {
#pragma unroll
            for (int mt = 0; mt < 4; mt++)
#pragma unroll
                for (int reg = 0; reg < 4; reg++) {
                    int r = mt * 16 + lhi * 4 + reg;
#pragma unroll
                    for (int nt = 0; nt < 8; nt++)
                        os[r * 256 + hc + nt * 16 + lrow] = f2bf(acc[mt][nt][reg] * rv[mt][reg]);
                }
        }
        __syncthreads();
        unsigned short* dstg = pass ? ks : qs;
#pragma unroll
        for (int i = 0; i < 8; i++) {
            int chunk = i * 256 + t;
            int r = chunk >> 5, c = (chunk & 31) * 8;
            int n = n0 + r;
            if (n < N)
                *reinterpret_cast<short8*>(&dstg[(size_t)n * 256 + c]) =
                    *reinterpret_cast<const short8*>(&os[r * 256 + c]);
        }
        __syncthreads();
    }
}

// ---------------------------------------------------------------- ks_sum: 2-stage column reduction
__global__ __launch_bounds__(256) void k_colsum(const unsigned short* __restrict__ ks, int N,
                                                float* __restrict__ part) {
    const int t = threadIdx.x;
    const int stride = (N + 255) >> 8;
    int r0 = blockIdx.x * stride;
    int rend = min(r0 + stride, N);
    float s = 0.f;
    for (int n = r0; n < rend; n++) s += bf2f(ks[(size_t)n * 256 + t]);
    part[blockIdx.x * 256 + t] = s;
}

__global__ __launch_bounds__(256) void k_colsum2(const float* __restrict__ part,
                                                 float* __restrict__ ks_sum) {
    const int t = threadIdx.x;
    float s = 0.f;
    for (int b = 0; b < 256; b++) s += part[b * 256 + t];
    ks_sum[t] = s;
}

// ---------------------------------------------------------------- den = qs . ks_sum + N
__global__ __launch_bounds__(256) void k_den(const unsigned short* __restrict__ qs,
                                             const float* __restrict__ ks_sum,
                                             float* __restrict__ den, int N) {
    int w = threadIdx.x >> 6, lane = threadIdx.x & 63;
    int n = blockIdx.x * 4 + w;
    if (n >= N) return;
    float4 q = ld4f(&qs[(size_t)n * 256 + lane * 4]);
    float4 kv = *reinterpret_cast<const float4*>(&ks_sum[lane * 4]);
    float s = q.x * kv.x + q.y * kv.y + q.z * kv.z + q.w * kv.w;
#pragma unroll
    for (int off = 1; off < 32; off <<= 1) s += __shfl_xor(s, off);
    if ((lane & 31) == 0) den[n * 2 + (lane >> 5)] = s + (float)N;
}

// ---------------------------------------------------------------- kvs = ks^T @ vs (split-K, atomic combine)
template <typename TV>
__global__ __launch_bounds__(256) void k_kvs(const unsigned short* __restrict__ ks,
                                             const TV* __restrict__ vs, int vstride, int vmask,
                                             float* __restrict__ kvs, float* __restrict__ vs_sum,
                                             int N) {
    __shared__ float ksb[32][64];
    __shared__ float vsb[32][64];
    const int t = threadIdx.x;
    const int combo = blockIdx.y;
    const int h = combo >> 2, ti = (combo >> 1) & 1, tj = combo & 1;
    const int rows_per = (N + 255) >> 8;
    int r0 = blockIdx.x * rows_per;
    int rend = min(r0 + rows_per, N);
    const int ir = t >> 4, jr = t & 15;
    const int i0 = ir * 4, j0 = jr * 4;
    const int kbase = h * 128 + ti * 64;
    const int vbase = h * 128 + tj * 64;
    const bool do_vsum = (ti == 0) && (ir == 0);

    float acc[4][4];
#pragma unroll
    for (int a = 0; a < 4; a++)
#pragma unroll
        for (int b = 0; b < 4; b++) acc[a][b] = 0.f;
    float vsum[4] = {0.f, 0.f, 0.f, 0.f};

    for (int c0 = r0; c0 < rend; c0 += 32) {
        int L = rend - c0;
        if (L > 32) L = 32;
#pragma unroll
        for (int i = 0; i < 4; i++) {
            int idx4 = i * 256 + t;
            int arr = idx4 >> 9;
            int rem = idx4 & 511;
            int ll = rem >> 4, c4 = (rem & 15) * 4;
            float4 v = make_float4(0.f, 0.f, 0.f, 0.f);
            if (ll < L) {
                if (arr == 0)
                    v = ld4f(&ks[(size_t)(c0 + ll) * 256 + kbase + c4]);
                else
                    v = ld4f(&vs[(size_t)(c0 + ll) * vstride + ((vbase + c4) & vmask)]);
            }
            if (arr == 0)
                *reinterpret_cast<float4*>(&ksb[ll][c4]) = v;
            else
                *reinterpret_cast<float4*>(&vsb[ll][c4]) = v;
        }
        __syncthreads();
#pragma unroll 4
        for (int ll = 0; ll < 32; ll++) {
            float4 kv = *reinterpret_cast<const float4*>(&ksb[ll][i0]);
            float4 vv = *reinterpret_cast<const float4*>(&vsb[ll][j0]);
            acc[0][0] += kv.x * vv.x; acc[0][1] += kv.x * vv.y; acc[0][2] += kv.x * vv.z; acc[0][3] += kv.x * vv.w;
            acc[1][0] += kv.y * vv.x; acc[1][1] += kv.y * vv.y; acc[1][2] += kv.y * vv.z; acc[1][3] += kv.y * vv.w;
            acc[2][0] += kv.z * vv.x; acc[2][1] += kv.z * vv.y; acc[2][2] += kv.z * vv.z; acc[2][3] += kv.z * vv.w;
            acc[3][0] += kv.w * vv.x; acc[3][1] += kv.w * vv.y; acc[3][2] += kv.w * vv.z; acc[3][3] += kv.w * vv.w;
            if (do_vsum) { vsum[0] += vv.x; vsum[1] += vv.y; vsum[2] += vv.z; vsum[3] += vv.w; }
        }
        __syncthreads();
    }
#pragma unroll
    for (int a = 0; a < 4; a++)
#pragma unroll
        for (int b = 0; b < 4; b++)
            atomicAdd(&kvs[h * 16384 + (ti * 64 + i0 + a) * 128 + tj * 64 + j0 + b], acc[a][b]);
    if (do_vsum) {
#pragma unroll
        for (int b = 0; b < 4; b++) atomicAdd(&vs_sum[h * 128 + tj * 64 + j0 + b], vsum[b]);
    }
}

// ---------------------------------------------------------------- GCN gather: cur = 0.5*deg_inv*sum prev[src]
template <typename TS>
__global__ __launch_bounds__(256) void k_gather(const TS* __restrict__ prev, int pstride, int pmask,
                                                const int* __restrict__ csr_src,
                                                const int* __restrict__ offs,
                                                const int* __restrict__ cnt,
                                                const float* __restrict__ deg_inv,
                                                unsigned short* __restrict__ cur, int N) {
    const int t = threadIdx.x;
    const int ch = t & pmask;
    int nbase = blockIdx.x * 8;
    for (int i = 0; i < 8; i++) {
        int n = nbase + i;
        if (n >= N) return;
        int start = offs[n], d = cnt[n];
        int e = start, eend = start + d;
        float acc = 0.f;
        for (; e + 4 <= eend; e += 4) {
            int s0 = csr_src[e], s1 = csr_src[e + 1], s2 = csr_src[e + 2], s3 = csr_src[e + 3];
            acc += ld1f(&prev[(size_t)s0 * pstride + ch]);
            acc += ld1f(&prev[(size_t)s1 * pstride + ch]);
            acc += ld1f(&prev[(size_t)s2 * pstride + ch]);
            acc += ld1f(&prev[(size_t)s3 * pstride + ch]);
        }
        for (; e < eend; e++) acc += ld1f(&prev[(size_t)csr_src[e] * pstride + ch]);
        cur[(size_t)n * 256 + t] = f2bf(0.5f * deg_inv[n] * acc);
    }
}

// ---------------------------------------------------------------- fused: cur += (qs@kvs+vs_sum)/den ; out += 0.5*cur@Wo_blk
__global__ __launch_bounds__(256) void k_att_out(const unsigned short* __restrict__ qs,
                                                 const unsigned short* __restrict__ kvsT,
                                                 const float* __restrict__ vs_sum,
                                                 const float* __restrict__ den,
                                                 unsigned short* __restrict__ cur,
                                                 const unsigned short* __restrict__ WoT,
                                                 float* __restrict__ out, int tblk, int N) {
    __shared__ unsigned short sm[64 * 256];
    const int t = threadIdx.x;
    const int n0 = blockIdx.x * 64;
    // stage qs tile (64 x 256), swizzled
#pragma unroll
    for (int i = 0; i < 8; i++) {
        int chunk = i * 256 + t;
        int r = chunk >> 5, c0 = (chunk & 31) * 8;
        short8 v = {0, 0, 0, 0, 0, 0, 0, 0};
        if (n0 + r < N) v = *reinterpret_cast<const short8*>(&qs[(size_t)(n0 + r) * 256 + c0]);
        *reinterpret_cast<short8*>(reinterpret_cast<char*>(sm) + r * 512 +
                                   ((c0 * 2) ^ ((r & 7) << 4))) = v;
    }
    __syncthreads();
    const int w = t >> 6, l = t & 63, lrow = l & 15, lhi = l >> 4;
    const int h = w >> 1, jh = w & 1;
    const f32x4 fz = {0.f, 0.f, 0.f, 0.f};
    f32x4 acc[4][4];
#pragma unroll
    for (int mt = 0; mt < 4; mt++)
#pragma unroll
        for (int nt = 0; nt < 4; nt++) acc[mt][nt] = fz;

    for (int kk = 0; kk < 4; kk++) {
        int kb = kk * 32 + lhi * 8;
        short8 af[4];
#pragma unroll
        for (int mt = 0; mt < 4; mt++) {
            int r = mt * 16 + lrow;
            af[mt] = *reinterpret_cast<const short8*>(
                reinterpret_cast<const char*>(sm) + r * 512 +
                (((h * 128 + kb) * 2) ^ ((r & 7) << 4)));
        }
#pragma unroll
        for (int nt = 0; nt < 4; nt++) {
            int c = jh * 64 + nt * 16 + lrow;
            short8 bf = *reinterpret_cast<const short8*>(&kvsT[((size_t)h * 128 + c) * 128 + kb]);
#pragma unroll
            for (int mt = 0; mt < 4; mt++)
                acc[mt][nt] = __builtin_amdgcn_mfma_f32_16x16x32_bf16(af[mt], bf, acc[mt][nt], 0, 0, 0);
        }
    }
    __syncthreads();  // done reading qs from sm
    // phase2: cur = gather + (attn + vs_sum)/den ; write back + stage into sm
#pragma unroll
    for (int mt = 0; mt < 4; mt++) {
#pragma unroll
        for (int reg = 0; reg < 4; reg++) {
            int r = mt * 16 + lhi * 4 + reg;
            int n = n0 + r;
            if (n < N) {
                float idn = 1.0f / den[n * 2 + h];
#pragma unroll
                for (int nt = 0; nt < 4; nt++) {
                    int c = h * 128 + jh * 64 + nt * 16 + lrow;
                    float g = bf2f(cur[(size_t)n * 256 + c]);
                    float v = g + (acc[mt][nt][reg] + vs_sum[c]) * idn;
                    unsigned short ub = f2bf(v);
                    cur[(size_t)n * 256 + c] = ub;
                    *reinterpret_cast<unsigned short*>(reinterpret_cast<char*>(sm) + r * 512 +
                                                       ((c * 2) ^ ((r & 7) << 4))) = ub;
                }
            }
        }
    }
    __syncthreads();
    // phase3: out += 0.5 * cur @ WoT(tblk), wave w covers j in [w*32, w*32+32)
    f32x4 acc2[4][2];
#pragma unroll
    for (int mt = 0; mt < 4; mt++)
#pragma unroll
        for (int nt = 0; nt < 2; nt++) acc2[mt][nt] = fz;
    for (int kk = 0; kk < 8; kk++) {
        int kb = kk * 32 + lhi * 8;
        short8 af[4];
#pragma unroll
        for (int mt = 0; mt < 4; mt++) {
            int r = mt * 16 + lrow;
            af[mt] = *reinterpret_cast<const short8*>(
                reinterpret_cast<const char*>(sm) + r * 512 + ((kb * 2) ^ ((r & 7) << 4)));
        }
        int woff = (kb >> 7) * 640 + tblk * 128 + (kb & 127);
#pragma unroll
        for (int nt = 0; nt < 2; nt++) {
            int j = w * 32 + nt * 16 + lrow;
            short8 bf = *reinterpret_cast<const short8*>(&WoT[(size_t)j * 1280 + woff]);
#pragma unroll
            for (int mt = 0; mt < 4; mt++)
                acc2[mt][nt] = __builtin_amdgcn_mfma_f32_16x16x32_bf16(af[mt], bf, acc2[mt][nt], 0, 0, 0);
        }
    }
#pragma unroll
    for (int nt = 0; nt < 2; nt++) {
        int j = w * 32 + nt * 16 + lrow;
#pragma unroll
        for (int mt = 0; mt < 4; mt++)
#pragma unroll
            for (int reg = 0; reg < 4; reg++) {
                int n = n0 + mt * 16 + lhi * 4 + reg;
                if (n < N) out[(size_t)n * 128 + j] += 0.5f * acc2[mt][nt][reg];
            }
    }
}

// ---------------------------------------------------------------- term0: out = 0.5*([x|x]@Wo_0 + bias)
__global__ __launch_bounds__(256) void k_out0(const float* __restrict__ x,
                                              const unsigned short* __restrict__ WoT,
                                              const float* __restrict__ Wo_b,
                                              float* __restrict__ out, int N) {
    __shared__ unsigned short sm[64 * 256];
    const int t = threadIdx.x;
    const int n0 = blockIdx.x * 64;
#pragma unroll
    for (int i = 0; i < 8; i++) {
        int chunk = i * 256 + t;
        int r = chunk >> 5, c0 = (chunk & 31) * 8, cs = c0 & 127;
        float4 a0 = make_float4(0.f, 0.f, 0.f, 0.f), a1 = a0;
        if (n0 + r < N) {
            a0 = ld4f(&x[(size_t)(n0 + r) * 128 + cs]);
            a1 = ld4f(&x[(size_t)(n0 + r) * 128 + cs + 4]);
        }
        short8 v = {(short)f2bf(a0.x), (short)f2bf(a0.y), (short)f2bf(a0.z), (short)f2bf(a0.w),
                    (short)f2bf(a1.x), (short)f2bf(a1.y), (short)f2bf(a1.z), (short)f2bf(a1.w)};
        *reinterpret_cast<short8*>(reinterpret_cast<char*>(sm) + r * 512 +
                                   ((c0 * 2) ^ ((r & 7) << 4))) = v;
    }
    __syncthreads();
    const int w = t >> 6, l = t & 63, lrow = l & 15, lhi = l >> 4;
    const f32x4 fz = {0.f, 0.f, 0.f, 0.f};
    f32x4 acc2[4][2];
#pragma unroll
    for (int mt = 0; mt < 4; mt++)
#pragma unroll
        for (int nt = 0; nt < 2; nt++) acc2[mt][nt] = fz;
    for (int kk = 0; kk < 8; kk++) {
        int kb = kk * 32 + lhi * 8;
        short8 af[4];
#pragma unroll
        for (int mt = 0; mt < 4; mt++) {
            int r = mt * 16 + lrow;
            af[mt] = *reinterpret_cast<const short8*>(
                reinterpret_cast<const char*>(sm) + r * 512 + ((kb * 2) ^ ((r & 7) << 4)));
        }
        int woff = (kb >> 7) * 640 + (kb & 127);  // tblk = 0
#pragma unroll
        for (int nt = 0; nt < 2; nt++) {
            int j = w * 32 + nt * 16 + lrow;
            short8 bf = *reinterpret_cast<const short8*>(&WoT[(size_t)j * 1280 + woff]);
#pragma unroll
            for (int mt = 0; mt < 4; mt++)
                acc2[mt][nt] = __builtin_amdgcn_mfma_f32_16x16x32_bf16(af[mt], bf, acc2[mt][nt], 0, 0, 0);
        }
    }
#pragma unroll
    for (int nt = 0; nt < 2; nt++) {
        int j = w * 32 + nt * 16 + lrow;
        float b = Wo_b[j];
#pragma unroll
        for (int mt = 0; mt < 4; mt++)
#pragma unroll
            for (int reg = 0; reg < 4; reg++) {
                int n = n0 + mt * 16 + lhi * 4 + reg;
                if (n < N) out[(size_t)n * 128 + j] = 0.5f * (acc2[mt][nt][reg] + b);
            }
    }
}

// ================================================================ host
extern "C" void kernel_launch(void* const* d_in, const int* in_sizes, int n_in,
                              void* d_out, int out_size, void* d_ws, size_t ws_size,
                              hipStream_t stream) {
    const int N = in_sizes[0] / 128;
    const int E = in_sizes[1] / 2;
    const float* x = (const float*)d_in[0];
    const int* eraw = (const int*)d_in[1];
    const float* Wq_w = (const float*)d_in[2];
    const float* Wq_b = (const float*)d_in[3];
    const float* Wk_w = (const float*)d_in[4];
    const float* Wk_b = (const float*)d_in[5];
    const float* Wo_w = (const float*)d_in[6];
    const float* Wo_b = (const float*)d_in[7];
    float* out = (float*)d_out;

    char* p = (char*)d_ws;
    auto alloc = [&](size_t bytes) -> void* {
        void* r = (void*)p;
        p += (bytes + 255) & ~(size_t)255;
        return r;
    };
    unsigned short* qs = (unsigned short*)alloc((size_t)N * 256 * 2);
    unsigned short* ks = (unsigned short*)alloc((size_t)N * 256 * 2);
    unsigned short* bufA = (unsigned short*)alloc((size_t)N * 256 * 2);
    unsigned short* bufB = (unsigned short*)alloc((size_t)N * 256 * 2);
    float* deg_inv = (float*)alloc((size_t)N * 4);
    float* den = (float*)alloc((size_t)N * 2 * 4);
    float* kvs = (float*)alloc((size_t)(2 * 128 * 128 + 256) * 4);  // + vs_sum tail
    float* ks_sum = (float*)alloc(256 * 4);
    float* colpart = (float*)alloc(256 * 256 * 4);
    unsigned short* WqkT = (unsigned short*)alloc(512 * 128 * 2);
    unsigned short* WoT = (unsigned short*)alloc(1280 * 128 * 2);
    unsigned short* kvsTb = (unsigned short*)alloc(32768 * 2);
    int* cnt = (int*)alloc((size_t)N * 4);
    int* offs = (int*)alloc((size_t)N * 4);
    int* cursor = (int*)alloc((size_t)N * 4);
    int* bsum = (int*)alloc(512 * 4);
    int* mode = (int*)alloc(256);
    int* csr = (int*)alloc((size_t)E * 4);

    hipMemsetAsync(cnt, 0, (size_t)N * 4, stream);

    const int nb = (N + 255) / 256;
    const int eb = (E + 255) / 256;
    k_detect<<<1, 256, 0, stream>>>(eraw, E, mode);
    k_count<<<eb, 256, 0, stream>>>(eraw, E, mode, N, cnt);
    k_scan1<<<nb, 256, 0, stream>>>(cnt, N, bsum);
    k_scan2<<<1, 512, 0, stream>>>(bsum, nb);
    k_scan3<<<nb, 256, 0, stream>>>(cnt, N, bsum, offs);
    k_deginv<<<nb, 256, 0, stream>>>(cnt, offs, N, deg_inv, cursor);
    k_scatter<<<eb, 256, 0, stream>>>(eraw, E, mode, N, cursor, csr);

    k_prep_wqk<<<256, 256, 0, stream>>>(Wq_w, Wk_w, WqkT);
    k_prep_wo<<<640, 256, 0, stream>>>(Wo_w, WoT);

    const int nb64 = (N + 63) / 64;
    k_proj<<<nb64, 256, 0, stream>>>(x, WqkT, Wq_b, Wk_b, qs, ks, N);
    k_colsum<<<256, 256, 0, stream>>>(ks, N, colpart);
    k_colsum2<<<1, 256, 0, stream>>>(colpart, ks_sum);
    k_den<<<(N + 3) / 4, 256, 0, stream>>>(qs, ks_sum, den, N);
    k_out0<<<nb64, 256, 0, stream>>>(x, WoT, Wo_b, out, N);

    const size_t kvs_bytes = (size_t)(2 * 128 * 128 + 256) * 4;
    dim3 g1(256, 8);
    const int gb = (N + 7) / 8;

    // hop 1: prev = x (f32, stride 128, head-broadcast)
    hipMemsetAsync(kvs, 0, kvs_bytes, stream);
    k_kvs<float><<<g1, 256, 0, stream>>>(ks, x, 128, 127, kvs, kvs + 32768, N);
    k_kvsT<<<128, 256, 0, stream>>>(kvs, kvsTb);
    k_gather<float><<<gb, 256, 0, stream>>>(x, 128, 127, csr, offs, cnt, deg_inv, bufA, N);
    k_att_out<<<nb64, 256, 0, stream>>>(qs, kvsTb, kvs + 32768, den, bufA, WoT, out, 1, N);

    // hops 2..4
    unsigned short* prev = bufA;
    unsigned short* cur = bufB;
    for (int step = 2; step <= 4; step++) {
        hipMemsetAsync(kvs, 0, kvs_bytes, stream);
        k_kvs<unsigned short><<<g1, 256, 0, stream>>>(ks, prev, 256, 255, kvs, kvs + 32768, N);
        k_kvsT<<<128, 256, 0, stream>>>(kvs, kvsTb);
        k_gather<unsigned short><<<gb, 256, 0, stream>>>(prev, 256, 255, csr, offs, cnt, deg_inv,
                                                         cur, N);
        k_att_out<<<nb64, 256, 0, stream>>>(qs, kvsTb, kvs + 32768, den, cur, WoT, out, step, N);
        unsigned short* tmp = prev;
        prev = cur;
        cur = tmp;
    }
}

// Round 5
// 2254.053 us; speedup vs baseline: 1.3524x; 1.0590x over previous
//
#include <hip/hip_runtime.h>

#define THREADS 256

typedef __attribute__((ext_vector_type(8))) short short8;
typedef __attribute__((ext_vector_type(4))) float f32x4;

// ---------------------------------------------------------------- bf16 helpers (raw ushort storage)
__device__ __forceinline__ float bf2f(unsigned short u) {
    union { unsigned int i; float f; } v;
    v.i = ((unsigned int)u) << 16;
    return v.f;
}
__device__ __forceinline__ unsigned short f2bf(float f) {
    union { float f; unsigned int i; } v;
    v.f = f;
    unsigned int r = (v.i + 0x7FFFu + ((v.i >> 16) & 1u)) >> 16;  // RNE
    return (unsigned short)r;
}
__device__ __forceinline__ float4 ld4f(const float* p) {
    return *reinterpret_cast<const float4*>(p);
}
__device__ __forceinline__ float4 ld4f(const unsigned short* p) {
    ushort4 u = *reinterpret_cast<const ushort4*>(p);
    return make_float4(bf2f(u.x), bf2f(u.y), bf2f(u.z), bf2f(u.w));
}
__device__ __forceinline__ float ld1f(const float* p) { return *p; }
__device__ __forceinline__ float ld1f(const unsigned short* p) { return bf2f(*p); }

// ---------------------------------------------------------------- edge accessor (int32 or int64 payload)
__device__ __forceinline__ int edge_get(const int* base, int E, int mode, int which, int e) {
    size_t idx = (size_t)which * (size_t)E + (size_t)e;
    return mode ? base[2 * idx] : base[idx];
}

__global__ __launch_bounds__(256) void k_detect(const int* __restrict__ e, int E,
                                                int* __restrict__ mode) {
    __shared__ int nz;
    if (threadIdx.x == 0) nz = 0;
    __syncthreads();
    int lim = 2 * E;
    if (lim > 8192) lim = 8192;
    for (int i = 1 + 2 * (int)threadIdx.x; i < lim; i += 512)
        if (e[i] != 0) nz = 1;
    __syncthreads();
    if (threadIdx.x == 0) *mode = (nz == 0) ? 1 : 0;
}

// ---------------------------------------------------------------- graph prep
__global__ __launch_bounds__(256) void k_count(const int* __restrict__ eb, int E,
                                               const int* __restrict__ mode, int N,
                                               int* __restrict__ cnt) {
    int m = *mode;
    int e = blockIdx.x * THREADS + threadIdx.x;
    if (e < E) {
        int c = edge_get(eb, E, m, 1, e);
        if ((unsigned)c < (unsigned)N) atomicAdd(&cnt[c], 1);
    }
}

__global__ __launch_bounds__(256) void k_scan1(const int* __restrict__ cnt, int N,
                                               int* __restrict__ bsum) {
    __shared__ int s[256];
    int i = blockIdx.x * 256 + threadIdx.x;
    s[threadIdx.x] = (i < N) ? cnt[i] : 0;
    __syncthreads();
    for (int off = 128; off > 0; off >>= 1) {
        if (threadIdx.x < off) s[threadIdx.x] += s[threadIdx.x + off];
        __syncthreads();
    }
    if (threadIdx.x == 0) bsum[blockIdx.x] = s[0];
}

__global__ __launch_bounds__(512) void k_scan2(int* __restrict__ bsum, int nb) {
    __shared__ int s[512];
    int t = threadIdx.x;
    int v = (t < nb) ? bsum[t] : 0;
    s[t] = v;
    __syncthreads();
    for (int off = 1; off < 512; off <<= 1) {
        int add = (t >= off) ? s[t - off] : 0;
        __syncthreads();
        s[t] += add;
        __syncthreads();
    }
    if (t < nb) bsum[t] = s[t] - v;  // exclusive
}

__global__ __launch_bounds__(256) void k_scan3(const int* __restrict__ cnt, int N,
                                               const int* __restrict__ bsum,
                                               int* __restrict__ offs) {
    __shared__ int s[256];
    int i = blockIdx.x * 256 + threadIdx.x;
    int v = (i < N) ? cnt[i] : 0;
    s[threadIdx.x] = v;
    __syncthreads();
    for (int off = 1; off < 256; off <<= 1) {
        int add = (threadIdx.x >= off) ? s[threadIdx.x - off] : 0;
        __syncthreads();
        s[threadIdx.x] += add;
        __syncthreads();
    }
    if (i < N) offs[i] = bsum[blockIdx.x] + s[threadIdx.x] - v;
}

__global__ __launch_bounds__(256) void k_deginv(const int* __restrict__ cnt,
                                                const int* __restrict__ offs, int N,
                                                float* __restrict__ deg_inv,
                                                int* __restrict__ cursor) {
    int i = blockIdx.x * 256 + threadIdx.x;
    if (i < N) {
        int c = cnt[i];
        deg_inv[i] = (c > 0) ? 1.0f / (float)c : 0.0f;
        cursor[i] = offs[i];
    }
}

__global__ __launch_bounds__(256) void k_scatter(const int* __restrict__ eb, int E,
                                                 const int* __restrict__ mode, int N,
                                                 int* __restrict__ cursor,
                                                 int* __restrict__ csr_src) {
    int m = *mode;
    int e = blockIdx.x * THREADS + threadIdx.x;
    if (e < E) {
        int c = edge_get(eb, E, m, 1, e);
        if ((unsigned)c < (unsigned)N) {
            int r = edge_get(eb, E, m, 0, e);
            if ((unsigned)r >= (unsigned)N) r = 0;
            int pos = atomicAdd(&cursor[c], 1);
            csr_src[pos] = r;
        }
    }
}

// ---------------------------------------------------------------- weight prep (bf16, transposed)
__global__ __launch_bounds__(256) void k_prep_wqk(const float* __restrict__ Wq,
                                                  const float* __restrict__ Wk,
                                                  unsigned short* __restrict__ WqkT) {
    int i = blockIdx.x * 256 + threadIdx.x;  // 512*128
    if (i < 512 * 128) {
        int oc = i >> 7, k = i & 127;
        float v = (oc < 256) ? Wq[k * 256 + oc] : Wk[k * 256 + (oc - 256)];
        WqkT[i] = f2bf(v);
    }
}

__global__ __launch_bounds__(256) void k_prep_wo(const float* __restrict__ Wo,
                                                 unsigned short* __restrict__ WoT) {
    int i = blockIdx.x * 256 + threadIdx.x;  // 1280*128
    if (i < 1280 * 128) {
        int r = i >> 7, j = i & 127;
        WoT[(size_t)j * 1280 + r] = f2bf(Wo[i]);
    }
}

// ---------------------------------------------------------------- Q/K proj + row L2-norm (MFMA, atomic-free)
__global__ __launch_bounds__(256) void k_proj(const float* __restrict__ x,
                                              const unsigned short* __restrict__ WqkT,
                                              const float* __restrict__ bq,
                                              const float* __restrict__ bk,
                                              unsigned short* __restrict__ qs,
                                              unsigned short* __restrict__ ks, int N) {
    __shared__ unsigned short xs[64 * 128];  // 16 KB input staging
    __shared__ unsigned short os[64 * 256];  // 32 KB output staging
    const int t = threadIdx.x;
    const int n0 = blockIdx.x * 64;
#pragma unroll
    for (int i = 0; i < 4; i++) {
        int chunk = i * 256 + t;
        int r = chunk >> 4, c0 = (chunk & 15) * 8;
        float4 a0 = make_float4(0.f, 0.f, 0.f, 0.f), a1 = a0;
        if (n0 + r < N) {
            a0 = ld4f(&x[(size_t)(n0 + r) * 128 + c0]);
            a1 = ld4f(&x[(size_t)(n0 + r) * 128 + c0 + 4]);
        }
        short8 v = {(short)f2bf(a0.x), (short)f2bf(a0.y), (short)f2bf(a0.z), (short)f2bf(a0.w),
                    (short)f2bf(a1.x), (short)f2bf(a1.y), (short)f2bf(a1.z), (short)f2bf(a1.w)};
        int byte = r * 256 + ((c0 * 2) ^ ((r & 7) << 4));
        *reinterpret_cast<short8*>(reinterpret_cast<char*>(xs) + byte) = v;
    }
    __syncthreads();
    const int w = t >> 6, l = t & 63, lrow = l & 15, lhi = l >> 4;
    f32x4 acc[4][8];
    const f32x4 fz = {0.f, 0.f, 0.f, 0.f};
#pragma unroll
    for (int mt = 0; mt < 4; mt++)
#pragma unroll
        for (int nt = 0; nt < 8; nt++) acc[mt][nt] = fz;

    for (int kk = 0; kk < 4; kk++) {
        int kb = kk * 32 + lhi * 8;
        short8 af[4];
#pragma unroll
        for (int mt = 0; mt < 4; mt++) {
            int r = mt * 16 + lrow;
            af[mt] = *reinterpret_cast<const short8*>(
                reinterpret_cast<const char*>(xs) + r * 256 + ((kb * 2) ^ ((r & 7) << 4)));
        }
#pragma unroll
        for (int nt = 0; nt < 8; nt++) {
            int oc = w * 128 + nt * 16 + lrow;
            short8 bf = *reinterpret_cast<const short8*>(&WqkT[(size_t)oc * 128 + kb]);
#pragma unroll
            for (int mt = 0; mt < 4; mt++)
                acc[mt][nt] = __builtin_amdgcn_mfma_f32_16x16x32_bf16(af[mt], bf, acc[mt][nt], 0, 0, 0);
        }
    }
    // bias
#pragma unroll
    for (int nt = 0; nt < 8; nt++) {
        int oc = w * 128 + nt * 16 + lrow;
        float b = (oc < 256) ? bq[oc] : bk[oc - 256];
#pragma unroll
        for (int mt = 0; mt < 4; mt++)
#pragma unroll
            for (int reg = 0; reg < 4; reg++) acc[mt][nt][reg] += b;
    }
    // row-norm in registers
    const int hc = (w & 1) * 128;
    float rv[4][4];
#pragma unroll
    for (int mt = 0; mt < 4; mt++) {
        float ss[4] = {0.f, 0.f, 0.f, 0.f};
#pragma unroll
        for (int nt = 0; nt < 8; nt++)
#pragma unroll
            for (int reg = 0; reg < 4; reg++) ss[reg] += acc[mt][nt][reg] * acc[mt][nt][reg];
#pragma unroll
        for (int m_ = 1; m_ < 16; m_ <<= 1)
#pragma unroll
            for (int reg = 0; reg < 4; reg++) ss[reg] += __shfl_xor(ss[reg], m_);
#pragma unroll
        for (int reg = 0; reg < 4; reg++) rv[mt][reg] = rsqrtf(ss[reg]);
    }
    // two passes: pass0 waves 0,1 (q) -> os -> coalesced global; pass1 waves 2,3 (k)
    for (int pass = 0; pass < 2; pass++) {
        if ((w >> 1) == pass) {
#pragma unroll
            for (int mt = 0; mt < 4; mt++)
#pragma unroll
                for (int reg = 0; reg < 4; reg++) {
                    int r = mt * 16 + lhi * 4 + reg;
#pragma unroll
                    for (int nt = 0; nt < 8; nt++)
                        os[r * 256 + hc + nt * 16 + lrow] = f2bf(acc[mt][nt][reg] * rv[mt][reg]);
                }
        }
        __syncthreads();
        unsigned short* dstg = pass ? ks : qs;
#pragma unroll
        for (int i = 0; i < 8; i++) {
            int chunk = i * 256 + t;
            int r = chunk >> 5, c = (chunk & 31) * 8;
            int n = n0 + r;
            if (n < N)
                *reinterpret_cast<short8*>(&dstg[(size_t)n * 256 + c]) =
                    *reinterpret_cast<const short8*>(&os[r * 256 + c]);
        }
        __syncthreads();
    }
}

// ---------------------------------------------------------------- ks_sum: 2-stage column reduction
__global__ __launch_bounds__(256) void k_colsum(const unsigned short* __restrict__ ks, int N,
                                                float* __restrict__ part) {
    const int t = threadIdx.x;
    const int stride = (N + 255) >> 8;
    int r0 = blockIdx.x * stride;
    int rend = min(r0 + stride, N);
    float s = 0.f;
    for (int n = r0; n < rend; n++) s += bf2f(ks[(size_t)n * 256 + t]);
    part[blockIdx.x * 256 + t] = s;
}

__global__ __launch_bounds__(256) void k_colsum2(const float* __restrict__ part,
                                                 float* __restrict__ ks_sum) {
    const int t = threadIdx.x;
    float s = 0.f;
    for (int b = 0; b < 256; b++) s += part[b * 256 + t];
    ks_sum[t] = s;
}

// ---------------------------------------------------------------- den = qs . ks_sum + N
__global__ __launch_bounds__(256) void k_den(const unsigned short* __restrict__ qs,
                                             const float* __restrict__ ks_sum,
                                             float* __restrict__ den, int N) {
    int w = threadIdx.x >> 6, lane = threadIdx.x & 63;
    int n = blockIdx.x * 4 + w;
    if (n >= N) return;
    float4 q = ld4f(&qs[(size_t)n * 256 + lane * 4]);
    float4 kv = *reinterpret_cast<const float4*>(&ks_sum[lane * 4]);
    float s = q.x * kv.x + q.y * kv.y + q.z * kv.z + q.w * kv.w;
#pragma unroll
    for (int off = 1; off < 32; off <<= 1) s += __shfl_xor(s, off);
    if ((lane & 31) == 0) den[n * 2 + (lane >> 5)] = s + (float)N;
}

// ---------------------------------------------------------------- kvsT = vs^T @ ks per head (MFMA split-K)
// Tiles stored linearly [32][256] bf16 with byte-swizzle: byte = n*512 + ((c*2) ^ (((n>>3)&3)<<5))
// Fragment gather (8 consecutive n at fixed c) hits 4 disjoint bank groups -> conflict-free.
__device__ __forceinline__ short8 frag_ld(const unsigned short* tile, int kb, int col) {
    const char* b = reinterpret_cast<const char*>(tile);
    int cb = (col * 2) ^ (((kb >> 3) & 3) << 5);  // (n>>3) constant over the 8-elem run
    short8 r;
#pragma unroll
    for (int i = 0; i < 8; i++)
        r[i] = (short)*reinterpret_cast<const unsigned short*>(b + (kb + i) * 512 + cb);
    return r;
}

template <typename TV>
__global__ __launch_bounds__(256) void k_kvs2(const unsigned short* __restrict__ ks,
                                              const TV* __restrict__ vs, int vstride, int vmask,
                                              float* __restrict__ partial,
                                              float* __restrict__ pvsum, int rows_per, int N) {
    __shared__ unsigned short kt[32 * 256];  // 16 KB  ks tile [n][j]
    __shared__ unsigned short vt[32 * 256];  // 16 KB  vs tile [n][c]
    __shared__ float vred[8][256];           // 8 KB   vs_sum block reduce
    const int t = threadIdx.x;
    const int w = t >> 6, l = t & 63, lrow = l & 15, lhi = l >> 4;
    const int h = w >> 1, mhalf = w & 1;
    const int r0 = blockIdx.x * rows_per;
    const int rend = min(r0 + rows_per, N);

    const f32x4 fz = {0.f, 0.f, 0.f, 0.f};
    f32x4 acc[4][8];
#pragma unroll
    for (int mt = 0; mt < 4; mt++)
#pragma unroll
        for (int nt = 0; nt < 8; nt++) acc[mt][nt] = fz;
    float vsum8[8] = {0.f, 0.f, 0.f, 0.f, 0.f, 0.f, 0.f, 0.f};

    for (int c0 = r0; c0 < rend; c0 += 32) {
        // stage ks tile: 4 iters x ushort8
#pragma unroll
        for (int i = 0; i < 4; i++) {
            int chunk = i * 256 + t;
            int n = chunk >> 5, cc = (chunk & 31) * 8;
            short8 v = {0, 0, 0, 0, 0, 0, 0, 0};
            if (c0 + n < rend)
                v = *reinterpret_cast<const short8*>(&ks[(size_t)(c0 + n) * 256 + cc]);
            *reinterpret_cast<short8*>(reinterpret_cast<char*>(kt) + n * 512 +
                                       ((cc * 2) ^ (((n >> 3) & 3) << 5))) = v;
        }
        // stage vs tile (+ per-thread column sums; cc fixed per thread since 256%32==0)
#pragma unroll
        for (int i = 0; i < 4; i++) {
            int chunk = i * 256 + t;
            int n = chunk >> 5, cc = (chunk & 31) * 8;
            float4 a0 = make_float4(0.f, 0.f, 0.f, 0.f), a1 = a0;
            if (c0 + n < rend) {
                a0 = ld4f(&vs[(size_t)(c0 + n) * vstride + (cc & vmask)]);
                a1 = ld4f(&vs[(size_t)(c0 + n) * vstride + ((cc + 4) & vmask)]);
            }
            unsigned short u0 = f2bf(a0.x), u1 = f2bf(a0.y), u2 = f2bf(a0.z), u3 = f2bf(a0.w);
            unsigned short u4 = f2bf(a1.x), u5 = f2bf(a1.y), u6 = f2bf(a1.z), u7 = f2bf(a1.w);
            vsum8[0] += bf2f(u0); vsum8[1] += bf2f(u1); vsum8[2] += bf2f(u2); vsum8[3] += bf2f(u3);
            vsum8[4] += bf2f(u4); vsum8[5] += bf2f(u5); vsum8[6] += bf2f(u6); vsum8[7] += bf2f(u7);
            short8 v = {(short)u0, (short)u1, (short)u2, (short)u3,
                        (short)u4, (short)u5, (short)u6, (short)u7};
            *reinterpret_cast<short8*>(reinterpret_cast<char*>(vt) + n * 512 +
                                       ((cc * 2) ^ (((n >> 3) & 3) << 5))) = v;
        }
        __syncthreads();
        // compute: one 16x16x32 k-step per chunk
        {
            int kb = lhi * 8;
            short8 af[4];
#pragma unroll
            for (int mt = 0; mt < 4; mt++)
                af[mt] = frag_ld(vt, kb, h * 128 + mhalf * 64 + mt * 16 + lrow);
#pragma unroll
            for (int nt = 0; nt < 8; nt++) {
                short8 bf = frag_ld(kt, kb, h * 128 + nt * 16 + lrow);
#pragma unroll
                for (int mt = 0; mt < 4; mt++)
                    acc[mt][nt] =
                        __builtin_amdgcn_mfma_f32_16x16x32_bf16(af[mt], bf, acc[mt][nt], 0, 0, 0);
            }
        }
        __syncthreads();
    }
    // write partial kvsT: [s][h][c][j]
    float* pb = &partial[((size_t)blockIdx.x * 2 + h) * 16384];
#pragma unroll
    for (int mt = 0; mt < 4; mt++)
#pragma unroll
        for (int reg = 0; reg < 4; reg++) {
            int c_local = mhalf * 64 + mt * 16 + lhi * 4 + reg;
#pragma unroll
            for (int nt = 0; nt < 8; nt++) pb[c_local * 128 + nt * 16 + lrow] = acc[mt][nt][reg];
        }
    // vs_sum partial: vsum8[j] covers column (t&31)*8+j summed over rows (t>>5)+8i
    {
        int cc = (t & 31) * 8;
#pragma unroll
        for (int j = 0; j < 8; j++) vred[t >> 5][cc + j] = vsum8[j];
        __syncthreads();
        float s = 0.f;
#pragma unroll
        for (int r = 0; r < 8; r++) s += vred[r][t];
        pvsum[blockIdx.x * 256 + t] = s;
    }
}

__global__ __launch_bounds__(256) void k_kvred(const float* __restrict__ partial, int S,
                                               unsigned short* __restrict__ kvsT) {
    int e = blockIdx.x * 256 + threadIdx.x;  // 32768 elems
    float s = 0.f;
    for (int i = 0; i < S; i++) s += partial[(size_t)i * 32768 + e];
    kvsT[e] = f2bf(s);
}

__global__ __launch_bounds__(256) void k_vsred(const float* __restrict__ pvsum, int S,
                                               float* __restrict__ vs_sum) {
    int c = threadIdx.x;
    float s = 0.f;
    for (int i = 0; i < S; i++) s += pvsum[i * 256 + c];
    vs_sum[c] = s;
}

// ---------------------------------------------------------------- GCN gather: cur = 0.5*deg_inv*sum prev[src]
template <typename TS>
__global__ __launch_bounds__(256) void k_gather(const TS* __restrict__ prev, int pstride, int pmask,
                                                const int* __restrict__ csr_src,
                                                const int* __restrict__ offs,
                                                const int* __restrict__ cnt,
                                                const float* __restrict__ deg_inv,
                                                unsigned short* __restrict__ cur, int N) {
    const int t = threadIdx.x;
    const int ch = t & pmask;
    int nbase = blockIdx.x * 8;
    for (int i = 0; i < 8; i++) {
        int n = nbase + i;
        if (n >= N) return;
        int start = offs[n], d = cnt[n];
        int e = start, eend = start + d;
        float acc = 0.f;
        for (; e + 4 <= eend; e += 4) {
            int s0 = csr_src[e], s1 = csr_src[e + 1], s2 = csr_src[e + 2], s3 = csr_src[e + 3];
            acc += ld1f(&prev[(size_t)s0 * pstride + ch]);
            acc += ld1f(&prev[(size_t)s1 * pstride + ch]);
            acc += ld1f(&prev[(size_t)s2 * pstride + ch]);
            acc += ld1f(&prev[(size_t)s3 * pstride + ch]);
        }
        for (; e < eend; e++) acc += ld1f(&prev[(size_t)csr_src[e] * pstride + ch]);
        cur[(size_t)n * 256 + t] = f2bf(0.5f * deg_inv[n] * acc);
    }
}

// ---------------------------------------------------------------- fused: cur += (qs@kvs+vs_sum)/den ; out += 0.5*cur@Wo_blk
__global__ __launch_bounds__(256) void k_att_out(const unsigned short* __restrict__ qs,
                                                 const unsigned short* __restrict__ kvsT,
                                                 const float* __restrict__ vs_sum,
                                                 const float* __restrict__ den,
                                                 unsigned short* __restrict__ cur,
                                                 const unsigned short* __restrict__ WoT,
                                                 float* __restrict__ out, int tblk, int N) {
    __shared__ unsigned short sm[64 * 256];
    const int t = threadIdx.x;
    const int n0 = blockIdx.x * 64;
    // stage qs tile (64 x 256), swizzled
#pragma unroll
    for (int i = 0; i < 8; i++) {
        int chunk = i * 256 + t;
        int r = chunk >> 5, c0 = (chunk & 31) * 8;
        short8 v = {0, 0, 0, 0, 0, 0, 0, 0};
        if (n0 + r < N) v = *reinterpret_cast<const short8*>(&qs[(size_t)(n0 + r) * 256 + c0]);
        *reinterpret_cast<short8*>(reinterpret_cast<char*>(sm) + r * 512 +
                                   ((c0 * 2) ^ ((r & 7) << 4))) = v;
    }
    __syncthreads();
    const int w = t >> 6, l = t & 63, lrow = l & 15, lhi = l >> 4;
    const int h = w >> 1, jh = w & 1;
    const f32x4 fz = {0.f, 0.f, 0.f, 0.f};
    f32x4 acc[4][4];
#pragma unroll
    for (int mt = 0; mt < 4; mt++)
#pragma unroll
        for (int nt = 0; nt < 4; nt++) acc[mt][nt] = fz;

    for (int kk = 0; kk < 4; kk++) {
        int kb = kk * 32 + lhi * 8;
        short8 af[4];
#pragma unroll
        for (int mt = 0; mt < 4; mt++) {
            int r = mt * 16 + lrow;
            af[mt] = *reinterpret_cast<const short8*>(
                reinterpret_cast<const char*>(sm) + r * 512 +
                (((h * 128 + kb) * 2) ^ ((r & 7) << 4)));
        }
#pragma unroll
        for (int nt = 0; nt < 4; nt++) {
            int c = jh * 64 + nt * 16 + lrow;
            short8 bf = *reinterpret_cast<const short8*>(&kvsT[((size_t)h * 128 + c) * 128 + kb]);
#pragma unroll
            for (int mt = 0; mt < 4; mt++)
                acc[mt][nt] = __builtin_amdgcn_mfma_f32_16x16x32_bf16(af[mt], bf, acc[mt][nt], 0, 0, 0);
        }
    }
    __syncthreads();  // done reading qs from sm
    // phase2: cur = gather + (attn + vs_sum)/den ; write back + stage into sm
#pragma unroll
    for (int mt = 0; mt < 4; mt++) {
#pragma unroll
        for (int reg = 0; reg < 4; reg++) {
            int r = mt * 16 + lhi * 4 + reg;
            int n = n0 + r;
            if (n < N) {
                float idn = 1.0f / den[n * 2 + h];
#pragma unroll
                for (int nt = 0; nt < 4; nt++) {
                    int c = h * 128 + jh * 64 + nt * 16 + lrow;
                    float g = bf2f(cur[(size_t)n * 256 + c]);
                    float v = g + (acc[mt][nt][reg] + vs_sum[c]) * idn;
                    unsigned short ub = f2bf(v);
                    cur[(size_t)n * 256 + c] = ub;
                    *reinterpret_cast<unsigned short*>(reinterpret_cast<char*>(sm) + r * 512 +
                                                       ((c * 2) ^ ((r & 7) << 4))) = ub;
                }
            }
        }
    }
    __syncthreads();
    // phase3: out += 0.5 * cur @ WoT(tblk), wave w covers j in [w*32, w*32+32)
    f32x4 acc2[4][2];
#pragma unroll
    for (int mt = 0; mt < 4; mt++)
#pragma unroll
        for (int nt = 0; nt < 2; nt++) acc2[mt][nt] = fz;
    for (int kk = 0; kk < 8; kk++) {
        int kb = kk * 32 + lhi * 8;
        short8 af[4];
#pragma unroll
        for (int mt = 0; mt < 4; mt++) {
            int r = mt * 16 + lrow;
            af[mt] = *reinterpret_cast<const short8*>(
                reinterpret_cast<const char*>(sm) + r * 512 + ((kb * 2) ^ ((r & 7) << 4)));
        }
        int woff = (kb >> 7) * 640 + tblk * 128 + (kb & 127);
#pragma unroll
        for (int nt = 0; nt < 2; nt++) {
            int j = w * 32 + nt * 16 + lrow;
            short8 bf = *reinterpret_cast<const short8*>(&WoT[(size_t)j * 1280 + woff]);
#pragma unroll
            for (int mt = 0; mt < 4; mt++)
                acc2[mt][nt] = __builtin_amdgcn_mfma_f32_16x16x32_bf16(af[mt], bf, acc2[mt][nt], 0, 0, 0);
        }
    }
#pragma unroll
    for (int nt = 0; nt < 2; nt++) {
        int j = w * 32 + nt * 16 + lrow;
#pragma unroll
        for (int mt = 0; mt < 4; mt++)
#pragma unroll
            for (int reg = 0; reg < 4; reg++) {
                int n = n0 + mt * 16 + lhi * 4 + reg;
                if (n < N) out[(size_t)n * 128 + j] += 0.5f * acc2[mt][nt][reg];
            }
    }
}

// ---------------------------------------------------------------- term0: out = 0.5*([x|x]@Wo_0 + bias)
__global__ __launch_bounds__(256) void k_out0(const float* __restrict__ x,
                                              const unsigned short* __restrict__ WoT,
                                              const float* __restrict__ Wo_b,
                                              float* __restrict__ out, int N) {
    __shared__ unsigned short sm[64 * 256];
    const int t = threadIdx.x;
    const int n0 = blockIdx.x * 64;
#pragma unroll
    for (int i = 0; i < 8; i++) {
        int chunk = i * 256 + t;
        int r = chunk >> 5, c0 = (chunk & 31) * 8, cs = c0 & 127;
        float4 a0 = make_float4(0.f, 0.f, 0.f, 0.f), a1 = a0;
        if (n0 + r < N) {
            a0 = ld4f(&x[(size_t)(n0 + r) * 128 + cs]);
            a1 = ld4f(&x[(size_t)(n0 + r) * 128 + cs + 4]);
        }
        short8 v = {(short)f2bf(a0.x), (short)f2bf(a0.y), (short)f2bf(a0.z), (short)f2bf(a0.w),
                    (short)f2bf(a1.x), (short)f2bf(a1.y), (short)f2bf(a1.z), (short)f2bf(a1.w)};
        *reinterpret_cast<short8*>(reinterpret_cast<char*>(sm) + r * 512 +
                                   ((c0 * 2) ^ ((r & 7) << 4))) = v;
    }
    __syncthreads();
    const int w = t >> 6, l = t & 63, lrow = l & 15, lhi = l >> 4;
    const f32x4 fz = {0.f, 0.f, 0.f, 0.f};
    f32x4 acc2[4][2];
#pragma unroll
    for (int mt = 0; mt < 4; mt++)
#pragma unroll
        for (int nt = 0; nt < 2; nt++) acc2[mt][nt] = fz;
    for (int kk = 0; kk < 8; kk++) {
        int kb = kk * 32 + lhi * 8;
        short8 af[4];
#pragma unroll
        for (int mt = 0; mt < 4; mt++) {
            int r = mt * 16 + lrow;
            af[mt] = *reinterpret_cast<const short8*>(
                reinterpret_cast<const char*>(sm) + r * 512 + ((kb * 2) ^ ((r & 7) << 4)));
        }
        int woff = (kb >> 7) * 640 + (kb & 127);  // tblk = 0
#pragma unroll
        for (int nt = 0; nt < 2; nt++) {
            int j = w * 32 + nt * 16 + lrow;
            short8 bf = *reinterpret_cast<const short8*>(&WoT[(size_t)j * 1280 + woff]);
#pragma unroll
            for (int mt = 0; mt < 4; mt++)
                acc2[mt][nt] = __builtin_amdgcn_mfma_f32_16x16x32_bf16(af[mt], bf, acc2[mt][nt], 0, 0, 0);
        }
    }
#pragma unroll
    for (int nt = 0; nt < 2; nt++) {
        int j = w * 32 + nt * 16 + lrow;
        float b = Wo_b[j];
#pragma unroll
        for (int mt = 0; mt < 4; mt++)
#pragma unroll
            for (int reg = 0; reg < 4; reg++) {
                int n = n0 + mt * 16 + lhi * 4 + reg;
                if (n < N) out[(size_t)n * 128 + j] = 0.5f * (acc2[mt][nt][reg] + b);
            }
    }
}

// ================================================================ host
extern "C" void kernel_launch(void* const* d_in, const int* in_sizes, int n_in,
                              void* d_out, int out_size, void* d_ws, size_t ws_size,
                              hipStream_t stream) {
    const int N = in_sizes[0] / 128;
    const int E = in_sizes[1] / 2;
    const float* x = (const float*)d_in[0];
    const int* eraw = (const int*)d_in[1];
    const float* Wq_w = (const float*)d_in[2];
    const float* Wq_b = (const float*)d_in[3];
    const float* Wk_w = (const float*)d_in[4];
    const float* Wk_b = (const float*)d_in[5];
    const float* Wo_w = (const float*)d_in[6];
    const float* Wo_b = (const float*)d_in[7];
    float* out = (float*)d_out;

    char* p = (char*)d_ws;
    auto alloc = [&](size_t bytes) -> void* {
        void* r = (void*)p;
        p += (bytes + 255) & ~(size_t)255;
        return r;
    };
    unsigned short* qs = (unsigned short*)alloc((size_t)N * 256 * 2);
    unsigned short* ks = (unsigned short*)alloc((size_t)N * 256 * 2);
    unsigned short* bufA = (unsigned short*)alloc((size_t)N * 256 * 2);
    unsigned short* bufB = (unsigned short*)alloc((size_t)N * 256 * 2);
    float* deg_inv = (float*)alloc((size_t)N * 4);
    float* den = (float*)alloc((size_t)N * 2 * 4);
    float* ks_sum = (float*)alloc(256 * 4);
    float* vs_sum = (float*)alloc(256 * 4);
    float* colpart = (float*)alloc(256 * 256 * 4);
    unsigned short* WqkT = (unsigned short*)alloc(512 * 128 * 2);
    unsigned short* WoT = (unsigned short*)alloc(1280 * 128 * 2);
    unsigned short* kvsTb = (unsigned short*)alloc(32768 * 2);
    int* cnt = (int*)alloc((size_t)N * 4);
    int* offs = (int*)alloc((size_t)N * 4);
    int* cursor = (int*)alloc((size_t)N * 4);
    int* bsum = (int*)alloc(512 * 4);
    int* mode = (int*)alloc(256);
    int* csr = (int*)alloc((size_t)E * 4);

    // split-K slice count, sized to remaining workspace (partial + pvsum per slice)
    size_t used = (size_t)(p - (char*)d_ws);
    size_t rem = (ws_size > used + (1 << 20)) ? ws_size - used - (1 << 20) : 0;
    int S = (int)(rem / (32768 * 4 + 1024));
    if (S > 256) S = 256;
    if (S < 8) S = 8;
    float* partial = (float*)alloc((size_t)S * 32768 * 4);
    float* pvsum = (float*)alloc((size_t)S * 256 * 4);
    const int rows_per = (N + S - 1) / S;

    hipMemsetAsync(cnt, 0, (size_t)N * 4, stream);

    const int nb = (N + 255) / 256;
    const int eb = (E + 255) / 256;
    k_detect<<<1, 256, 0, stream>>>(eraw, E, mode);
    k_count<<<eb, 256, 0, stream>>>(eraw, E, mode, N, cnt);
    k_scan1<<<nb, 256, 0, stream>>>(cnt, N, bsum);
    k_scan2<<<1, 512, 0, stream>>>(bsum, nb);
    k_scan3<<<nb, 256, 0, stream>>>(cnt, N, bsum, offs);
    k_deginv<<<nb, 256, 0, stream>>>(cnt, offs, N, deg_inv, cursor);
    k_scatter<<<eb, 256, 0, stream>>>(eraw, E, mode, N, cursor, csr);

    k_prep_wqk<<<256, 256, 0, stream>>>(Wq_w, Wk_w, WqkT);
    k_prep_wo<<<640, 256, 0, stream>>>(Wo_w, WoT);

    const int nb64 = (N + 63) / 64;
    k_proj<<<nb64, 256, 0, stream>>>(x, WqkT, Wq_b, Wk_b, qs, ks, N);
    k_colsum<<<256, 256, 0, stream>>>(ks, N, colpart);
    k_colsum2<<<1, 256, 0, stream>>>(colpart, ks_sum);
    k_den<<<(N + 3) / 4, 256, 0, stream>>>(qs, ks_sum, den, N);
    k_out0<<<nb64, 256, 0, stream>>>(x, WoT, Wo_b, out, N);

    const int gb = (N + 7) / 8;

    // hop 1: prev = x (f32, stride 128, head-broadcast)
    k_kvs2<float><<<S, 256, 0, stream>>>(ks, x, 128, 127, partial, pvsum, rows_per, N);
    k_kvred<<<128, 256, 0, stream>>>(partial, S, kvsTb);
    k_vsred<<<1, 256, 0, stream>>>(pvsum, S, vs_sum);
    k_gather<float><<<gb, 256, 0, stream>>>(x, 128, 127, csr, offs, cnt, deg_inv, bufA, N);
    k_att_out<<<nb64, 256, 0, stream>>>(qs, kvsTb, vs_sum, den, bufA, WoT, out, 1, N);

    // hops 2..4
    unsigned short* prev = bufA;
    unsigned short* cur = bufB;
    for (int step = 2; step <= 4; step++) {
        k_kvs2<unsigned short><<<S, 256, 0, stream>>>(ks, prev, 256, 255, partial, pvsum, rows_per,
                                                      N);
        k_kvred<<<128, 256, 0, stream>>>(partial, S, kvsTb);
        k_vsred<<<1, 256, 0, stream>>>(pvsum, S, vs_sum);
        k_gather<unsigned short><<<gb, 256, 0, stream>>>(prev, 256, 255, csr, offs, cnt, deg_inv,
                                                         cur, N);
        k_att_out<<<nb64, 256, 0, stream>>>(qs, kvsTb, vs_sum, den, cur, WoT, out, step, N);
        unsigned short* tmp = prev;
        prev = cur;
        cur = tmp;
    }
}

// Round 6
// 2100.657 us; speedup vs baseline: 1.4512x; 1.0730x over previous
//
#include <hip/hip_runtime.h>

#define THREADS 256

typedef __attribute__((ext_vector_type(8))) short short8;
typedef __attribute__((ext_vector_type(4))) float f32x4;

// ---------------------------------------------------------------- bf16 helpers (raw ushort storage)
__device__ __forceinline__ float bf2f(unsigned short u) {
    union { unsigned int i; float f; } v;
    v.i = ((unsigned int)u) << 16;
    return v.f;
}
__device__ __forceinline__ unsigned short f2bf(float f) {
    union { float f; unsigned int i; } v;
    v.f = f;
    unsigned int r = (v.i + 0x7FFFu + ((v.i >> 16) & 1u)) >> 16;  // RNE
    return (unsigned short)r;
}
__device__ __forceinline__ float4 ld4f(const float* p) {
    return *reinterpret_cast<const float4*>(p);
}
__device__ __forceinline__ float4 ld4f(const unsigned short* p) {
    ushort4 u = *reinterpret_cast<const ushort4*>(p);
    return make_float4(bf2f(u.x), bf2f(u.y), bf2f(u.z), bf2f(u.w));
}

// ---------------------------------------------------------------- edge accessor (int32 or int64 payload)
__device__ __forceinline__ int edge_get(const int* base, int E, int mode, int which, int e) {
    size_t idx = (size_t)which * (size_t)E + (size_t)e;
    return mode ? base[2 * idx] : base[idx];
}

__global__ __launch_bounds__(256) void k_detect(const int* __restrict__ e, int E,
                                                int* __restrict__ mode) {
    __shared__ int nz;
    if (threadIdx.x == 0) nz = 0;
    __syncthreads();
    int lim = 2 * E;
    if (lim > 8192) lim = 8192;
    for (int i = 1 + 2 * (int)threadIdx.x; i < lim; i += 512)
        if (e[i] != 0) nz = 1;
    __syncthreads();
    if (threadIdx.x == 0) *mode = (nz == 0) ? 1 : 0;
}

// ---------------------------------------------------------------- graph prep
__global__ __launch_bounds__(256) void k_count(const int* __restrict__ eb, int E,
                                               const int* __restrict__ mode, int N,
                                               int* __restrict__ cnt) {
    int m = *mode;
    int e = blockIdx.x * THREADS + threadIdx.x;
    if (e < E) {
        int c = edge_get(eb, E, m, 1, e);
        if ((unsigned)c < (unsigned)N) atomicAdd(&cnt[c], 1);
    }
}

__global__ __launch_bounds__(256) void k_scan1(const int* __restrict__ cnt, int N,
                                               int* __restrict__ bsum) {
    __shared__ int s[256];
    int i = blockIdx.x * 256 + threadIdx.x;
    s[threadIdx.x] = (i < N) ? cnt[i] : 0;
    __syncthreads();
    for (int off = 128; off > 0; off >>= 1) {
        if (threadIdx.x < off) s[threadIdx.x] += s[threadIdx.x + off];
        __syncthreads();
    }
    if (threadIdx.x == 0) bsum[blockIdx.x] = s[0];
}

__global__ __launch_bounds__(512) void k_scan2(int* __restrict__ bsum, int nb) {
    __shared__ int s[512];
    int t = threadIdx.x;
    int v = (t < nb) ? bsum[t] : 0;
    s[t] = v;
    __syncthreads();
    for (int off = 1; off < 512; off <<= 1) {
        int add = (t >= off) ? s[t - off] : 0;
        __syncthreads();
        s[t] += add;
        __syncthreads();
    }
    if (t < nb) bsum[t] = s[t] - v;  // exclusive
}

__global__ __launch_bounds__(256) void k_scan3(const int* __restrict__ cnt, int N,
                                               const int* __restrict__ bsum,
                                               int* __restrict__ offs) {
    __shared__ int s[256];
    int i = blockIdx.x * 256 + threadIdx.x;
    int v = (i < N) ? cnt[i] : 0;
    s[threadIdx.x] = v;
    __syncthreads();
    for (int off = 1; off < 256; off <<= 1) {
        int add = (threadIdx.x >= off) ? s[threadIdx.x - off] : 0;
        __syncthreads();
        s[threadIdx.x] += add;
        __syncthreads();
    }
    if (i < N) offs[i] = bsum[blockIdx.x] + s[threadIdx.x] - v;
}

__global__ __launch_bounds__(256) void k_deginv(const int* __restrict__ cnt,
                                                const int* __restrict__ offs, int N,
                                                float* __restrict__ deg_inv,
                                                int* __restrict__ cursor) {
    int i = blockIdx.x * 256 + threadIdx.x;
    if (i < N) {
        int c = cnt[i];
        deg_inv[i] = (c > 0) ? 1.0f / (float)c : 0.0f;
        cursor[i] = offs[i];
    }
}

__global__ __launch_bounds__(256) void k_scatter(const int* __restrict__ eb, int E,
                                                 const int* __restrict__ mode, int N,
                                                 int* __restrict__ cursor,
                                                 int* __restrict__ csr_src) {
    int m = *mode;
    int e = blockIdx.x * THREADS + threadIdx.x;
    if (e < E) {
        int c = edge_get(eb, E, m, 1, e);
        if ((unsigned)c < (unsigned)N) {
            int r = edge_get(eb, E, m, 0, e);
            if ((unsigned)r >= (unsigned)N) r = 0;
            int pos = atomicAdd(&cursor[c], 1);
            csr_src[pos] = r;
        }
    }
}

// ---------------------------------------------------------------- weight prep (bf16, transposed)
__global__ __launch_bounds__(256) void k_prep_wqk(const float* __restrict__ Wq,
                                                  const float* __restrict__ Wk,
                                                  unsigned short* __restrict__ WqkT) {
    int i = blockIdx.x * 256 + threadIdx.x;  // 512*128
    if (i < 512 * 128) {
        int oc = i >> 7, k = i & 127;
        float v = (oc < 256) ? Wq[k * 256 + oc] : Wk[k * 256 + (oc - 256)];
        WqkT[i] = f2bf(v);
    }
}

__global__ __launch_bounds__(256) void k_prep_wo(const float* __restrict__ Wo,
                                                 unsigned short* __restrict__ WoT) {
    int i = blockIdx.x * 256 + threadIdx.x;  // 1280*128
    if (i < 1280 * 128) {
        int r = i >> 7, j = i & 127;
        WoT[(size_t)j * 1280 + r] = f2bf(Wo[i]);
    }
}

// ---------------------------------------------------------------- Q/K proj + row L2-norm (MFMA, atomic-free)
__global__ __launch_bounds__(256) void k_proj(const float* __restrict__ x,
                                              const unsigned short* __restrict__ WqkT,
                                              const float* __restrict__ bq,
                                              const float* __restrict__ bk,
                                              unsigned short* __restrict__ qs,
                                              unsigned short* __restrict__ ks, int N) {
    __shared__ unsigned short xs[64 * 128];  // 16 KB input staging
    __shared__ unsigned short os[64 * 256];  // 32 KB output staging
    const int t = threadIdx.x;
    const int n0 = blockIdx.x * 64;
#pragma unroll
    for (int i = 0; i < 4; i++) {
        int chunk = i * 256 + t;
        int r = chunk >> 4, c0 = (chunk & 15) * 8;
        float4 a0 = make_float4(0.f, 0.f, 0.f, 0.f), a1 = a0;
        if (n0 + r < N) {
            a0 = ld4f(&x[(size_t)(n0 + r) * 128 + c0]);
            a1 = ld4f(&x[(size_t)(n0 + r) * 128 + c0 + 4]);
        }
        short8 v = {(short)f2bf(a0.x), (short)f2bf(a0.y), (short)f2bf(a0.z), (short)f2bf(a0.w),
                    (short)f2bf(a1.x), (short)f2bf(a1.y), (short)f2bf(a1.z), (short)f2bf(a1.w)};
        int byte = r * 256 + ((c0 * 2) ^ ((r & 7) << 4));
        *reinterpret_cast<short8*>(reinterpret_cast<char*>(xs) + byte) = v;
    }
    __syncthreads();
    const int w = t >> 6, l = t & 63, lrow = l & 15, lhi = l >> 4;
    f32x4 acc[4][8];
    const f32x4 fz = {0.f, 0.f, 0.f, 0.f};
#pragma unroll
    for (int mt = 0; mt < 4; mt++)
#pragma unroll
        for (int nt = 0; nt < 8; nt++) acc[mt][nt] = fz;

    for (int kk = 0; kk < 4; kk++) {
        int kb = kk * 32 + lhi * 8;
        short8 af[4];
#pragma unroll
        for (int mt = 0; mt < 4; mt++) {
            int r = mt * 16 + lrow;
            af[mt] = *reinterpret_cast<const short8*>(
                reinterpret_cast<const char*>(xs) + r * 256 + ((kb * 2) ^ ((r & 7) << 4)));
        }
#pragma unroll
        for (int nt = 0; nt < 8; nt++) {
            int oc = w * 128 + nt * 16 + lrow;
            short8 bf = *reinterpret_cast<const short8*>(&WqkT[(size_t)oc * 128 + kb]);
#pragma unroll
            for (int mt = 0; mt < 4; mt++)
                acc[mt][nt] = __builtin_amdgcn_mfma_f32_16x16x32_bf16(af[mt], bf, acc[mt][nt], 0, 0, 0);
        }
    }
    // bias
#pragma unroll
    for (int nt = 0; nt < 8; nt++) {
        int oc = w * 128 + nt * 16 + lrow;
        float b = (oc < 256) ? bq[oc] : bk[oc - 256];
#pragma unroll
        for (int mt = 0; mt < 4; mt++)
#pragma unroll
            for (int reg = 0; reg < 4; reg++) acc[mt][nt][reg] += b;
    }
    // row-norm in registers
    const int hc = (w & 1) * 128;
    float rv[4][4];
#pragma unroll
    for (int mt = 0; mt < 4; mt++) {
        float ss[4] = {0.f, 0.f, 0.f, 0.f};
#pragma unroll
        for (int nt = 0; nt < 8; nt++)
#pragma unroll
            for (int reg = 0; reg < 4; reg++) ss[reg] += acc[mt][nt][reg] * acc[mt][nt][reg];
#pragma unroll
        for (int m_ = 1; m_ < 16; m_ <<= 1)
#pragma unroll
            for (int reg = 0; reg < 4; reg++) ss[reg] += __shfl_xor(ss[reg], m_);
#pragma unroll
        for (int reg = 0; reg < 4; reg++) rv[mt][reg] = rsqrtf(ss[reg]);
    }
    // two passes: pass0 waves 0,1 (q) -> os -> coalesced global; pass1 waves 2,3 (k)
    for (int pass = 0; pass < 2; pass++) {
        if ((w >> 1) == pass) {
#pragma unroll
            for (int mt = 0; mt < 4; mt++)
#pragma unroll
                for (int reg = 0; reg < 4; reg++) {
                    int r = mt * 16 + lhi * 4 + reg;
#pragma unroll
                    for (int nt = 0; nt < 8; nt++)
                        os[r * 256 + hc + nt * 16 + lrow] = f2bf(acc[mt][nt][reg] * rv[mt][reg]);
                }
        }
        __syncthreads();
        unsigned short* dstg = pass ? ks : qs;
#pragma unroll
        for (int i = 0; i < 8; i++) {
            int chunk = i * 256 + t;
            int r = chunk >> 5, c = (chunk & 31) * 8;
            int n = n0 + r;
            if (n < N)
                *reinterpret_cast<short8*>(&dstg[(size_t)n * 256 + c]) =
                    *reinterpret_cast<const short8*>(&os[r * 256 + c]);
        }
        __syncthreads();
    }
}

// ---------------------------------------------------------------- ks_sum: 2-stage column reduction
__global__ __launch_bounds__(256) void k_colsum(const unsigned short* __restrict__ ks, int N,
                                                float* __restrict__ part) {
    const int t = threadIdx.x;
    const int stride = (N + 255) >> 8;
    int r0 = blockIdx.x * stride;
    int rend = min(r0 + stride, N);
    float s = 0.f;
    for (int n = r0; n < rend; n++) s += bf2f(ks[(size_t)n * 256 + t]);
    part[blockIdx.x * 256 + t] = s;
}

__global__ __launch_bounds__(256) void k_colsum2(const float* __restrict__ part,
                                                 float* __restrict__ ks_sum) {
    const int t = threadIdx.x;
    float s = 0.f;
    for (int b = 0; b < 256; b++) s += part[b * 256 + t];
    ks_sum[t] = s;
}

// ---------------------------------------------------------------- den = qs . ks_sum + N
__global__ __launch_bounds__(256) void k_den(const unsigned short* __restrict__ qs,
                                             const float* __restrict__ ks_sum,
                                             float* __restrict__ den, int N) {
    int w = threadIdx.x >> 6, lane = threadIdx.x & 63;
    int n = blockIdx.x * 4 + w;
    if (n >= N) return;
    float4 q = ld4f(&qs[(size_t)n * 256 + lane * 4]);
    float4 kv = *reinterpret_cast<const float4*>(&ks_sum[lane * 4]);
    float s = q.x * kv.x + q.y * kv.y + q.z * kv.z + q.w * kv.w;
#pragma unroll
    for (int off = 1; off < 32; off <<= 1) s += __shfl_xor(s, off);
    if ((lane & 31) == 0) den[n * 2 + (lane >> 5)] = s + (float)N;
}

// ---------------------------------------------------------------- kvsT = vs^T @ ks per head (MFMA split-K)
__device__ __forceinline__ short8 frag_ld(const unsigned short* tile, int kb, int col) {
    const char* b = reinterpret_cast<const char*>(tile);
    int cb = (col * 2) ^ (((kb >> 3) & 3) << 5);
    short8 r;
#pragma unroll
    for (int i = 0; i < 8; i++)
        r[i] = (short)*reinterpret_cast<const unsigned short*>(b + (kb + i) * 512 + cb);
    return r;
}

template <typename TV>
__global__ __launch_bounds__(256) void k_kvs2(const unsigned short* __restrict__ ks,
                                              const TV* __restrict__ vs, int vstride, int vmask,
                                              float* __restrict__ partial,
                                              float* __restrict__ pvsum, int rows_per, int N) {
    __shared__ unsigned short kt[32 * 256];
    __shared__ unsigned short vt[32 * 256];
    __shared__ float vred[8][256];
    const int t = threadIdx.x;
    const int w = t >> 6, l = t & 63, lrow = l & 15, lhi = l >> 4;
    const int h = w >> 1, mhalf = w & 1;
    const int r0 = blockIdx.x * rows_per;
    const int rend = min(r0 + rows_per, N);

    const f32x4 fz = {0.f, 0.f, 0.f, 0.f};
    f32x4 acc[4][8];
#pragma unroll
    for (int mt = 0; mt < 4; mt++)
#pragma unroll
        for (int nt = 0; nt < 8; nt++) acc[mt][nt] = fz;
    float vsum8[8] = {0.f, 0.f, 0.f, 0.f, 0.f, 0.f, 0.f, 0.f};

    for (int c0 = r0; c0 < rend; c0 += 32) {
#pragma unroll
        for (int i = 0; i < 4; i++) {
            int chunk = i * 256 + t;
            int n = chunk >> 5, cc = (chunk & 31) * 8;
            short8 v = {0, 0, 0, 0, 0, 0, 0, 0};
            if (c0 + n < rend)
                v = *reinterpret_cast<const short8*>(&ks[(size_t)(c0 + n) * 256 + cc]);
            *reinterpret_cast<short8*>(reinterpret_cast<char*>(kt) + n * 512 +
                                       ((cc * 2) ^ (((n >> 3) & 3) << 5))) = v;
        }
#pragma unroll
        for (int i = 0; i < 4; i++) {
            int chunk = i * 256 + t;
            int n = chunk >> 5, cc = (chunk & 31) * 8;
            float4 a0 = make_float4(0.f, 0.f, 0.f, 0.f), a1 = a0;
            if (c0 + n < rend) {
                a0 = ld4f(&vs[(size_t)(c0 + n) * vstride + (cc & vmask)]);
                a1 = ld4f(&vs[(size_t)(c0 + n) * vstride + ((cc + 4) & vmask)]);
            }
            unsigned short u0 = f2bf(a0.x), u1 = f2bf(a0.y), u2 = f2bf(a0.z), u3 = f2bf(a0.w);
            unsigned short u4 = f2bf(a1.x), u5 = f2bf(a1.y), u6 = f2bf(a1.z), u7 = f2bf(a1.w);
            vsum8[0] += bf2f(u0); vsum8[1] += bf2f(u1); vsum8[2] += bf2f(u2); vsum8[3] += bf2f(u3);
            vsum8[4] += bf2f(u4); vsum8[5] += bf2f(u5); vsum8[6] += bf2f(u6); vsum8[7] += bf2f(u7);
            short8 v = {(short)u0, (short)u1, (short)u2, (short)u3,
                        (short)u4, (short)u5, (short)u6, (short)u7};
            *reinterpret_cast<short8*>(reinterpret_cast<char*>(vt) + n * 512 +
                                       ((cc * 2) ^ (((n >> 3) & 3) << 5))) = v;
        }
        __syncthreads();
        {
            int kb = lhi * 8;
            short8 af[4];
#pragma unroll
            for (int mt = 0; mt < 4; mt++)
                af[mt] = frag_ld(vt, kb, h * 128 + mhalf * 64 + mt * 16 + lrow);
#pragma unroll
            for (int nt = 0; nt < 8; nt++) {
                short8 bf = frag_ld(kt, kb, h * 128 + nt * 16 + lrow);
#pragma unroll
                for (int mt = 0; mt < 4; mt++)
                    acc[mt][nt] =
                        __builtin_amdgcn_mfma_f32_16x16x32_bf16(af[mt], bf, acc[mt][nt], 0, 0, 0);
            }
        }
        __syncthreads();
    }
    float* pb = &partial[((size_t)blockIdx.x * 2 + h) * 16384];
#pragma unroll
    for (int mt = 0; mt < 4; mt++)
#pragma unroll
        for (int reg = 0; reg < 4; reg++) {
            int c_local = mhalf * 64 + mt * 16 + lhi * 4 + reg;
#pragma unroll
            for (int nt = 0; nt < 8; nt++) pb[c_local * 128 + nt * 16 + lrow] = acc[mt][nt][reg];
        }
    {
        int cc = (t & 31) * 8;
#pragma unroll
        for (int j = 0; j < 8; j++) vred[t >> 5][cc + j] = vsum8[j];
        __syncthreads();
        float s = 0.f;
#pragma unroll
        for (int r = 0; r < 8; r++) s += vred[r][t];
        pvsum[blockIdx.x * 256 + t] = s;
    }
}

__global__ __launch_bounds__(256) void k_kvred(const float* __restrict__ partial, int S,
                                               unsigned short* __restrict__ kvsT) {
    int e = blockIdx.x * 256 + threadIdx.x;  // 32768 elems
    float s = 0.f;
    for (int i = 0; i < S; i++) s += partial[(size_t)i * 32768 + e];
    kvsT[e] = f2bf(s);
}

__global__ __launch_bounds__(256) void k_vsred(const float* __restrict__ pvsum, int S,
                                               float* __restrict__ vs_sum) {
    int c = threadIdx.x;
    float s = 0.f;
    for (int i = 0; i < S; i++) s += pvsum[i * 256 + c];
    vs_sum[c] = s;
}

// ---------------------------------------------------------------- GCN gather v2: wave-per-row, 8B/lane, 8-deep MLP
// bf16 prev [N][256]: lane l owns channels 4l..4l+3 (ushort4 = 8B); wave covers full 512B row.
__global__ __launch_bounds__(256) void k_gather2(const unsigned short* __restrict__ prev,
                                                 const int* __restrict__ csr_src,
                                                 const int* __restrict__ offs,
                                                 const int* __restrict__ cnt,
                                                 const float* __restrict__ deg_inv,
                                                 unsigned short* __restrict__ cur, int N) {
    const int w = threadIdx.x >> 6, l = threadIdx.x & 63;
    int n = blockIdx.x * 4 + w;
    if (n >= N) return;
    const int start = offs[n], d = cnt[n];
    int e = start;
    const int eend = start + d;
    float a0 = 0.f, a1 = 0.f, a2 = 0.f, a3 = 0.f;
    const int co = l * 4;
    for (; e + 8 <= eend; e += 8) {
        int s[8];
#pragma unroll
        for (int i = 0; i < 8; i++) s[i] = csr_src[e + i];
        ushort4 u[8];
#pragma unroll
        for (int i = 0; i < 8; i++)
            u[i] = *reinterpret_cast<const ushort4*>(&prev[(size_t)s[i] * 256 + co]);
#pragma unroll
        for (int i = 0; i < 8; i++) {
            a0 += bf2f(u[i].x); a1 += bf2f(u[i].y); a2 += bf2f(u[i].z); a3 += bf2f(u[i].w);
        }
    }
    for (; e < eend; e++) {
        ushort4 u = *reinterpret_cast<const ushort4*>(&prev[(size_t)csr_src[e] * 256 + co]);
        a0 += bf2f(u.x); a1 += bf2f(u.y); a2 += bf2f(u.z); a3 += bf2f(u.w);
    }
    float sc = 0.5f * deg_inv[n];
    ushort4 o;
    o.x = f2bf(a0 * sc); o.y = f2bf(a1 * sc); o.z = f2bf(a2 * sc); o.w = f2bf(a3 * sc);
    *reinterpret_cast<ushort4*>(&cur[(size_t)n * 256 + co]) = o;
}

// f32 variant (hop 1, prev = x [N][128], head-broadcast): lane l owns channels 2l,2l+1 (+128 dup)
__global__ __launch_bounds__(256) void k_gather2f(const float* __restrict__ prev,
                                                  const int* __restrict__ csr_src,
                                                  const int* __restrict__ offs,
                                                  const int* __restrict__ cnt,
                                                  const float* __restrict__ deg_inv,
                                                  unsigned short* __restrict__ cur, int N) {
    const int w = threadIdx.x >> 6, l = threadIdx.x & 63;
    int n = blockIdx.x * 4 + w;
    if (n >= N) return;
    const int start = offs[n], d = cnt[n];
    int e = start;
    const int eend = start + d;
    float a0 = 0.f, a1 = 0.f;
    const int co = l * 2;
    for (; e + 8 <= eend; e += 8) {
        int s[8];
#pragma unroll
        for (int i = 0; i < 8; i++) s[i] = csr_src[e + i];
        float2 u[8];
#pragma unroll
        for (int i = 0; i < 8; i++)
            u[i] = *reinterpret_cast<const float2*>(&prev[(size_t)s[i] * 128 + co]);
#pragma unroll
        for (int i = 0; i < 8; i++) { a0 += u[i].x; a1 += u[i].y; }
    }
    for (; e < eend; e++) {
        float2 u = *reinterpret_cast<const float2*>(&prev[(size_t)csr_src[e] * 128 + co]);
        a0 += u.x; a1 += u.y;
    }
    float sc = 0.5f * deg_inv[n];
    ushort2 o;
    o.x = f2bf(a0 * sc); o.y = f2bf(a1 * sc);
    *reinterpret_cast<ushort2*>(&cur[(size_t)n * 256 + co]) = o;
    *reinterpret_cast<ushort2*>(&cur[(size_t)n * 256 + 128 + co]) = o;
}

// ---------------------------------------------------------------- fused: cur += (qs@kvs+vs_sum)/den ; out += 0.5*cur@Wo_blk
__global__ __launch_bounds__(256) void k_att_out(const unsigned short* __restrict__ qs,
                                                 const unsigned short* __restrict__ kvsT,
                                                 const float* __restrict__ vs_sum,
                                                 const float* __restrict__ den,
                                                 unsigned short* __restrict__ cur,
                                                 const unsigned short* __restrict__ WoT,
                                                 float* __restrict__ out, int tblk, int N) {
    __shared__ unsigned short sm[64 * 256];
    const int t = threadIdx.x;
    const int n0 = blockIdx.x * 64;
#pragma unroll
    for (int i = 0; i < 8; i++) {
        int chunk = i * 256 + t;
        int r = chunk >> 5, c0 = (chunk & 31) * 8;
        short8 v = {0, 0, 0, 0, 0, 0, 0, 0};
        if (n0 + r < N) v = *reinterpret_cast<const short8*>(&qs[(size_t)(n0 + r) * 256 + c0]);
        *reinterpret_cast<short8*>(reinterpret_cast<char*>(sm) + r * 512 +
                                   ((c0 * 2) ^ ((r & 7) << 4))) = v;
    }
    __syncthreads();
    const int w = t >> 6, l = t & 63, lrow = l & 15, lhi = l >> 4;
    const int h = w >> 1, jh = w & 1;
    const f32x4 fz = {0.f, 0.f, 0.f, 0.f};
    f32x4 acc[4][4];
#pragma unroll
    for (int mt = 0; mt < 4; mt++)
#pragma unroll
        for (int nt = 0; nt < 4; nt++) acc[mt][nt] = fz;

    for (int kk = 0; kk < 4; kk++) {
        int kb = kk * 32 + lhi * 8;
        short8 af[4];
#pragma unroll
        for (int mt = 0; mt < 4; mt++) {
            int r = mt * 16 + lrow;
            af[mt] = *reinterpret_cast<const short8*>(
                reinterpret_cast<const char*>(sm) + r * 512 +
                (((h * 128 + kb) * 2) ^ ((r & 7) << 4)));
        }
#pragma unroll
        for (int nt = 0; nt < 4; nt++) {
            int c = jh * 64 + nt * 16 + lrow;
            short8 bf = *reinterpret_cast<const short8*>(&kvsT[((size_t)h * 128 + c) * 128 + kb]);
#pragma unroll
            for (int mt = 0; mt < 4; mt++)
                acc[mt][nt] = __builtin_amdgcn_mfma_f32_16x16x32_bf16(af[mt], bf, acc[mt][nt], 0, 0, 0);
        }
    }
    __syncthreads();
#pragma unroll
    for (int mt = 0; mt < 4; mt++) {
#pragma unroll
        for (int reg = 0; reg < 4; reg++) {
            int r = mt * 16 + lhi * 4 + reg;
            int n = n0 + r;
            if (n < N) {
                float idn = 1.0f / den[n * 2 + h];
#pragma unroll
                for (int nt = 0; nt < 4; nt++) {
                    int c = h * 128 + jh * 64 + nt * 16 + lrow;
                    float g = bf2f(cur[(size_t)n * 256 + c]);
                    float v = g + (acc[mt][nt][reg] + vs_sum[c]) * idn;
                    unsigned short ub = f2bf(v);
                    cur[(size_t)n * 256 + c] = ub;
                    *reinterpret_cast<unsigned short*>(reinterpret_cast<char*>(sm) + r * 512 +
                                                       ((c * 2) ^ ((r & 7) << 4))) = ub;
                }
            }
        }
    }
    __syncthreads();
    f32x4 acc2[4][2];
#pragma unroll
    for (int mt = 0; mt < 4; mt++)
#pragma unroll
        for (int nt = 0; nt < 2; nt++) acc2[mt][nt] = fz;
    for (int kk = 0; kk < 8; kk++) {
        int kb = kk * 32 + lhi * 8;
        short8 af[4];
#pragma unroll
        for (int mt = 0; mt < 4; mt++) {
            int r = mt * 16 + lrow;
            af[mt] = *reinterpret_cast<const short8*>(
                reinterpret_cast<const char*>(sm) + r * 512 + ((kb * 2) ^ ((r & 7) << 4)));
        }
        int woff = (kb >> 7) * 640 + tblk * 128 + (kb & 127);
#pragma unroll
        for (int nt = 0; nt < 2; nt++) {
            int j = w * 32 + nt * 16 + lrow;
            short8 bf = *reinterpret_cast<const short8*>(&WoT[(size_t)j * 1280 + woff]);
#pragma unroll
            for (int mt = 0; mt < 4; mt++)
                acc2[mt][nt] = __builtin_amdgcn_mfma_f32_16x16x32_bf16(af[mt], bf, acc2[mt][nt], 0, 0, 0);
        }
    }
#pragma unroll
    for (int nt = 0; nt < 2; nt++) {
        int j = w * 32 + nt * 16 + lrow;
#pragma unroll
        for (int mt = 0; mt < 4; mt++)
#pragma unroll
            for (int reg = 0; reg < 4; reg++) {
                int n = n0 + mt * 16 + lhi * 4 + reg;
                if (n < N) out[(size_t)n * 128 + j] += 0.5f * acc2[mt][nt][reg];
            }
    }
}

// ---------------------------------------------------------------- term0: out = 0.5*([x|x]@Wo_0 + bias)
__global__ __launch_bounds__(256) void k_out0(const float* __restrict__ x,
                                              const unsigned short* __restrict__ WoT,
                                              const float* __restrict__ Wo_b,
                                              float* __restrict__ out, int N) {
    __shared__ unsigned short sm[64 * 256];
    const int t = threadIdx.x;
    const int n0 = blockIdx.x * 64;
#pragma unroll
    for (int i = 0; i < 8; i++) {
        int chunk = i * 256 + t;
        int r = chunk >> 5, c0 = (chunk & 31) * 8, cs = c0 & 127;
        float4 a0 = make_float4(0.f, 0.f, 0.f, 0.f), a1 = a0;
        if (n0 + r < N) {
            a0 = ld4f(&x[(size_t)(n0 + r) * 128 + cs]);
            a1 = ld4f(&x[(size_t)(n0 + r) * 128 + cs + 4]);
        }
        short8 v = {(short)f2bf(a0.x), (short)f2bf(a0.y), (short)f2bf(a0.z), (short)f2bf(a0.w),
                    (short)f2bf(a1.x), (short)f2bf(a1.y), (short)f2bf(a1.z), (short)f2bf(a1.w)};
        *reinterpret_cast<short8*>(reinterpret_cast<char*>(sm) + r * 512 +
                                   ((c0 * 2) ^ ((r & 7) << 4))) = v;
    }
    __syncthreads();
    const int w = t >> 6, l = t & 63, lrow = l & 15, lhi = l >> 4;
    const f32x4 fz = {0.f, 0.f, 0.f, 0.f};
    f32x4 acc2[4][2];
#pragma unroll
    for (int mt = 0; mt < 4; mt++)
#pragma unroll
        for (int nt = 0; nt < 2; nt++) acc2[mt][nt] = fz;
    for (int kk = 0; kk < 8; kk++) {
        int kb = kk * 32 + lhi * 8;
        short8 af[4];
#pragma unroll
        for (int mt = 0; mt < 4; mt++) {
            int r = mt * 16 + lrow;
            af[mt] = *reinterpret_cast<const short8*>(
                reinterpret_cast<const char*>(sm) + r * 512 + ((kb * 2) ^ ((r & 7) << 4)));
        }
        int woff = (kb >> 7) * 640 + (kb & 127);  // tblk = 0
#pragma unroll
        for (int nt = 0; nt < 2; nt++) {
            int j = w * 32 + nt * 16 + lrow;
            short8 bf = *reinterpret_cast<const short8*>(&WoT[(size_t)j * 1280 + woff]);
#pragma unroll
            for (int mt = 0; mt < 4; mt++)
                acc2[mt][nt] = __builtin_amdgcn_mfma_f32_16x16x32_bf16(af[mt], bf, acc2[mt][nt], 0, 0, 0);
        }
    }
#pragma unroll
    for (int nt = 0; nt < 2; nt++) {
        int j = w * 32 + nt * 16 + lrow;
        float b = Wo_b[j];
#pragma unroll
        for (int mt = 0; mt < 4; mt++)
#pragma unroll
            for (int reg = 0; reg < 4; reg++) {
                int n = n0 + mt * 16 + lhi * 4 + reg;
                if (n < N) out[(size_t)n * 128 + j] = 0.5f * (acc2[mt][nt][reg] + b);
            }
    }
}

// ================================================================ host
extern "C" void kernel_launch(void* const* d_in, const int* in_sizes, int n_in,
                              void* d_out, int out_size, void* d_ws, size_t ws_size,
                              hipStream_t stream) {
    const int N = in_sizes[0] / 128;
    const int E = in_sizes[1] / 2;
    const float* x = (const float*)d_in[0];
    const int* eraw = (const int*)d_in[1];
    const float* Wq_w = (const float*)d_in[2];
    const float* Wq_b = (const float*)d_in[3];
    const float* Wk_w = (const float*)d_in[4];
    const float* Wk_b = (const float*)d_in[5];
    const float* Wo_w = (const float*)d_in[6];
    const float* Wo_b = (const float*)d_in[7];
    float* out = (float*)d_out;

    char* p = (char*)d_ws;
    auto alloc = [&](size_t bytes) -> void* {
        void* r = (void*)p;
        p += (bytes + 255) & ~(size_t)255;
        return r;
    };
    unsigned short* qs = (unsigned short*)alloc((size_t)N * 256 * 2);
    unsigned short* ks = (unsigned short*)alloc((size_t)N * 256 * 2);
    unsigned short* bufA = (unsigned short*)alloc((size_t)N * 256 * 2);
    unsigned short* bufB = (unsigned short*)alloc((size_t)N * 256 * 2);
    float* deg_inv = (float*)alloc((size_t)N * 4);
    float* den = (float*)alloc((size_t)N * 2 * 4);
    float* ks_sum = (float*)alloc(256 * 4);
    float* vs_sum = (float*)alloc(256 * 4);
    float* colpart = (float*)alloc(256 * 256 * 4);
    unsigned short* WqkT = (unsigned short*)alloc(512 * 128 * 2);
    unsigned short* WoT = (unsigned short*)alloc(1280 * 128 * 2);
    unsigned short* kvsTb = (unsigned short*)alloc(32768 * 2);
    int* cnt = (int*)alloc((size_t)N * 4);
    int* offs = (int*)alloc((size_t)N * 4);
    int* cursor = (int*)alloc((size_t)N * 4);
    int* bsum = (int*)alloc(512 * 4);
    int* mode = (int*)alloc(256);
    int* csr = (int*)alloc((size_t)E * 4);

    size_t used = (size_t)(p - (char*)d_ws);
    size_t rem = (ws_size > used + (1 << 20)) ? ws_size - used - (1 << 20) : 0;
    int S = (int)(rem / (32768 * 4 + 1024));
    if (S > 256) S = 256;
    if (S < 8) S = 8;
    float* partial = (float*)alloc((size_t)S * 32768 * 4);
    float* pvsum = (float*)alloc((size_t)S * 256 * 4);
    const int rows_per = (N + S - 1) / S;

    hipMemsetAsync(cnt, 0, (size_t)N * 4, stream);

    const int nb = (N + 255) / 256;
    const int eb = (E + 255) / 256;
    k_detect<<<1, 256, 0, stream>>>(eraw, E, mode);
    k_count<<<eb, 256, 0, stream>>>(eraw, E, mode, N, cnt);
    k_scan1<<<nb, 256, 0, stream>>>(cnt, N, bsum);
    k_scan2<<<1, 512, 0, stream>>>(bsum, nb);
    k_scan3<<<nb, 256, 0, stream>>>(cnt, N, bsum, offs);
    k_deginv<<<nb, 256, 0, stream>>>(cnt, offs, N, deg_inv, cursor);
    k_scatter<<<eb, 256, 0, stream>>>(eraw, E, mode, N, cursor, csr);

    k_prep_wqk<<<256, 256, 0, stream>>>(Wq_w, Wk_w, WqkT);
    k_prep_wo<<<640, 256, 0, stream>>>(Wo_w, WoT);

    const int nb64 = (N + 63) / 64;
    k_proj<<<nb64, 256, 0, stream>>>(x, WqkT, Wq_b, Wk_b, qs, ks, N);
    k_colsum<<<256, 256, 0, stream>>>(ks, N, colpart);
    k_colsum2<<<1, 256, 0, stream>>>(colpart, ks_sum);
    k_den<<<(N + 3) / 4, 256, 0, stream>>>(qs, ks_sum, den, N);
    k_out0<<<nb64, 256, 0, stream>>>(x, WoT, Wo_b, out, N);

    const int gb4 = (N + 3) / 4;

    // hop 1: prev = x (f32, stride 128, head-broadcast)
    k_kvs2<float><<<S, 256, 0, stream>>>(ks, x, 128, 127, partial, pvsum, rows_per, N);
    k_kvred<<<128, 256, 0, stream>>>(partial, S, kvsTb);
    k_vsred<<<1, 256, 0, stream>>>(pvsum, S, vs_sum);
    k_gather2f<<<gb4, 256, 0, stream>>>(x, csr, offs, cnt, deg_inv, bufA, N);
    k_att_out<<<nb64, 256, 0, stream>>>(qs, kvsTb, vs_sum, den, bufA, WoT, out, 1, N);

    // hops 2..4
    unsigned short* prev = bufA;
    unsigned short* cur = bufB;
    for (int step = 2; step <= 4; step++) {
        k_kvs2<unsigned short><<<S, 256, 0, stream>>>(ks, prev, 256, 255, partial, pvsum, rows_per,
                                                      N);
        k_kvred<<<128, 256, 0, stream>>>(partial, S, kvsTb);
        k_vsred<<<1, 256, 0, stream>>>(pvsum, S, vs_sum);
        k_gather2<<<gb4, 256, 0, stream>>>(prev, csr, offs, cnt, deg_inv, cur, N);
        k_att_out<<<nb64, 256, 0, stream>>>(qs, kvsTb, vs_sum, den, cur, WoT, out, step, N);
        unsigned short* tmp = prev;
        prev = cur;
        cur = tmp;
    }
}

// Round 7
// 1795.450 us; speedup vs baseline: 1.6978x; 1.1700x over previous
//
#include <hip/hip_runtime.h>

#define THREADS 256
#define NB 512
#define SEGCAP 6144

typedef __attribute__((ext_vector_type(8))) short short8;
typedef __attribute__((ext_vector_type(4))) float f32x4;

// ---------------------------------------------------------------- bf16 helpers (raw ushort storage)
__device__ __forceinline__ float bf2f(unsigned short u) {
    union { unsigned int i; float f; } v;
    v.i = ((unsigned int)u) << 16;
    return v.f;
}
__device__ __forceinline__ unsigned short f2bf(float f) {
    union { float f; unsigned int i; } v;
    v.f = f;
    unsigned int r = (v.i + 0x7FFFu + ((v.i >> 16) & 1u)) >> 16;  // RNE
    return (unsigned short)r;
}
__device__ __forceinline__ float4 ld4f(const float* p) {
    return *reinterpret_cast<const float4*>(p);
}
__device__ __forceinline__ float4 ld4f(const unsigned short* p) {
    ushort4 u = *reinterpret_cast<const ushort4*>(p);
    return make_float4(bf2f(u.x), bf2f(u.y), bf2f(u.z), bf2f(u.w));
}

// ---------------------------------------------------------------- edge accessor (int32 or int64 payload)
__device__ __forceinline__ int edge_get(const int* base, int E, int mode, int which, int e) {
    size_t idx = (size_t)which * (size_t)E + (size_t)e;
    return mode ? base[2 * idx] : base[idx];
}

__global__ __launch_bounds__(256) void k_detect(const int* __restrict__ e, int E,
                                                int* __restrict__ mode) {
    __shared__ int nz;
    if (threadIdx.x == 0) nz = 0;
    __syncthreads();
    int lim = 2 * E;
    if (lim > 8192) lim = 8192;
    for (int i = 1 + 2 * (int)threadIdx.x; i < lim; i += 512)
        if (e[i] != 0) nz = 1;
    __syncthreads();
    if (threadIdx.x == 0) *mode = (nz == 0) ? 1 : 0;
}

// ---------------------------------------------------------------- graph prep v2: bucket partition CSR build
__global__ __launch_bounds__(256) void k_hist(const int* __restrict__ eb, int E,
                                              const int* __restrict__ mode, int N, int CW, int epb,
                                              int* __restrict__ gcnt) {
    __shared__ int hist[NB];
    for (int i = threadIdx.x; i < NB; i += 256) hist[i] = 0;
    __syncthreads();
    int m = *mode;
    int e0 = blockIdx.x * epb;
    int e1 = min(e0 + epb, E);
    for (int e = e0 + threadIdx.x; e < e1; e += 256) {
        int c = edge_get(eb, E, m, 1, e);
        if ((unsigned)c < (unsigned)N) atomicAdd(&hist[c / CW], 1);
    }
    __syncthreads();
    for (int i = threadIdx.x; i < NB; i += 256)
        if (hist[i]) atomicAdd(&gcnt[i], hist[i]);
}

__global__ __launch_bounds__(NB) void k_bscan(const int* __restrict__ gcnt,
                                              int* __restrict__ gbase, int* __restrict__ gcursor) {
    __shared__ int s[NB];
    int t = threadIdx.x;
    int v = gcnt[t];
    s[t] = v;
    __syncthreads();
    for (int off = 1; off < NB; off <<= 1) {
        int add = (t >= off) ? s[t - off] : 0;
        __syncthreads();
        s[t] += add;
        __syncthreads();
    }
    gbase[t] = s[t] - v;
    gcursor[t] = s[t] - v;
}

__global__ __launch_bounds__(256) void k_part(const int* __restrict__ eb, int E,
                                              const int* __restrict__ mode, int N, int CW, int epb,
                                              int* __restrict__ gcursor, uint2* __restrict__ ebuf) {
    __shared__ int hist[NB];
    __shared__ int base[NB];
    for (int i = threadIdx.x; i < NB; i += 256) hist[i] = 0;
    __syncthreads();
    int m = *mode;
    int e0 = blockIdx.x * epb;
    int e1 = min(e0 + epb, E);
    for (int e = e0 + threadIdx.x; e < e1; e += 256) {
        int c = edge_get(eb, E, m, 1, e);
        if ((unsigned)c < (unsigned)N) atomicAdd(&hist[c / CW], 1);
    }
    __syncthreads();
    for (int i = threadIdx.x; i < NB; i += 256) {
        int h = hist[i];
        base[i] = h ? atomicAdd(&gcursor[i], h) : 0;
        hist[i] = 0;  // reuse as local cursor
    }
    __syncthreads();
    for (int e = e0 + threadIdx.x; e < e1; e += 256) {
        int c = edge_get(eb, E, m, 1, e);
        if ((unsigned)c < (unsigned)N) {
            int r = edge_get(eb, E, m, 0, e);
            if ((unsigned)r >= (unsigned)N) r = 0;
            int b = c / CW;
            int li = atomicAdd(&hist[b], 1);
            ebuf[(size_t)base[b] + li] = make_uint2((unsigned)r, (unsigned)c);
        }
    }
}

__global__ __launch_bounds__(256) void k_build(const uint2* __restrict__ ebuf,
                                               const int* __restrict__ gbase,
                                               const int* __restrict__ gcnt, int N, int CW,
                                               int* __restrict__ cnt, int* __restrict__ offs,
                                               float* __restrict__ deg_inv, int* __restrict__ csr) {
    __shared__ int hist[256];
    __shared__ int pfx[256];
    __shared__ int seg[SEGCAP];
    const int b = blockIdx.x;
    const int col0 = b * CW;
    const int ncols = min(CW, N - col0);
    if (ncols <= 0) return;
    const int ebase = gbase[b], ecnt = gcnt[b];
    const int t = threadIdx.x;
    for (int i = t; i < 256; i += 256) hist[i] = 0;
    __syncthreads();
    for (int e = t; e < ecnt; e += 256) {
        uint2 rc = ebuf[(size_t)ebase + e];
        atomicAdd(&hist[rc.y - col0], 1);
    }
    __syncthreads();
    int v = (t < ncols) ? hist[t] : 0;
    pfx[t] = v;
    __syncthreads();
    for (int off = 1; off < 256; off <<= 1) {
        int add = (t >= off) ? pfx[t - off] : 0;
        __syncthreads();
        pfx[t] += add;
        __syncthreads();
    }
    int excl = pfx[t] - v;
    if (t < ncols) {
        cnt[col0 + t] = v;
        offs[col0 + t] = ebase + excl;
        deg_inv[col0 + t] = (v > 0) ? 1.0f / (float)v : 0.0f;
    }
    __syncthreads();
    if (t < 256) hist[t] = (t < ncols) ? excl : 0;  // reuse as per-col cursor (bucket-local)
    __syncthreads();
    if (ecnt <= SEGCAP) {
        for (int e = t; e < ecnt; e += 256) {
            uint2 rc = ebuf[(size_t)ebase + e];
            int li = atomicAdd(&hist[rc.y - col0], 1);
            seg[li] = (int)rc.x;
        }
        __syncthreads();
        for (int e = t; e < ecnt; e += 256) csr[(size_t)ebase + e] = seg[e];
    } else {  // statistical overflow fallback (never taken for random graphs)
        for (int e = t; e < ecnt; e += 256) {
            uint2 rc = ebuf[(size_t)ebase + e];
            int li = atomicAdd(&hist[rc.y - col0], 1);
            csr[(size_t)ebase + li] = (int)rc.x;
        }
    }
}

// ---------------------------------------------------------------- weight prep (bf16, transposed)
__global__ __launch_bounds__(256) void k_prep_wqk(const float* __restrict__ Wq,
                                                  const float* __restrict__ Wk,
                                                  unsigned short* __restrict__ WqkT) {
    int i = blockIdx.x * 256 + threadIdx.x;  // 512*128
    if (i < 512 * 128) {
        int oc = i >> 7, k = i & 127;
        float v = (oc < 256) ? Wq[k * 256 + oc] : Wk[k * 256 + (oc - 256)];
        WqkT[i] = f2bf(v);
    }
}

__global__ __launch_bounds__(256) void k_prep_wo(const float* __restrict__ Wo,
                                                 unsigned short* __restrict__ WoT) {
    int i = blockIdx.x * 256 + threadIdx.x;  // 1280*128
    if (i < 1280 * 128) {
        int r = i >> 7, j = i & 127;
        WoT[(size_t)j * 1280 + r] = f2bf(Wo[i]);
    }
}

// ---------------------------------------------------------------- Q/K proj + row L2-norm (MFMA, atomic-free)
__global__ __launch_bounds__(256) void k_proj(const float* __restrict__ x,
                                              const unsigned short* __restrict__ WqkT,
                                              const float* __restrict__ bq,
                                              const float* __restrict__ bk,
                                              unsigned short* __restrict__ qs,
                                              unsigned short* __restrict__ ks, int N) {
    __shared__ unsigned short xs[64 * 128];  // 16 KB input staging
    __shared__ unsigned short os[64 * 256];  // 32 KB output staging
    const int t = threadIdx.x;
    const int n0 = blockIdx.x * 64;
#pragma unroll
    for (int i = 0; i < 4; i++) {
        int chunk = i * 256 + t;
        int r = chunk >> 4, c0 = (chunk & 15) * 8;
        float4 a0 = make_float4(0.f, 0.f, 0.f, 0.f), a1 = a0;
        if (n0 + r < N) {
            a0 = ld4f(&x[(size_t)(n0 + r) * 128 + c0]);
            a1 = ld4f(&x[(size_t)(n0 + r) * 128 + c0 + 4]);
        }
        short8 v = {(short)f2bf(a0.x), (short)f2bf(a0.y), (short)f2bf(a0.z), (short)f2bf(a0.w),
                    (short)f2bf(a1.x), (short)f2bf(a1.y), (short)f2bf(a1.z), (short)f2bf(a1.w)};
        int byte = r * 256 + ((c0 * 2) ^ ((r & 7) << 4));
        *reinterpret_cast<short8*>(reinterpret_cast<char*>(xs) + byte) = v;
    }
    __syncthreads();
    const int w = t >> 6, l = t & 63, lrow = l & 15, lhi = l >> 4;
    f32x4 acc[4][8];
    const f32x4 fz = {0.f, 0.f, 0.f, 0.f};
#pragma unroll
    for (int mt = 0; mt < 4; mt++)
#pragma unroll
        for (int nt = 0; nt < 8; nt++) acc[mt][nt] = fz;

    for (int kk = 0; kk < 4; kk++) {
        int kb = kk * 32 + lhi * 8;
        short8 af[4];
#pragma unroll
        for (int mt = 0; mt < 4; mt++) {
            int r = mt * 16 + lrow;
            af[mt] = *reinterpret_cast<const short8*>(
                reinterpret_cast<const char*>(xs) + r * 256 + ((kb * 2) ^ ((r & 7) << 4)));
        }
#pragma unroll
        for (int nt = 0; nt < 8; nt++) {
            int oc = w * 128 + nt * 16 + lrow;
            short8 bf = *reinterpret_cast<const short8*>(&WqkT[(size_t)oc * 128 + kb]);
#pragma unroll
            for (int mt = 0; mt < 4; mt++)
                acc[mt][nt] = __builtin_amdgcn_mfma_f32_16x16x32_bf16(af[mt], bf, acc[mt][nt], 0, 0, 0);
        }
    }
    // bias
#pragma unroll
    for (int nt = 0; nt < 8; nt++) {
        int oc = w * 128 + nt * 16 + lrow;
        float b = (oc < 256) ? bq[oc] : bk[oc - 256];
#pragma unroll
        for (int mt = 0; mt < 4; mt++)
#pragma unroll
            for (int reg = 0; reg < 4; reg++) acc[mt][nt][reg] += b;
    }
    // row-norm in registers
    const int hc = (w & 1) * 128;
    float rv[4][4];
#pragma unroll
    for (int mt = 0; mt < 4; mt++) {
        float ss[4] = {0.f, 0.f, 0.f, 0.f};
#pragma unroll
        for (int nt = 0; nt < 8; nt++)
#pragma unroll
            for (int reg = 0; reg < 4; reg++) ss[reg] += acc[mt][nt][reg] * acc[mt][nt][reg];
#pragma unroll
        for (int m_ = 1; m_ < 16; m_ <<= 1)
#pragma unroll
            for (int reg = 0; reg < 4; reg++) ss[reg] += __shfl_xor(ss[reg], m_);
#pragma unroll
        for (int reg = 0; reg < 4; reg++) rv[mt][reg] = rsqrtf(ss[reg]);
    }
    for (int pass = 0; pass < 2; pass++) {
        if ((w >> 1) == pass) {
#pragma unroll
            for (int mt = 0; mt < 4; mt++)
#pragma unroll
                for (int reg = 0; reg < 4; reg++) {
                    int r = mt * 16 + lhi * 4 + reg;
#pragma unroll
                    for (int nt = 0; nt < 8; nt++)
                        os[r * 256 + hc + nt * 16 + lrow] = f2bf(acc[mt][nt][reg] * rv[mt][reg]);
                }
        }
        __syncthreads();
        unsigned short* dstg = pass ? ks : qs;
#pragma unroll
        for (int i = 0; i < 8; i++) {
            int chunk = i * 256 + t;
            int r = chunk >> 5, c = (chunk & 31) * 8;
            int n = n0 + r;
            if (n < N)
                *reinterpret_cast<short8*>(&dstg[(size_t)n * 256 + c]) =
                    *reinterpret_cast<const short8*>(&os[r * 256 + c]);
        }
        __syncthreads();
    }
}

// ---------------------------------------------------------------- ks_sum: 2-stage column reduction
__global__ __launch_bounds__(256) void k_colsum(const unsigned short* __restrict__ ks, int N,
                                                float* __restrict__ part) {
    const int t = threadIdx.x;
    const int stride = (N + 255) >> 8;
    int r0 = blockIdx.x * stride;
    int rend = min(r0 + stride, N);
    float s = 0.f;
    for (int n = r0; n < rend; n++) s += bf2f(ks[(size_t)n * 256 + t]);
    part[blockIdx.x * 256 + t] = s;
}

__global__ __launch_bounds__(256) void k_colsum2(const float* __restrict__ part,
                                                 float* __restrict__ ks_sum) {
    const int t = threadIdx.x;
    float s = 0.f;
    for (int b = 0; b < 256; b++) s += part[b * 256 + t];
    ks_sum[t] = s;
}

// ---------------------------------------------------------------- den = qs . ks_sum + N
__global__ __launch_bounds__(256) void k_den(const unsigned short* __restrict__ qs,
                                             const float* __restrict__ ks_sum,
                                             float* __restrict__ den, int N) {
    int w = threadIdx.x >> 6, lane = threadIdx.x & 63;
    int n = blockIdx.x * 4 + w;
    if (n >= N) return;
    float4 q = ld4f(&qs[(size_t)n * 256 + lane * 4]);
    float4 kv = *reinterpret_cast<const float4*>(&ks_sum[lane * 4]);
    float s = q.x * kv.x + q.y * kv.y + q.z * kv.z + q.w * kv.w;
#pragma unroll
    for (int off = 1; off < 32; off <<= 1) s += __shfl_xor(s, off);
    if ((lane & 31) == 0) den[n * 2 + (lane >> 5)] = s + (float)N;
}

// ---------------------------------------------------------------- kvsT = vs^T @ ks per head (MFMA split-K)
__device__ __forceinline__ short8 frag_ld(const unsigned short* tile, int kb, int col) {
    const char* b = reinterpret_cast<const char*>(tile);
    int cb = (col * 2) ^ (((kb >> 3) & 3) << 5);
    short8 r;
#pragma unroll
    for (int i = 0; i < 8; i++)
        r[i] = (short)*reinterpret_cast<const unsigned short*>(b + (kb + i) * 512 + cb);
    return r;
}

template <typename TV>
__global__ __launch_bounds__(256) void k_kvs2(const unsigned short* __restrict__ ks,
                                              const TV* __restrict__ vs, int vstride, int vmask,
                                              float* __restrict__ partial,
                                              float* __restrict__ pvsum, int rows_per, int N) {
    __shared__ unsigned short kt[32 * 256];
    __shared__ unsigned short vt[32 * 256];
    __shared__ float vred[8][256];
    const int t = threadIdx.x;
    const int w = t >> 6, l = t & 63, lrow = l & 15, lhi = l >> 4;
    const int h = w >> 1, mhalf = w & 1;
    const int r0 = blockIdx.x * rows_per;
    const int rend = min(r0 + rows_per, N);

    const f32x4 fz = {0.f, 0.f, 0.f, 0.f};
    f32x4 acc[4][8];
#pragma unroll
    for (int mt = 0; mt < 4; mt++)
#pragma unroll
        for (int nt = 0; nt < 8; nt++) acc[mt][nt] = fz;
    float vsum8[8] = {0.f, 0.f, 0.f, 0.f, 0.f, 0.f, 0.f, 0.f};

    for (int c0 = r0; c0 < rend; c0 += 32) {
#pragma unroll
        for (int i = 0; i < 4; i++) {
            int chunk = i * 256 + t;
            int n = chunk >> 5, cc = (chunk & 31) * 8;
            short8 v = {0, 0, 0, 0, 0, 0, 0, 0};
            if (c0 + n < rend)
                v = *reinterpret_cast<const short8*>(&ks[(size_t)(c0 + n) * 256 + cc]);
            *reinterpret_cast<short8*>(reinterpret_cast<char*>(kt) + n * 512 +
                                       ((cc * 2) ^ (((n >> 3) & 3) << 5))) = v;
        }
#pragma unroll
        for (int i = 0; i < 4; i++) {
            int chunk = i * 256 + t;
            int n = chunk >> 5, cc = (chunk & 31) * 8;
            float4 a0 = make_float4(0.f, 0.f, 0.f, 0.f), a1 = a0;
            if (c0 + n < rend) {
                a0 = ld4f(&vs[(size_t)(c0 + n) * vstride + (cc & vmask)]);
                a1 = ld4f(&vs[(size_t)(c0 + n) * vstride + ((cc + 4) & vmask)]);
            }
            unsigned short u0 = f2bf(a0.x), u1 = f2bf(a0.y), u2 = f2bf(a0.z), u3 = f2bf(a0.w);
            unsigned short u4 = f2bf(a1.x), u5 = f2bf(a1.y), u6 = f2bf(a1.z), u7 = f2bf(a1.w);
            vsum8[0] += bf2f(u0); vsum8[1] += bf2f(u1); vsum8[2] += bf2f(u2); vsum8[3] += bf2f(u3);
            vsum8[4] += bf2f(u4); vsum8[5] += bf2f(u5); vsum8[6] += bf2f(u6); vsum8[7] += bf2f(u7);
            short8 v = {(short)u0, (short)u1, (short)u2, (short)u3,
                        (short)u4, (short)u5, (short)u6, (short)u7};
            *reinterpret_cast<short8*>(reinterpret_cast<char*>(vt) + n * 512 +
                                       ((cc * 2) ^ (((n >> 3) & 3) << 5))) = v;
        }
        __syncthreads();
        {
            int kb = lhi * 8;
            short8 af[4];
#pragma unroll
            for (int mt = 0; mt < 4; mt++)
                af[mt] = frag_ld(vt, kb, h * 128 + mhalf * 64 + mt * 16 + lrow);
#pragma unroll
            for (int nt = 0; nt < 8; nt++) {
                short8 bf = frag_ld(kt, kb, h * 128 + nt * 16 + lrow);
#pragma unroll
                for (int mt = 0; mt < 4; mt++)
                    acc[mt][nt] =
                        __builtin_amdgcn_mfma_f32_16x16x32_bf16(af[mt], bf, acc[mt][nt], 0, 0, 0);
            }
        }
        __syncthreads();
    }
    float* pb = &partial[((size_t)blockIdx.x * 2 + h) * 16384];
#pragma unroll
    for (int mt = 0; mt < 4; mt++)
#pragma unroll
        for (int reg = 0; reg < 4; reg++) {
            int c_local = mhalf * 64 + mt * 16 + lhi * 4 + reg;
#pragma unroll
            for (int nt = 0; nt < 8; nt++) pb[c_local * 128 + nt * 16 + lrow] = acc[mt][nt][reg];
        }
    {
        int cc = (t & 31) * 8;
#pragma unroll
        for (int j = 0; j < 8; j++) vred[t >> 5][cc + j] = vsum8[j];
        __syncthreads();
        float s = 0.f;
#pragma unroll
        for (int r = 0; r < 8; r++) s += vred[r][t];
        pvsum[blockIdx.x * 256 + t] = s;
    }
}

// fused kvsT + vs_sum reduction: blocks 0..127 reduce kvsT, block 128 reduces vs_sum
__global__ __launch_bounds__(256) void k_kvred(const float* __restrict__ partial,
                                               const float* __restrict__ pvsum, int S,
                                               unsigned short* __restrict__ kvsT,
                                               float* __restrict__ vs_sum) {
    if (blockIdx.x == 128) {
        int c = threadIdx.x;
        float s = 0.f;
        for (int i = 0; i < S; i++) s += pvsum[i * 256 + c];
        vs_sum[c] = s;
        return;
    }
    int e = blockIdx.x * 256 + threadIdx.x;  // 32768 elems
    float s = 0.f;
    for (int i = 0; i < S; i++) s += partial[(size_t)i * 32768 + e];
    kvsT[e] = f2bf(s);
}

// ---------------------------------------------------------------- GCN gather v2: wave-per-row, 8B/lane, 8-deep MLP
__global__ __launch_bounds__(256) void k_gather2(const unsigned short* __restrict__ prev,
                                                 const int* __restrict__ csr_src,
                                                 const int* __restrict__ offs,
                                                 const int* __restrict__ cnt,
                                                 const float* __restrict__ deg_inv,
                                                 unsigned short* __restrict__ cur, int N) {
    const int w = threadIdx.x >> 6, l = threadIdx.x & 63;
    int n = blockIdx.x * 4 + w;
    if (n >= N) return;
    const int start = offs[n], d = cnt[n];
    int e = start;
    const int eend = start + d;
    float a0 = 0.f, a1 = 0.f, a2 = 0.f, a3 = 0.f;
    const int co = l * 4;
    for (; e + 8 <= eend; e += 8) {
        int s[8];
#pragma unroll
        for (int i = 0; i < 8; i++) s[i] = csr_src[e + i];
        ushort4 u[8];
#pragma unroll
        for (int i = 0; i < 8; i++)
            u[i] = *reinterpret_cast<const ushort4*>(&prev[(size_t)s[i] * 256 + co]);
#pragma unroll
        for (int i = 0; i < 8; i++) {
            a0 += bf2f(u[i].x); a1 += bf2f(u[i].y); a2 += bf2f(u[i].z); a3 += bf2f(u[i].w);
        }
    }
    for (; e < eend; e++) {
        ushort4 u = *reinterpret_cast<const ushort4*>(&prev[(size_t)csr_src[e] * 256 + co]);
        a0 += bf2f(u.x); a1 += bf2f(u.y); a2 += bf2f(u.z); a3 += bf2f(u.w);
    }
    float sc = 0.5f * deg_inv[n];
    ushort4 o;
    o.x = f2bf(a0 * sc); o.y = f2bf(a1 * sc); o.z = f2bf(a2 * sc); o.w = f2bf(a3 * sc);
    *reinterpret_cast<ushort4*>(&cur[(size_t)n * 256 + co]) = o;
}

__global__ __launch_bounds__(256) void k_gather2f(const float* __restrict__ prev,
                                                  const int* __restrict__ csr_src,
                                                  const int* __restrict__ offs,
                                                  const int* __restrict__ cnt,
                                                  const float* __restrict__ deg_inv,
                                                  unsigned short* __restrict__ cur, int N) {
    const int w = threadIdx.x >> 6, l = threadIdx.x & 63;
    int n = blockIdx.x * 4 + w;
    if (n >= N) return;
    const int start = offs[n], d = cnt[n];
    int e = start;
    const int eend = start + d;
    float a0 = 0.f, a1 = 0.f;
    const int co = l * 2;
    for (; e + 8 <= eend; e += 8) {
        int s[8];
#pragma unroll
        for (int i = 0; i < 8; i++) s[i] = csr_src[e + i];
        float2 u[8];
#pragma unroll
        for (int i = 0; i < 8; i++)
            u[i] = *reinterpret_cast<const float2*>(&prev[(size_t)s[i] * 128 + co]);
#pragma unroll
        for (int i = 0; i < 8; i++) { a0 += u[i].x; a1 += u[i].y; }
    }
    for (; e < eend; e++) {
        float2 u = *reinterpret_cast<const float2*>(&prev[(size_t)csr_src[e] * 128 + co]);
        a0 += u.x; a1 += u.y;
    }
    float sc = 0.5f * deg_inv[n];
    ushort2 o;
    o.x = f2bf(a0 * sc); o.y = f2bf(a1 * sc);
    *reinterpret_cast<ushort2*>(&cur[(size_t)n * 256 + co]) = o;
    *reinterpret_cast<ushort2*>(&cur[(size_t)n * 256 + 128 + co]) = o;
}

// ---------------------------------------------------------------- fused: cur += (qs@kvs+vs_sum)/den ; out += 0.5*cur@Wo_blk
__global__ __launch_bounds__(256) void k_att_out(const unsigned short* __restrict__ qs,
                                                 const unsigned short* __restrict__ kvsT,
                                                 const float* __restrict__ vs_sum,
                                                 const float* __restrict__ den,
                                                 unsigned short* __restrict__ cur,
                                                 const unsigned short* __restrict__ WoT,
                                                 float* __restrict__ out, int tblk, int N) {
    __shared__ unsigned short sm[64 * 256];
    const int t = threadIdx.x;
    const int n0 = blockIdx.x * 64;
    // stage qs tile (64 x 256), swizzled
#pragma unroll
    for (int i = 0; i < 8; i++) {
        int chunk = i * 256 + t;
        int r = chunk >> 5, c0 = (chunk & 31) * 8;
        short8 v = {0, 0, 0, 0, 0, 0, 0, 0};
        if (n0 + r < N) v = *reinterpret_cast<const short8*>(&qs[(size_t)(n0 + r) * 256 + c0]);
        *reinterpret_cast<short8*>(reinterpret_cast<char*>(sm) + r * 512 +
                                   ((c0 * 2) ^ ((r & 7) << 4))) = v;
    }
    __syncthreads();
    const int w = t >> 6, l = t & 63, lrow = l & 15, lhi = l >> 4;
    const int h = w >> 1, jh = w & 1;
    const f32x4 fz = {0.f, 0.f, 0.f, 0.f};
    f32x4 acc[4][4];
#pragma unroll
    for (int mt = 0; mt < 4; mt++)
#pragma unroll
        for (int nt = 0; nt < 4; nt++) acc[mt][nt] = fz;

    for (int kk = 0; kk < 4; kk++) {
        int kb = kk * 32 + lhi * 8;
        short8 af[4];
#pragma unroll
        for (int mt = 0; mt < 4; mt++) {
            int r = mt * 16 + lrow;
            af[mt] = *reinterpret_cast<const short8*>(
                reinterpret_cast<const char*>(sm) + r * 512 +
                (((h * 128 + kb) * 2) ^ ((r & 7) << 4)));
        }
#pragma unroll
        for (int nt = 0; nt < 4; nt++) {
            int c = jh * 64 + nt * 16 + lrow;
            short8 bf = *reinterpret_cast<const short8*>(&kvsT[((size_t)h * 128 + c) * 128 + kb]);
#pragma unroll
            for (int mt = 0; mt < 4; mt++)
                acc[mt][nt] = __builtin_amdgcn_mfma_f32_16x16x32_bf16(af[mt], bf, acc[mt][nt], 0, 0, 0);
        }
    }
    __syncthreads();  // done reading qs from sm
    // stage cur into sm (coalesced), overwriting qs
#pragma unroll
    for (int i = 0; i < 8; i++) {
        int chunk = i * 256 + t;
        int r = chunk >> 5, c0 = (chunk & 31) * 8;
        short8 v = {0, 0, 0, 0, 0, 0, 0, 0};
        if (n0 + r < N) v = *reinterpret_cast<const short8*>(&cur[(size_t)(n0 + r) * 256 + c0]);
        *reinterpret_cast<short8*>(reinterpret_cast<char*>(sm) + r * 512 +
                                   ((c0 * 2) ^ ((r & 7) << 4))) = v;
    }
    __syncthreads();
    // phase2: sm = gather + (attn + vs_sum)/den  (all in LDS)
#pragma unroll
    for (int mt = 0; mt < 4; mt++) {
#pragma unroll
        for (int reg = 0; reg < 4; reg++) {
            int r = mt * 16 + lhi * 4 + reg;
            int n = n0 + r;
            if (n < N) {
                float idn = 1.0f / den[n * 2 + h];
#pragma unroll
                for (int nt = 0; nt < 4; nt++) {
                    int c = h * 128 + jh * 64 + nt * 16 + lrow;
                    unsigned short* sp = reinterpret_cast<unsigned short*>(
                        reinterpret_cast<char*>(sm) + r * 512 + ((c * 2) ^ ((r & 7) << 4)));
                    float v = bf2f(*sp) + (acc[mt][nt][reg] + vs_sum[c]) * idn;
                    *sp = f2bf(v);
                }
            }
        }
    }
    __syncthreads();
    // writeback sm -> cur (coalesced)
#pragma unroll
    for (int i = 0; i < 8; i++) {
        int chunk = i * 256 + t;
        int r = chunk >> 5, c0 = (chunk & 31) * 8;
        int n = n0 + r;
        if (n < N)
            *reinterpret_cast<short8*>(&cur[(size_t)n * 256 + c0]) =
                *reinterpret_cast<const short8*>(reinterpret_cast<const char*>(sm) + r * 512 +
                                                 ((c0 * 2) ^ ((r & 7) << 4)));
    }
    __syncthreads();
    // phase3: out += 0.5 * cur @ WoT(tblk)
    f32x4 acc2[4][2];
#pragma unroll
    for (int mt = 0; mt < 4; mt++)
#pragma unroll
        for (int nt = 0; nt < 2; nt++) acc2[mt][nt] = fz;
    for (int kk = 0; kk < 8; kk++) {
        int kb = kk * 32 + lhi * 8;
        short8 af[4];
#pragma unroll
        for (int mt = 0; mt < 4; mt++) {
            int r = mt * 16 + lrow;
            af[mt] = *reinterpret_cast<const short8*>(
                reinterpret_cast<const char*>(sm) + r * 512 + ((kb * 2) ^ ((r & 7) << 4)));
        }
        int woff = (kb >> 7) * 640 + tblk * 128 + (kb & 127);
#pragma unroll
        for (int nt = 0; nt < 2; nt++) {
            int j = w * 32 + nt * 16 + lrow;
            short8 bf = *reinterpret_cast<const short8*>(&WoT[(size_t)j * 1280 + woff]);
#pragma unroll
            for (int mt = 0; mt < 4; mt++)
                acc2[mt][nt] = __builtin_amdgcn_mfma_f32_16x16x32_bf16(af[mt], bf, acc2[mt][nt], 0, 0, 0);
        }
    }
#pragma unroll
    for (int nt = 0; nt < 2; nt++) {
        int j = w * 32 + nt * 16 + lrow;
#pragma unroll
        for (int mt = 0; mt < 4; mt++)
#pragma unroll
            for (int reg = 0; reg < 4; reg++) {
                int n = n0 + mt * 16 + lhi * 4 + reg;
                if (n < N) out[(size_t)n * 128 + j] += 0.5f * acc2[mt][nt][reg];
            }
    }
}

// ---------------------------------------------------------------- term0: out = 0.5*([x|x]@Wo_0 + bias)
__global__ __launch_bounds__(256) void k_out0(const float* __restrict__ x,
                                              const unsigned short* __restrict__ WoT,
                                              const float* __restrict__ Wo_b,
                                              float* __restrict__ out, int N) {
    __shared__ unsigned short sm[64 * 256];
    const int t = threadIdx.x;
    const int n0 = blockIdx.x * 64;
#pragma unroll
    for (int i = 0; i < 8; i++) {
        int chunk = i * 256 + t;
        int r = chunk >> 5, c0 = (chunk & 31) * 8, cs = c0 & 127;
        float4 a0 = make_float4(0.f, 0.f, 0.f, 0.f), a1 = a0;
        if (n0 + r < N) {
            a0 = ld4f(&x[(size_t)(n0 + r) * 128 + cs]);
            a1 = ld4f(&x[(size_t)(n0 + r) * 128 + cs + 4]);
        }
        short8 v = {(short)f2bf(a0.x), (short)f2bf(a0.y), (short)f2bf(a0.z), (short)f2bf(a0.w),
                    (short)f2bf(a1.x), (short)f2bf(a1.y), (short)f2bf(a1.z), (short)f2bf(a1.w)};
        *reinterpret_cast<short8*>(reinterpret_cast<char*>(sm) + r * 512 +
                                   ((c0 * 2) ^ ((r & 7) << 4))) = v;
    }
    __syncthreads();
    const int w = t >> 6, l = t & 63, lrow = l & 15, lhi = l >> 4;
    const f32x4 fz = {0.f, 0.f, 0.f, 0.f};
    f32x4 acc2[4][2];
#pragma unroll
    for (int mt = 0; mt < 4; mt++)
#pragma unroll
        for (int nt = 0; nt < 2; nt++) acc2[mt][nt] = fz;
    for (int kk = 0; kk < 8; kk++) {
        int kb = kk * 32 + lhi * 8;
        short8 af[4];
#pragma unroll
        for (int mt = 0; mt < 4; mt++) {
            int r = mt * 16 + lrow;
            af[mt] = *reinterpret_cast<const short8*>(
                reinterpret_cast<const char*>(sm) + r * 512 + ((kb * 2) ^ ((r & 7) << 4)));
        }
        int woff = (kb >> 7) * 640 + (kb & 127);  // tblk = 0
#pragma unroll
        for (int nt = 0; nt < 2; nt++) {
            int j = w * 32 + nt * 16 + lrow;
            short8 bf = *reinterpret_cast<const short8*>(&WoT[(size_t)j * 1280 + woff]);
#pragma unroll
            for (int mt = 0; mt < 4; mt++)
                acc2[mt][nt] = __builtin_amdgcn_mfma_f32_16x16x32_bf16(af[mt], bf, acc2[mt][nt], 0, 0, 0);
        }
    }
#pragma unroll
    for (int nt = 0; nt < 2; nt++) {
        int j = w * 32 + nt * 16 + lrow;
        float b = Wo_b[j];
#pragma unroll
        for (int mt = 0; mt < 4; mt++)
#pragma unroll
            for (int reg = 0; reg < 4; reg++) {
                int n = n0 + mt * 16 + lhi * 4 + reg;
                if (n < N) out[(size_t)n * 128 + j] = 0.5f * (acc2[mt][nt][reg] + b);
            }
    }
}

// ================================================================ host
extern "C" void kernel_launch(void* const* d_in, const int* in_sizes, int n_in,
                              void* d_out, int out_size, void* d_ws, size_t ws_size,
                              hipStream_t stream) {
    const int N = in_sizes[0] / 128;
    const int E = in_sizes[1] / 2;
    const float* x = (const float*)d_in[0];
    const int* eraw = (const int*)d_in[1];
    const float* Wq_w = (const float*)d_in[2];
    const float* Wq_b = (const float*)d_in[3];
    const float* Wk_w = (const float*)d_in[4];
    const float* Wk_b = (const float*)d_in[5];
    const float* Wo_w = (const float*)d_in[6];
    const float* Wo_b = (const float*)d_in[7];
    float* out = (float*)d_out;

    char* p = (char*)d_ws;
    auto alloc = [&](size_t bytes) -> void* {
        void* r = (void*)p;
        p += (bytes + 255) & ~(size_t)255;
        return r;
    };
    unsigned short* qs = (unsigned short*)alloc((size_t)N * 256 * 2);
    unsigned short* ks = (unsigned short*)alloc((size_t)N * 256 * 2);
    unsigned short* bufA = (unsigned short*)alloc((size_t)N * 256 * 2);
    unsigned short* bufB = (unsigned short*)alloc((size_t)N * 256 * 2);
    float* deg_inv = (float*)alloc((size_t)N * 4);
    float* den = (float*)alloc((size_t)N * 2 * 4);
    float* ks_sum = (float*)alloc(256 * 4);
    float* vs_sum = (float*)alloc(256 * 4);
    float* colpart = (float*)alloc(256 * 256 * 4);
    unsigned short* WqkT = (unsigned short*)alloc(512 * 128 * 2);
    unsigned short* WoT = (unsigned short*)alloc(1280 * 128 * 2);
    unsigned short* kvsTb = (unsigned short*)alloc(32768 * 2);
    int* cnt = (int*)alloc((size_t)N * 4);
    int* offs = (int*)alloc((size_t)N * 4);
    int* gcnt = (int*)alloc(NB * 4);
    int* gbase = (int*)alloc(NB * 4);
    int* gcursor = (int*)alloc(NB * 4);
    int* mode = (int*)alloc(256);
    int* csr = (int*)alloc((size_t)E * 4);
    uint2* ebuf = (uint2*)alloc((size_t)E * 8);

    size_t used = (size_t)(p - (char*)d_ws);
    size_t rem = (ws_size > used + (1 << 20)) ? ws_size - used - (1 << 20) : 0;
    int S = (int)(rem / (32768 * 4 + 1024));
    if (S > 256) S = 256;
    if (S < 8) S = 8;
    float* partial = (float*)alloc((size_t)S * 32768 * 4);
    float* pvsum = (float*)alloc((size_t)S * 256 * 4);
    const int rows_per = (N + S - 1) / S;

    const int CW = (N + NB - 1) / NB;
    const int EBLK = 256;
    const int epb = (E + EBLK - 1) / EBLK;

    hipMemsetAsync(gcnt, 0, NB * 4, stream);

    k_detect<<<1, 256, 0, stream>>>(eraw, E, mode);
    k_hist<<<EBLK, 256, 0, stream>>>(eraw, E, mode, N, CW, epb, gcnt);
    k_bscan<<<1, NB, 0, stream>>>(gcnt, gbase, gcursor);
    k_part<<<EBLK, 256, 0, stream>>>(eraw, E, mode, N, CW, epb, gcursor, ebuf);
    k_build<<<NB, 256, 0, stream>>>(ebuf, gbase, gcnt, N, CW, cnt, offs, deg_inv, csr);

    k_prep_wqk<<<256, 256, 0, stream>>>(Wq_w, Wk_w, WqkT);
    k_prep_wo<<<640, 256, 0, stream>>>(Wo_w, WoT);

    const int nb64 = (N + 63) / 64;
    k_proj<<<nb64, 256, 0, stream>>>(x, WqkT, Wq_b, Wk_b, qs, ks, N);
    k_colsum<<<256, 256, 0, stream>>>(ks, N, colpart);
    k_colsum2<<<1, 256, 0, stream>>>(colpart, ks_sum);
    k_den<<<(N + 3) / 4, 256, 0, stream>>>(qs, ks_sum, den, N);
    k_out0<<<nb64, 256, 0, stream>>>(x, WoT, Wo_b, out, N);

    const int gb4 = (N + 3) / 4;

    // hop 1: prev = x (f32, stride 128, head-broadcast)
    k_kvs2<float><<<S, 256, 0, stream>>>(ks, x, 128, 127, partial, pvsum, rows_per, N);
    k_kvred<<<129, 256, 0, stream>>>(partial, pvsum, S, kvsTb, vs_sum);
    k_gather2f<<<gb4, 256, 0, stream>>>(x, csr, offs, cnt, deg_inv, bufA, N);
    k_att_out<<<nb64, 256, 0, stream>>>(qs, kvsTb, vs_sum, den, bufA, WoT, out, 1, N);

    // hops 2..4
    unsigned short* prev = bufA;
    unsigned short* cur = bufB;
    for (int step = 2; step <= 4; step++) {
        k_kvs2<unsigned short><<<S, 256, 0, stream>>>(ks, prev, 256, 255, partial, pvsum, rows_per,
                                                      N);
        k_kvred<<<129, 256, 0, stream>>>(partial, pvsum, S, kvsTb, vs_sum);
        k_gather2<<<gb4, 256, 0, stream>>>(prev, csr, offs, cnt, deg_inv, cur, N);
        k_att_out<<<nb64, 256, 0, stream>>>(qs, kvsTb, vs_sum, den, cur, WoT, out, step, N);
        unsigned short* tmp = prev;
        prev = cur;
        cur = tmp;
    }
}